// Round 1
// baseline (1657.620 us; speedup 1.0000x reference)
//
#include <hip/hip_runtime.h>
#include <math.h>

// Problem constants (fixed by the reference)
#define NN   32768
#define BG   128
#define SG   256
#define EE   524288
#define DIN_ 128
#define DH_  256
#define NH   8
#define HD_  32
#define DFF_ 1024
#define EPS_ 1e-5f

// ---------------------------------------------------------------------------
// init_avg_h: per-graph mean of raw x. Graph b = rows [b*256, b*256+256)
// (batch input is repeat(arange(B), S) — fixed data, reshape in the reference
// already requires this contiguity).
__global__ __launch_bounds__(128) void initavg_kernel(const float* __restrict__ X,
                                                      float* __restrict__ out2) {
    int b = blockIdx.x, j = threadIdx.x;
    float s = 0.f;
    for (int r = 0; r < SG; ++r) s += X[(size_t)(b * SG + r) * DIN_ + j];
    out2[b * DIN_ + j] = s * (1.f / (float)SG);
}

// Column sum / sumsq partials for BatchNorm stats (axis 0 over all N rows).
template <int C>
__global__ __launch_bounds__(C) void colstats_kernel(const float* __restrict__ X,
                                                     float* __restrict__ csum,
                                                     float* __restrict__ csumsq) {
    int j = threadIdx.x;
    size_t r0 = (size_t)blockIdx.x * 256;
    float s = 0.f, sq = 0.f;
    for (int r = 0; r < 256; ++r) {
        float v = X[(r0 + r) * C + j];
        s += v; sq += v * v;
    }
    atomicAdd(&csum[j], s);
    atomicAdd(&csumsq[j], sq);
}

template <int C>
__global__ __launch_bounds__(C) void bnfin_kernel(const float* __restrict__ csum,
                                                  const float* __restrict__ csumsq,
                                                  const float* __restrict__ g,
                                                  const float* __restrict__ b,
                                                  float* __restrict__ scale,
                                                  float* __restrict__ shift) {
    int j = threadIdx.x;
    float mu  = csum[j] * (1.f / (float)NN);
    float var = csumsq[j] * (1.f / (float)NN) - mu * mu;
    float s = g[j] * rsqrtf(var + EPS_);
    scale[j] = s;
    shift[j] = b[j] - mu * s;
}

template <int C>
__global__ __launch_bounds__(256) void bnapply_kernel(const float* __restrict__ X,
                                                      const float* __restrict__ sc,
                                                      const float* __restrict__ sh,
                                                      float* __restrict__ Y) {
    int i = blockIdx.x * 256 + threadIdx.x;
    int j = i & (C - 1);
    Y[i] = X[i] * sc[j] + sh[j];
}

// ---------------------------------------------------------------------------
// CSR build: deg (atomic), exclusive scan (single 1024-thread block over 32768),
// scatter edges by dest. dis[c] = rsqrt(deg_with_selfloop) = rsqrt(count+1).
__global__ __launch_bounds__(256) void deg_kernel(const int* __restrict__ col,
                                                  int* __restrict__ deg) {
    int e = blockIdx.x * 256 + threadIdx.x;
    if (e < EE) atomicAdd(&deg[col[e]], 1);
}

__global__ __launch_bounds__(1024) void scan_kernel(const int* __restrict__ deg,
                                                    int* __restrict__ off,
                                                    float* __restrict__ dis) {
    __shared__ int sums[1024];
    int t = threadIdx.x;
    int base = t * 32;
    int loc[32];
    int run = 0;
#pragma unroll
    for (int i = 0; i < 32; ++i) { loc[i] = run; run += deg[base + i]; }
    sums[t] = run;
    __syncthreads();
    for (int d = 1; d < 1024; d <<= 1) {
        int tmp = (t >= d) ? sums[t - d] : 0;
        __syncthreads();
        sums[t] += tmp;
        __syncthreads();
    }
    int excl = sums[t] - run;  // exclusive prefix of this thread's chunk
#pragma unroll
    for (int i = 0; i < 32; ++i) {
        off[base + i] = excl + loc[i];
        dis[base + i] = rsqrtf((float)(deg[base + i] + 1));
    }
    if (t == 1023) off[NN] = sums[1023];
}

__global__ __launch_bounds__(256) void scatter_kernel(const int* __restrict__ row,
                                                      const int* __restrict__ col,
                                                      const int* __restrict__ off,
                                                      int* __restrict__ cnt,
                                                      int* __restrict__ srow) {
    int e = blockIdx.x * 256 + threadIdx.x;
    if (e < EE) {
        int c = col[e];
        int p = off[c] + atomicAdd(&cnt[c], 1);
        srow[p] = row[e];
    }
}

// ---------------------------------------------------------------------------
// GCN aggregation (gather form). out[c] = dis[c]*(sum_e dis[row] Hw[row] +
// dis[c]*Hw[c]) + bias, then relu; MODE 1 adds residual h1 and inter_f[graph].
template <int MODE>
__global__ __launch_bounds__(256) void agg_kernel(const float* __restrict__ Hw,
                                                  const int* __restrict__ off,
                                                  const int* __restrict__ srow,
                                                  const float* __restrict__ dis,
                                                  const float* __restrict__ bias,
                                                  const float* __restrict__ h1,
                                                  const float* __restrict__ inter,
                                                  float* __restrict__ out) {
    int c = blockIdx.x;
    int j = threadIdx.x;
    float dc = dis[c];
    float acc = dc * Hw[(size_t)c * DH_ + j];
    int s = off[c], e = off[c + 1];
    for (int i = s; i < e; ++i) {
        int r = srow[i];
        acc += dis[r] * Hw[(size_t)r * DH_ + j];
    }
    float v = fmaxf(acc * dc + bias[j], 0.f);
    if (MODE == 1) {
        int b = c >> 8;  // SG = 256
        v = h1[(size_t)c * DH_ + j] + v + inter[b * DH_ + j];
    }
    out[(size_t)c * DH_ + j] = v;
}

// ---------------------------------------------------------------------------
// Generic fp32 GEMM: C[M,Nc] = A[M,K] @ B[K,Nc] (+bias col) (+res) (relu?).
// 64x64 tile, 256 threads, 4x4 per thread, K panels of 16 in LDS.
// M%64==0, Nc%64==0, K%16==0 hold for every call here.
__global__ __launch_bounds__(256) void gemm_kernel(const float* __restrict__ A,
                                                   const float* __restrict__ B,
                                                   float* __restrict__ C,
                                                   int M, int K, int Nc,
                                                   const float* __restrict__ bias,
                                                   const float* __restrict__ res,
                                                   int do_relu) {
    __shared__ float As[16][68];
    __shared__ float Bs[16][68];
    int bm = blockIdx.y * 64;
    int bn = blockIdx.x * 64;
    int tid = threadIdx.x;
    int tx = tid & 15, ty = tid >> 4;
    float acc[4][4] = {};
    for (int k0 = 0; k0 < K; k0 += 16) {
#pragma unroll
        for (int it = 0; it < 4; ++it) {
            int idx = tid + it * 256;
            int m = idx >> 4, kk = idx & 15;
            As[kk][m] = A[(size_t)(bm + m) * K + k0 + kk];
        }
#pragma unroll
        for (int it = 0; it < 4; ++it) {
            int idx = tid + it * 256;
            int kk = idx >> 6, n = idx & 63;
            Bs[kk][n] = B[(size_t)(k0 + kk) * Nc + bn + n];
        }
        __syncthreads();
#pragma unroll
        for (int kk = 0; kk < 16; ++kk) {
            float4 a4 = *(const float4*)&As[kk][ty * 4];
            float4 b4 = *(const float4*)&Bs[kk][tx * 4];
            float a[4] = {a4.x, a4.y, a4.z, a4.w};
            float bb[4] = {b4.x, b4.y, b4.z, b4.w};
#pragma unroll
            for (int i = 0; i < 4; ++i)
#pragma unroll
                for (int j = 0; j < 4; ++j) acc[i][j] += a[i] * bb[j];
        }
        __syncthreads();
    }
#pragma unroll
    for (int i = 0; i < 4; ++i) {
        int row = bm + ty * 4 + i;
#pragma unroll
        for (int j = 0; j < 4; ++j) {
            int colc = bn + tx * 4 + j;
            float v = acc[i][j];
            if (bias) v += bias[colc];
            if (res) v += res[(size_t)row * Nc + colc];
            if (do_relu) v = fmaxf(v, 0.f);
            C[(size_t)row * Nc + colc] = v;
        }
    }
}

// ---------------------------------------------------------------------------
// Attention: one block per (graph, head). K/V head slices (256x32 each) in LDS,
// one query per thread, register online-softmax.
__global__ __launch_bounds__(256) void attn_kernel(const float* __restrict__ Qm,
                                                   const float* __restrict__ Km,
                                                   const float* __restrict__ Vm,
                                                   float* __restrict__ Om) {
    int b = blockIdx.x >> 3;
    int h = blockIdx.x & 7;
    __shared__ float Ks[SG][HD_];
    __shared__ float Vs[SG][HD_];
    const float* kg = Km + (size_t)b * SG * DH_ + h * HD_;
    const float* vg = Vm + (size_t)b * SG * DH_ + h * HD_;
    for (int c2 = 0; c2 < 32; ++c2) {
        int idx = c2 * 256 + threadIdx.x;
        int s = idx >> 5, d = idx & 31;
        Ks[s][d] = kg[(size_t)s * DH_ + d];
        Vs[s][d] = vg[(size_t)s * DH_ + d];
    }
    __syncthreads();
    int q = threadIdx.x;
    const float* qg = Qm + (size_t)(b * SG + q) * DH_ + h * HD_;
    float qr[HD_];
#pragma unroll
    for (int d = 0; d < HD_; d += 4) {
        float4 t4 = *(const float4*)&qg[d];
        qr[d] = t4.x; qr[d + 1] = t4.y; qr[d + 2] = t4.z; qr[d + 3] = t4.w;
    }
    float m = -1e30f, l = 0.f;
    float o[HD_];
#pragma unroll
    for (int d = 0; d < HD_; ++d) o[d] = 0.f;
    const float sc = 0.17677669529663689f;  // 1/sqrt(32)
    for (int k = 0; k < SG; ++k) {
        float s = 0.f;
#pragma unroll
        for (int d = 0; d < HD_; d += 4) {
            float4 kv = *(const float4*)&Ks[k][d];
            s += qr[d] * kv.x + qr[d + 1] * kv.y + qr[d + 2] * kv.z + qr[d + 3] * kv.w;
        }
        s *= sc;
        float mn = fmaxf(m, s);
        float corr = __expf(m - mn);
        float p = __expf(s - mn);
        l = l * corr + p;
#pragma unroll
        for (int d = 0; d < HD_; d += 4) {
            float4 vv = *(const float4*)&Vs[k][d];
            o[d]     = o[d] * corr     + p * vv.x;
            o[d + 1] = o[d + 1] * corr + p * vv.y;
            o[d + 2] = o[d + 2] * corr + p * vv.z;
            o[d + 3] = o[d + 3] * corr + p * vv.w;
        }
        m = mn;
    }
    float inv = 1.f / l;
    float* og = Om + (size_t)(b * SG + q) * DH_ + h * HD_;
#pragma unroll
    for (int d = 0; d < HD_; d += 4) {
        float4 w4;
        w4.x = o[d] * inv; w4.y = o[d + 1] * inv; w4.z = o[d + 2] * inv; w4.w = o[d + 3] * inv;
        *(float4*)&og[d] = w4;
    }
}

// LayerNorm over last dim (256). One wave per row; in-place safe.
__global__ __launch_bounds__(256) void ln_kernel(const float* __restrict__ Z,
                                                 float* __restrict__ Out,
                                                 const float* __restrict__ g,
                                                 const float* __restrict__ bt) {
    int row = blockIdx.x * 4 + (threadIdx.x >> 6);
    int lane = threadIdx.x & 63;
    const float* z = Z + (size_t)row * DH_;
    float v[4];
    float sum = 0.f;
#pragma unroll
    for (int i = 0; i < 4; ++i) { v[i] = z[lane + i * 64]; sum += v[i]; }
#pragma unroll
    for (int off = 32; off; off >>= 1) sum += __shfl_xor(sum, off);
    float mu = sum * (1.f / (float)DH_);
    float vs = 0.f;
#pragma unroll
    for (int i = 0; i < 4; ++i) { float d = v[i] - mu; vs += d * d; }
#pragma unroll
    for (int off = 32; off; off >>= 1) vs += __shfl_xor(vs, off);
    float rs = rsqrtf(vs * (1.f / (float)DH_) + EPS_);
#pragma unroll
    for (int i = 0; i < 4; ++i) {
        int col = lane + i * 64;
        Out[(size_t)row * DH_ + col] = (v[i] - mu) * rs * g[col] + bt[col];
    }
}

// Readout: per-graph column sum of t3.
__global__ __launch_bounds__(256) void readout_kernel(const float* __restrict__ T3,
                                                      float* __restrict__ out) {
    int b = blockIdx.x, j = threadIdx.x;
    float s = 0.f;
    for (int r = 0; r < SG; ++r) s += T3[(size_t)(b * SG + r) * DH_ + j];
    out[b * DH_ + j] = s;
}

// ---------------------------------------------------------------------------
extern "C" void kernel_launch(void* const* d_in, const int* in_sizes, int n_in,
                              void* d_out, int out_size, void* d_ws, size_t ws_size,
                              hipStream_t stream) {
    const float* x       = (const float*)d_in[0];
    const int*   ei      = (const int*)d_in[1];   // [0..E) row, [E..2E) col
    const float* inter_f = (const float*)d_in[3];
    const float* bn1_g = (const float*)d_in[4],  *bn1_b = (const float*)d_in[5];
    const float* bn2_g = (const float*)d_in[6],  *bn2_b = (const float*)d_in[7];
    const float* w_conv1 = (const float*)d_in[8],  *b_conv1 = (const float*)d_in[9];
    const float* w_conv2 = (const float*)d_in[10], *b_conv2 = (const float*)d_in[11];
    const float* wq = (const float*)d_in[12], *bq = (const float*)d_in[13];
    const float* wk = (const float*)d_in[14], *bk = (const float*)d_in[15];
    const float* wv = (const float*)d_in[16], *bv = (const float*)d_in[17];
    const float* wo = (const float*)d_in[18], *bo = (const float*)d_in[19];
    const float* ln1_g = (const float*)d_in[20], *ln1_b = (const float*)d_in[21];
    const float* ln2_g = (const float*)d_in[22], *ln2_b = (const float*)d_in[23];
    const float* w_ff1 = (const float*)d_in[24], *b_ff1 = (const float*)d_in[25];
    const float* w_ff2 = (const float*)d_in[26], *b_ff2 = (const float*)d_in[27];
    float* out = (float*)d_out;

    // Workspace layout (~195 MB): small CSR/stats region + six 32 MB slots.
    char* base = (char*)d_ws;
    size_t o = 0;
    auto alloc = [&](size_t bytes) -> void* {
        void* p = base + o;
        o = (o + bytes + 255) & ~(size_t)255;
        return p;
    };
    int*   deg    = (int*)alloc(NN * 4);
    int*   off    = (int*)alloc((NN + 1) * 4);
    int*   cnt    = (int*)alloc(NN * 4);
    int*   srow   = (int*)alloc(EE * 4);
    float* dis    = (float*)alloc(NN * 4);
    float* csum   = (float*)alloc(256 * 4);
    float* csumsq = (float*)alloc(256 * 4);
    float* scl    = (float*)alloc(256 * 4);
    float* shf    = (float*)alloc(256 * 4);
    const size_t SLOT = (size_t)NN * DH_;  // floats (32 MB)
    float* S0 = (float*)alloc(SLOT * 4);
    float* S1 = (float*)alloc(SLOT * 4);   // S1..S4 contiguous: FFN hidden lives here
    float* S2 = (float*)alloc(SLOT * 4);
    float* S3 = (float*)alloc(SLOT * 4);
    float* S4 = (float*)alloc(SLOT * 4);
    float* S5 = (float*)alloc(SLOT * 4);

    // Zero accumulators (re-poisoned to 0xAA before every timed launch).
    hipMemsetAsync(deg, 0, NN * 4, stream);
    hipMemsetAsync(cnt, 0, NN * 4, stream);
    hipMemsetAsync(csum, 0, 2048, stream);  // csum + csumsq (adjacent)

    // init_avg_h -> out[B*DH ...]
    initavg_kernel<<<BG, 128, 0, stream>>>(x, out + BG * DH_);

    // BN1 stats + apply: xb -> S0
    colstats_kernel<DIN_><<<NN / 256, DIN_, 0, stream>>>(x, csum, csumsq);
    bnfin_kernel<DIN_><<<1, DIN_, 0, stream>>>(csum, csumsq, bn1_g, bn1_b, scl, shf);
    bnapply_kernel<DIN_><<<NN * DIN_ / 256, 256, 0, stream>>>(x, scl, shf, S0);

    // CSR build
    deg_kernel<<<EE / 256, 256, 0, stream>>>(ei + EE, deg);
    scan_kernel<<<1, 1024, 0, stream>>>(deg, off, dis);
    scatter_kernel<<<EE / 256, 256, 0, stream>>>(ei, ei + EE, off, cnt, srow);

    // conv1: Hw1 = xb @ w_conv1 -> S1 ; h1 = relu(agg + b) -> S2
    gemm_kernel<<<dim3(DH_ / 64, NN / 64), 256, 0, stream>>>(S0, w_conv1, S1, NN, DIN_, DH_,
                                                             nullptr, nullptr, 0);
    agg_kernel<0><<<NN, 256, 0, stream>>>(S1, off, srow, dis, b_conv1, nullptr, nullptr, S2);

    // BN2 stats + apply: xb2 -> S0
    hipMemsetAsync(csum, 0, 2048, stream);
    colstats_kernel<DH_><<<NN / 256, DH_, 0, stream>>>(S2, csum, csumsq);
    bnfin_kernel<DH_><<<1, DH_, 0, stream>>>(csum, csumsq, bn2_g, bn2_b, scl, shf);
    bnapply_kernel<DH_><<<NN * DH_ / 256, 256, 0, stream>>>(S2, scl, shf, S0);

    // conv2: Hw2 = xb2 @ w_conv2 -> S1 ; t = h1 + relu(agg + b) + inter -> S3
    gemm_kernel<<<dim3(DH_ / 64, NN / 64), 256, 0, stream>>>(S0, w_conv2, S1, NN, DH_, DH_,
                                                             nullptr, nullptr, 0);
    agg_kernel<1><<<NN, 256, 0, stream>>>(S1, off, srow, dis, b_conv2, S2, inter_f, S3);

    // Q,K,V projections
    gemm_kernel<<<dim3(DH_ / 64, NN / 64), 256, 0, stream>>>(S3, wq, S0, NN, DH_, DH_, bq, nullptr, 0);
    gemm_kernel<<<dim3(DH_ / 64, NN / 64), 256, 0, stream>>>(S3, wk, S1, NN, DH_, DH_, bk, nullptr, 0);
    gemm_kernel<<<dim3(DH_ / 64, NN / 64), 256, 0, stream>>>(S3, wv, S2, NN, DH_, DH_, bv, nullptr, 0);

    // attention -> O in S4
    attn_kernel<<<BG * NH, 256, 0, stream>>>(S0, S1, S2, S4);

    // z = O @ wo + bo + t -> S5 ; t2 = LN(z) -> S0
    gemm_kernel<<<dim3(DH_ / 64, NN / 64), 256, 0, stream>>>(S4, wo, S5, NN, DH_, DH_, bo, S3, 0);
    ln_kernel<<<NN / 4, 256, 0, stream>>>(S5, S0, ln1_g, ln1_b);

    // FFN: F = relu(t2 @ w_ff1 + b1) -> S1..S4 (128 MB) ; z2 = F @ w_ff2 + b2 + t2 -> S5
    gemm_kernel<<<dim3(DFF_ / 64, NN / 64), 256, 0, stream>>>(S0, w_ff1, S1, NN, DH_, DFF_,
                                                              b_ff1, nullptr, 1);
    gemm_kernel<<<dim3(DH_ / 64, NN / 64), 256, 0, stream>>>(S1, w_ff2, S5, NN, DFF_, DH_,
                                                             b_ff2, S0, 0);

    // t3 = LN(z2) in-place ; readout -> out[0 .. B*DH)
    ln_kernel<<<NN / 4, 256, 0, stream>>>(S5, S5, ln2_g, ln2_b);
    readout_kernel<<<BG, 256, 0, stream>>>(S5, out);
}

// Round 2
// 1055.838 us; speedup vs baseline: 1.5700x; 1.5700x over previous
//
#include <hip/hip_runtime.h>
#include <math.h>

// Problem constants (fixed by the reference)
#define NN   32768
#define BG   128
#define SG   256
#define EE   524288
#define DIN_ 128
#define DH_  256
#define NH   8
#define HD_  32
#define DFF_ 1024
#define EPS_ 1e-5f

typedef __attribute__((ext_vector_type(8))) short bf16x8;
typedef __attribute__((ext_vector_type(4))) float f32x4;

__device__ __forceinline__ unsigned short f2bf(float f) {
    unsigned int u = __builtin_bit_cast(unsigned int, f);
    unsigned int r = u + 0x7FFFu + ((u >> 16) & 1u);
    return (unsigned short)(r >> 16);
}

// ---------------------------------------------------------------------------
// init_avg_h: per-graph mean of raw x (graph b = rows [b*256, b*256+256)).
__global__ __launch_bounds__(128) void initavg_kernel(const float* __restrict__ X,
                                                      float* __restrict__ out2) {
    int b = blockIdx.x, j = threadIdx.x;
    float s = 0.f;
    for (int r = 0; r < SG; ++r) s += X[(size_t)(b * SG + r) * DIN_ + j];
    out2[b * DIN_ + j] = s * (1.f / (float)SG);
}

// Column sum / sumsq partials for BatchNorm stats (axis 0 over all N rows).
template <int C>
__global__ __launch_bounds__(C) void colstats_kernel(const float* __restrict__ X,
                                                     float* __restrict__ csum,
                                                     float* __restrict__ csumsq) {
    int j = threadIdx.x;
    size_t r0 = (size_t)blockIdx.x * 256;
    float s = 0.f, sq = 0.f;
    for (int r = 0; r < 256; ++r) {
        float v = X[(r0 + r) * C + j];
        s += v; sq += v * v;
    }
    atomicAdd(&csum[j], s);
    atomicAdd(&csumsq[j], sq);
}

template <int C>
__global__ __launch_bounds__(C) void bnfin_kernel(const float* __restrict__ csum,
                                                  const float* __restrict__ csumsq,
                                                  const float* __restrict__ g,
                                                  const float* __restrict__ b,
                                                  float* __restrict__ scale,
                                                  float* __restrict__ shift) {
    int j = threadIdx.x;
    float mu  = csum[j] * (1.f / (float)NN);
    float var = csumsq[j] * (1.f / (float)NN) - mu * mu;
    float s = g[j] * rsqrtf(var + EPS_);
    scale[j] = s;
    shift[j] = b[j] - mu * s;
}

// BN apply, bf16 output (feeds MFMA GEMM A operand).
template <int C>
__global__ __launch_bounds__(256) void bnapply_kernel(const float* __restrict__ X,
                                                      const float* __restrict__ sc,
                                                      const float* __restrict__ sh,
                                                      unsigned short* __restrict__ Y) {
    int i = blockIdx.x * 256 + threadIdx.x;
    int j = i & (C - 1);
    Y[i] = f2bf(X[i] * sc[j] + sh[j]);
}

// Weight cast+transpose: W[K,N] fp32 -> Wt[N,K] bf16. Coalesced writes.
__global__ __launch_bounds__(256) void wtrans_kernel(const float* __restrict__ W,
                                                     unsigned short* __restrict__ Wt,
                                                     int K, int N) {
    int idx = blockIdx.x * 256 + threadIdx.x;
    if (idx < K * N) {
        int n = idx / K, k = idx - n * K;
        Wt[idx] = f2bf(W[(size_t)k * N + n]);
    }
}

// ---------------------------------------------------------------------------
// CSR build
__global__ __launch_bounds__(256) void deg_kernel(const int* __restrict__ col,
                                                  int* __restrict__ deg) {
    int e = blockIdx.x * 256 + threadIdx.x;
    if (e < EE) atomicAdd(&deg[col[e]], 1);
}

__global__ __launch_bounds__(1024) void scan_kernel(const int* __restrict__ deg,
                                                    int* __restrict__ off,
                                                    float* __restrict__ dis) {
    __shared__ int sums[1024];
    int t = threadIdx.x;
    int base = t * 32;
    int loc[32];
    int run = 0;
#pragma unroll
    for (int i = 0; i < 32; ++i) { loc[i] = run; run += deg[base + i]; }
    sums[t] = run;
    __syncthreads();
    for (int d = 1; d < 1024; d <<= 1) {
        int tmp = (t >= d) ? sums[t - d] : 0;
        __syncthreads();
        sums[t] += tmp;
        __syncthreads();
    }
    int excl = sums[t] - run;
#pragma unroll
    for (int i = 0; i < 32; ++i) {
        off[base + i] = excl + loc[i];
        dis[base + i] = rsqrtf((float)(deg[base + i] + 1));
    }
    if (t == 1023) off[NN] = sums[1023];
}

__global__ __launch_bounds__(256) void scatter_kernel(const int* __restrict__ row,
                                                      const int* __restrict__ col,
                                                      const int* __restrict__ off,
                                                      int* __restrict__ cnt,
                                                      int* __restrict__ srow) {
    int e = blockIdx.x * 256 + threadIdx.x;
    if (e < EE) {
        int c = col[e];
        int p = off[c] + atomicAdd(&cnt[c], 1);
        srow[p] = row[e];
    }
}

// ---------------------------------------------------------------------------
// GCN aggregation (gather form). MODE 0: out fp32 = relu(agg+bias).
// MODE 1: t = h1 + relu(agg+bias) + inter[graph]; writes fp32 AND bf16.
template <int MODE>
__global__ __launch_bounds__(256) void agg_kernel(const float* __restrict__ Hw,
                                                  const int* __restrict__ off,
                                                  const int* __restrict__ srow,
                                                  const float* __restrict__ dis,
                                                  const float* __restrict__ bias,
                                                  const float* __restrict__ h1,
                                                  const float* __restrict__ inter,
                                                  float* __restrict__ out,
                                                  unsigned short* __restrict__ outb) {
    int c = blockIdx.x;
    int j = threadIdx.x;
    float dc = dis[c];
    float acc = dc * Hw[(size_t)c * DH_ + j];
    int s = off[c], e = off[c + 1];
    for (int i = s; i < e; ++i) {
        int r = srow[i];
        acc += dis[r] * Hw[(size_t)r * DH_ + j];
    }
    float v = fmaxf(acc * dc + bias[j], 0.f);
    if (MODE == 1) {
        int b = c >> 8;
        v = h1[(size_t)c * DH_ + j] + v + inter[b * DH_ + j];
        outb[(size_t)c * DH_ + j] = f2bf(v);
    }
    out[(size_t)c * DH_ + j] = v;
}

// ---------------------------------------------------------------------------
// bf16 MFMA GEMM: C[M,N] = A[M,K] @ B[K,N], A bf16 row-major, Bt = B^T bf16
// [N,K] row-major. 128x128 tile, 4 waves in 2x2, each wave 4x4 grid of
// 16x16x32 MFMAs. Optional bias/res(fp32)/relu; writes fp32 and/or bf16.
// M%128==0, N%128==0, K%32==0.
__global__ __launch_bounds__(256) void gemm_bf16_kernel(
    const unsigned short* __restrict__ A,
    const unsigned short* __restrict__ Bt,
    float* __restrict__ Cf,
    unsigned short* __restrict__ Cb,
    int M, int K, int N,
    const float* __restrict__ bias,
    const float* __restrict__ res,
    int do_relu) {
    constexpr int LDP = 40;  // row pitch in bf16 (32 + 8 pad -> 2-way banks only)
    __shared__ unsigned short As[128 * LDP];
    __shared__ unsigned short Bs[128 * LDP];
    int bm = blockIdx.y * 128;
    int bn = blockIdx.x * 128;
    int tid = threadIdx.x;
    int wave = tid >> 6, lane = tid & 63;
    int wm = (wave & 1) * 64, wn = (wave >> 1) * 64;
    int lrc = lane & 15;    // row(m) for A-frag / col(n) for B-frag
    int koct = lane >> 4;   // k-octet 0..3

    f32x4 acc[4][4];
#pragma unroll
    for (int i = 0; i < 4; ++i)
#pragma unroll
        for (int j = 0; j < 4; ++j) acc[i][j] = (f32x4){0.f, 0.f, 0.f, 0.f};

    for (int k0 = 0; k0 < K; k0 += 32) {
        // stage 128x32 bf16 tiles as 512 16B chunks each; 2 chunks/thread each
#pragma unroll
        for (int it = 0; it < 2; ++it) {
            int c = tid + it * 256;
            int row = c >> 2, offk = (c & 3) * 8;
            *(uint4*)(As + row * LDP + offk) =
                *(const uint4*)(A + (size_t)(bm + row) * K + k0 + offk);
            *(uint4*)(Bs + row * LDP + offk) =
                *(const uint4*)(Bt + (size_t)(bn + row) * K + k0 + offk);
        }
        __syncthreads();
        bf16x8 af[4], bfr[4];
#pragma unroll
        for (int i = 0; i < 4; ++i)
            af[i] = *(const bf16x8*)(As + (wm + i * 16 + lrc) * LDP + koct * 8);
#pragma unroll
        for (int j = 0; j < 4; ++j)
            bfr[j] = *(const bf16x8*)(Bs + (wn + j * 16 + lrc) * LDP + koct * 8);
#pragma unroll
        for (int i = 0; i < 4; ++i)
#pragma unroll
            for (int j = 0; j < 4; ++j)
                acc[i][j] = __builtin_amdgcn_mfma_f32_16x16x32_bf16(af[i], bfr[j],
                                                                    acc[i][j], 0, 0, 0);
        __syncthreads();
    }
    // epilogue: C/D layout col=lane&15, row=(lane>>4)*4+reg
#pragma unroll
    for (int i = 0; i < 4; ++i) {
#pragma unroll
        for (int r = 0; r < 4; ++r) {
            int grow = bm + wm + i * 16 + koct * 4 + r;
#pragma unroll
            for (int j = 0; j < 4; ++j) {
                int gcol = bn + wn + j * 16 + lrc;
                float v = acc[i][j][r];
                if (bias) v += bias[gcol];
                if (res) v += res[(size_t)grow * N + gcol];
                if (do_relu) v = fmaxf(v, 0.f);
                if (Cf) Cf[(size_t)grow * N + gcol] = v;
                if (Cb) Cb[(size_t)grow * N + gcol] = f2bf(v);
            }
        }
    }
}

// ---------------------------------------------------------------------------
// Attention: one block per (graph, head). K/V head slices in LDS, one query
// per thread, register online-softmax. Output written as bf16 (feeds O-proj).
__global__ __launch_bounds__(256) void attn_kernel(const float* __restrict__ Qm,
                                                   const float* __restrict__ Km,
                                                   const float* __restrict__ Vm,
                                                   unsigned short* __restrict__ Om) {
    int b = blockIdx.x >> 3;
    int h = blockIdx.x & 7;
    __shared__ float Ks[SG][HD_];
    __shared__ float Vs[SG][HD_];
    const float* kg = Km + (size_t)b * SG * DH_ + h * HD_;
    const float* vg = Vm + (size_t)b * SG * DH_ + h * HD_;
    for (int c2 = 0; c2 < 32; ++c2) {
        int idx = c2 * 256 + threadIdx.x;
        int s = idx >> 5, d = idx & 31;
        Ks[s][d] = kg[(size_t)s * DH_ + d];
        Vs[s][d] = vg[(size_t)s * DH_ + d];
    }
    __syncthreads();
    int q = threadIdx.x;
    const float* qg = Qm + (size_t)(b * SG + q) * DH_ + h * HD_;
    float qr[HD_];
#pragma unroll
    for (int d = 0; d < HD_; d += 4) {
        float4 t4 = *(const float4*)&qg[d];
        qr[d] = t4.x; qr[d + 1] = t4.y; qr[d + 2] = t4.z; qr[d + 3] = t4.w;
    }
    float m = -1e30f, l = 0.f;
    float o[HD_];
#pragma unroll
    for (int d = 0; d < HD_; ++d) o[d] = 0.f;
    const float sc = 0.17677669529663689f;  // 1/sqrt(32)
    for (int k = 0; k < SG; ++k) {
        float s = 0.f;
#pragma unroll
        for (int d = 0; d < HD_; d += 4) {
            float4 kv = *(const float4*)&Ks[k][d];
            s += qr[d] * kv.x + qr[d + 1] * kv.y + qr[d + 2] * kv.z + qr[d + 3] * kv.w;
        }
        s *= sc;
        float mn = fmaxf(m, s);
        float corr = __expf(m - mn);
        float p = __expf(s - mn);
        l = l * corr + p;
#pragma unroll
        for (int d = 0; d < HD_; d += 4) {
            float4 vv = *(const float4*)&Vs[k][d];
            o[d]     = o[d] * corr     + p * vv.x;
            o[d + 1] = o[d + 1] * corr + p * vv.y;
            o[d + 2] = o[d + 2] * corr + p * vv.z;
            o[d + 3] = o[d + 3] * corr + p * vv.w;
        }
        m = mn;
    }
    float inv = 1.f / l;
    unsigned short* og = Om + (size_t)(b * SG + q) * DH_ + h * HD_;
#pragma unroll
    for (int d = 0; d < HD_; ++d) og[d] = f2bf(o[d] * inv);
}

// LayerNorm over last dim (256). One wave per row; in-place safe.
// Optional bf16 secondary output.
__global__ __launch_bounds__(256) void ln_kernel(const float* __restrict__ Z,
                                                 float* __restrict__ Out,
                                                 unsigned short* __restrict__ Outb,
                                                 const float* __restrict__ g,
                                                 const float* __restrict__ bt) {
    int row = blockIdx.x * 4 + (threadIdx.x >> 6);
    int lane = threadIdx.x & 63;
    const float* z = Z + (size_t)row * DH_;
    float v[4];
    float sum = 0.f;
#pragma unroll
    for (int i = 0; i < 4; ++i) { v[i] = z[lane + i * 64]; sum += v[i]; }
#pragma unroll
    for (int off = 32; off; off >>= 1) sum += __shfl_xor(sum, off);
    float mu = sum * (1.f / (float)DH_);
    float vs = 0.f;
#pragma unroll
    for (int i = 0; i < 4; ++i) { float d = v[i] - mu; vs += d * d; }
#pragma unroll
    for (int off = 32; off; off >>= 1) vs += __shfl_xor(vs, off);
    float rs = rsqrtf(vs * (1.f / (float)DH_) + EPS_);
#pragma unroll
    for (int i = 0; i < 4; ++i) {
        int col = lane + i * 64;
        float y = (v[i] - mu) * rs * g[col] + bt[col];
        Out[(size_t)row * DH_ + col] = y;
        if (Outb) Outb[(size_t)row * DH_ + col] = f2bf(y);
    }
}

// Readout: per-graph column sum of t3.
__global__ __launch_bounds__(256) void readout_kernel(const float* __restrict__ T3,
                                                      float* __restrict__ out) {
    int b = blockIdx.x, j = threadIdx.x;
    float s = 0.f;
    for (int r = 0; r < SG; ++r) s += T3[(size_t)(b * SG + r) * DH_ + j];
    out[b * DH_ + j] = s;
}

// ---------------------------------------------------------------------------
extern "C" void kernel_launch(void* const* d_in, const int* in_sizes, int n_in,
                              void* d_out, int out_size, void* d_ws, size_t ws_size,
                              hipStream_t stream) {
    const float* x       = (const float*)d_in[0];
    const int*   ei      = (const int*)d_in[1];
    const float* inter_f = (const float*)d_in[3];
    const float* bn1_g = (const float*)d_in[4],  *bn1_b = (const float*)d_in[5];
    const float* bn2_g = (const float*)d_in[6],  *bn2_b = (const float*)d_in[7];
    const float* w_conv1 = (const float*)d_in[8],  *b_conv1 = (const float*)d_in[9];
    const float* w_conv2 = (const float*)d_in[10], *b_conv2 = (const float*)d_in[11];
    const float* wq = (const float*)d_in[12], *bq = (const float*)d_in[13];
    const float* wk = (const float*)d_in[14], *bk = (const float*)d_in[15];
    const float* wv = (const float*)d_in[16], *bv = (const float*)d_in[17];
    const float* wo = (const float*)d_in[18], *bo = (const float*)d_in[19];
    const float* ln1_g = (const float*)d_in[20], *ln1_b = (const float*)d_in[21];
    const float* ln2_g = (const float*)d_in[22], *ln2_b = (const float*)d_in[23];
    const float* w_ff1 = (const float*)d_in[24], *b_ff1 = (const float*)d_in[25];
    const float* w_ff2 = (const float*)d_in[26], *b_ff2 = (const float*)d_in[27];
    float* out = (float*)d_out;

    // Workspace (~180 MB): CSR/stats + 5 fp32 slots (S0,S1 contiguous for the
    // 64 MB bf16 FFN-hidden alias) + one 16 MB bf16 scratch + bf16 weights.
    char* base = (char*)d_ws;
    size_t o = 0;
    auto alloc = [&](size_t bytes) -> void* {
        void* p = base + o;
        o = (o + bytes + 255) & ~(size_t)255;
        return p;
    };
    int*   deg    = (int*)alloc(NN * 4);
    int*   off    = (int*)alloc((NN + 1) * 4);
    int*   cnt    = (int*)alloc(NN * 4);
    int*   srow   = (int*)alloc(EE * 4);
    float* dis    = (float*)alloc(NN * 4);
    float* csum   = (float*)alloc(256 * 4);
    float* csumsq = (float*)alloc(256 * 4);
    float* scl    = (float*)alloc(256 * 4);
    float* shf    = (float*)alloc(256 * 4);
    const size_t SLOT = (size_t)NN * DH_;            // 8M floats = 32 MB
    float* S0 = (float*)alloc(SLOT * 4);             // Hw -> Q -> F(lo)
    float* S1 = (float*)alloc(SLOT * 4);             // h1 -> K -> F(hi)
    float* S2 = (float*)alloc(SLOT * 4);             // V -> z2/t3
    float* S3 = (float*)alloc(SLOT * 4);             // t
    float* S4 = (float*)alloc(SLOT * 4);             // z -> t2
    unsigned short* B0 = (unsigned short*)alloc(SLOT * 2);  // Xb/X2b/tb/Ob/t2b
    unsigned short* wc1t = (unsigned short*)alloc((size_t)DIN_ * DH_ * 2);
    unsigned short* wc2t = (unsigned short*)alloc((size_t)DH_ * DH_ * 2);
    unsigned short* wqt  = (unsigned short*)alloc((size_t)DH_ * DH_ * 2);
    unsigned short* wkt  = (unsigned short*)alloc((size_t)DH_ * DH_ * 2);
    unsigned short* wvt  = (unsigned short*)alloc((size_t)DH_ * DH_ * 2);
    unsigned short* wot  = (unsigned short*)alloc((size_t)DH_ * DH_ * 2);
    unsigned short* wf1t = (unsigned short*)alloc((size_t)DH_ * DFF_ * 2);
    unsigned short* wf2t = (unsigned short*)alloc((size_t)DFF_ * DH_ * 2);
    unsigned short* Fb   = (unsigned short*)S0;      // 64 MB bf16 over S0+S1

    hipMemsetAsync(deg, 0, NN * 4, stream);
    hipMemsetAsync(cnt, 0, NN * 4, stream);
    hipMemsetAsync(csum, 0, 2048, stream);

    // Weight transposes (bf16): tiny, overlap with everything below.
    wtrans_kernel<<<(DIN_ * DH_ + 255) / 256, 256, 0, stream>>>(w_conv1, wc1t, DIN_, DH_);
    wtrans_kernel<<<(DH_ * DH_ + 255) / 256, 256, 0, stream>>>(w_conv2, wc2t, DH_, DH_);
    wtrans_kernel<<<(DH_ * DH_ + 255) / 256, 256, 0, stream>>>(wq, wqt, DH_, DH_);
    wtrans_kernel<<<(DH_ * DH_ + 255) / 256, 256, 0, stream>>>(wk, wkt, DH_, DH_);
    wtrans_kernel<<<(DH_ * DH_ + 255) / 256, 256, 0, stream>>>(wv, wvt, DH_, DH_);
    wtrans_kernel<<<(DH_ * DH_ + 255) / 256, 256, 0, stream>>>(wo, wot, DH_, DH_);
    wtrans_kernel<<<(DH_ * DFF_ + 255) / 256, 256, 0, stream>>>(w_ff1, wf1t, DH_, DFF_);
    wtrans_kernel<<<(DFF_ * DH_ + 255) / 256, 256, 0, stream>>>(w_ff2, wf2t, DFF_, DH_);

    // init_avg_h -> out[B*DH ...]
    initavg_kernel<<<BG, 128, 0, stream>>>(x, out + BG * DH_);

    // BN1 -> Xb bf16 (B0)
    colstats_kernel<DIN_><<<NN / 256, DIN_, 0, stream>>>(x, csum, csumsq);
    bnfin_kernel<DIN_><<<1, DIN_, 0, stream>>>(csum, csumsq, bn1_g, bn1_b, scl, shf);
    bnapply_kernel<DIN_><<<NN * DIN_ / 256, 256, 0, stream>>>(x, scl, shf, B0);

    // CSR build
    deg_kernel<<<EE / 256, 256, 0, stream>>>(ei + EE, deg);
    scan_kernel<<<1, 1024, 0, stream>>>(deg, off, dis);
    scatter_kernel<<<EE / 256, 256, 0, stream>>>(ei, ei + EE, off, cnt, srow);

    // conv1: Hw = Xb @ w_conv1 -> S0 ; h1 = relu(agg + b) -> S1
    gemm_bf16_kernel<<<dim3(DH_ / 128, NN / 128), 256, 0, stream>>>(
        B0, wc1t, S0, nullptr, NN, DIN_, DH_, nullptr, nullptr, 0);
    agg_kernel<0><<<NN, 256, 0, stream>>>(S0, off, srow, dis, b_conv1, nullptr, nullptr,
                                          S1, nullptr);

    // BN2 -> X2b bf16 (B0)
    hipMemsetAsync(csum, 0, 2048, stream);
    colstats_kernel<DH_><<<NN / 256, DH_, 0, stream>>>(S1, csum, csumsq);
    bnfin_kernel<DH_><<<1, DH_, 0, stream>>>(csum, csumsq, bn2_g, bn2_b, scl, shf);
    bnapply_kernel<DH_><<<NN * DH_ / 256, 256, 0, stream>>>(S1, scl, shf, B0);

    // conv2: Hw = X2b @ w_conv2 -> S0 ; t = h1 + relu(agg+b) + inter -> S3 + B0(bf16)
    gemm_bf16_kernel<<<dim3(DH_ / 128, NN / 128), 256, 0, stream>>>(
        B0, wc2t, S0, nullptr, NN, DH_, DH_, nullptr, nullptr, 0);
    agg_kernel<1><<<NN, 256, 0, stream>>>(S0, off, srow, dis, b_conv2, S1, inter_f,
                                          S3, B0);

    // Q,K,V projections (A = t bf16 in B0)
    gemm_bf16_kernel<<<dim3(DH_ / 128, NN / 128), 256, 0, stream>>>(
        B0, wqt, S0, nullptr, NN, DH_, DH_, bq, nullptr, 0);
    gemm_bf16_kernel<<<dim3(DH_ / 128, NN / 128), 256, 0, stream>>>(
        B0, wkt, S1, nullptr, NN, DH_, DH_, bk, nullptr, 0);
    gemm_bf16_kernel<<<dim3(DH_ / 128, NN / 128), 256, 0, stream>>>(
        B0, wvt, S2, nullptr, NN, DH_, DH_, bv, nullptr, 0);

    // attention -> Ob bf16 (B0; tb dead after V projection)
    attn_kernel<<<BG * NH, 256, 0, stream>>>(S0, S1, S2, B0);

    // z = Ob @ wo + bo + t -> S4 ; t2 = LN(z) -> S4 (+bf16 B0)
    gemm_bf16_kernel<<<dim3(DH_ / 128, NN / 128), 256, 0, stream>>>(
        B0, wot, S4, nullptr, NN, DH_, DH_, bo, S3, 0);
    ln_kernel<<<NN / 4, 256, 0, stream>>>(S4, S4, B0, ln1_g, ln1_b);

    // FFN: F = relu(t2 @ w_ff1 + b1) -> Fb (bf16, S0+S1) ;
    //      z2 = F @ w_ff2 + b2 + t2 -> S2
    gemm_bf16_kernel<<<dim3(DFF_ / 128, NN / 128), 256, 0, stream>>>(
        B0, wf1t, nullptr, Fb, NN, DH_, DFF_, b_ff1, nullptr, 1);
    gemm_bf16_kernel<<<dim3(DH_ / 128, NN / 128), 256, 0, stream>>>(
        Fb, wf2t, S2, nullptr, NN, DFF_, DH_, b_ff2, S4, 0);

    // t3 = LN(z2) in-place ; readout -> out[0 .. B*DH)
    ln_kernel<<<NN / 4, 256, 0, stream>>>(S2, S2, nullptr, ln2_g, ln2_b);
    readout_kernel<<<BG, 256, 0, stream>>>(S2, out);
}

// Round 3
// 893.650 us; speedup vs baseline: 1.8549x; 1.1815x over previous
//
#include <hip/hip_runtime.h>
#include <math.h>

// Problem constants (fixed by the reference)
#define NN   32768
#define BG   128
#define SG   256
#define EE   524288
#define DIN_ 128
#define DH_  256
#define NH   8
#define HD_  32
#define DFF_ 1024
#define EPS_ 1e-5f

typedef __attribute__((ext_vector_type(8))) short bf16x8;
typedef __attribute__((ext_vector_type(4))) float f32x4;

__device__ __forceinline__ unsigned short f2bf(float f) {
    unsigned int u = __builtin_bit_cast(unsigned int, f);
    unsigned int r = u + 0x7FFFu + ((u >> 16) & 1u);
    return (unsigned short)(r >> 16);
}

// ---------------------------------------------------------------------------
// init_avg_h: per-graph mean of raw x (graph b = rows [b*256, b*256+256)).
__global__ __launch_bounds__(128) void initavg_kernel(const float* __restrict__ X,
                                                      float* __restrict__ out2) {
    int b = blockIdx.x, j = threadIdx.x;
    float s = 0.f;
    for (int r = 0; r < SG; ++r) s += X[(size_t)(b * SG + r) * DIN_ + j];
    out2[b * DIN_ + j] = s * (1.f / (float)SG);
}

// Column sum / sumsq partials for BatchNorm stats (axis 0 over all N rows).
template <int C>
__global__ __launch_bounds__(C) void colstats_kernel(const float* __restrict__ X,
                                                     float* __restrict__ csum,
                                                     float* __restrict__ csumsq) {
    int j = threadIdx.x;
    size_t r0 = (size_t)blockIdx.x * 256;
    float s = 0.f, sq = 0.f;
    for (int r = 0; r < 256; ++r) {
        float v = X[(r0 + r) * C + j];
        s += v; sq += v * v;
    }
    atomicAdd(&csum[j], s);
    atomicAdd(&csumsq[j], sq);
}

template <int C>
__global__ __launch_bounds__(C) void bnfin_kernel(const float* __restrict__ csum,
                                                  const float* __restrict__ csumsq,
                                                  const float* __restrict__ g,
                                                  const float* __restrict__ b,
                                                  float* __restrict__ scale,
                                                  float* __restrict__ shift) {
    int j = threadIdx.x;
    float mu  = csum[j] * (1.f / (float)NN);
    float var = csumsq[j] * (1.f / (float)NN) - mu * mu;
    float s = g[j] * rsqrtf(var + EPS_);
    scale[j] = s;
    shift[j] = b[j] - mu * s;
}

// BN apply, bf16 output (feeds MFMA GEMM A operand).
template <int C>
__global__ __launch_bounds__(256) void bnapply_kernel(const float* __restrict__ X,
                                                      const float* __restrict__ sc,
                                                      const float* __restrict__ sh,
                                                      unsigned short* __restrict__ Y) {
    int i = blockIdx.x * 256 + threadIdx.x;
    int j = i & (C - 1);
    Y[i] = f2bf(X[i] * sc[j] + sh[j]);
}

// Weight cast+transpose: W[K,N] fp32 -> Wt[N,K] bf16. Coalesced writes.
__global__ __launch_bounds__(256) void wtrans_kernel(const float* __restrict__ W,
                                                     unsigned short* __restrict__ Wt,
                                                     int K, int N) {
    int idx = blockIdx.x * 256 + threadIdx.x;
    if (idx < K * N) {
        int n = idx / K, k = idx - n * K;
        Wt[idx] = f2bf(W[(size_t)k * N + n]);
    }
}

// Concat Q/K/V biases into one fp32[768].
__global__ __launch_bounds__(256) void bcat_kernel(const float* __restrict__ bq,
                                                   const float* __restrict__ bk,
                                                   const float* __restrict__ bv,
                                                   float* __restrict__ o) {
    int j = threadIdx.x;
    if (blockIdx.x == 0) o[j] = bq[j];
    else if (blockIdx.x == 1) o[DH_ + j] = bk[j];
    else o[2 * DH_ + j] = bv[j];
}

// ---------------------------------------------------------------------------
// CSR build
__global__ __launch_bounds__(256) void deg_kernel(const int* __restrict__ col,
                                                  int* __restrict__ deg) {
    int e = blockIdx.x * 256 + threadIdx.x;
    if (e < EE) atomicAdd(&deg[col[e]], 1);
}

__global__ __launch_bounds__(1024) void scan_kernel(const int* __restrict__ deg,
                                                    int* __restrict__ off,
                                                    float* __restrict__ dis) {
    __shared__ int sums[1024];
    int t = threadIdx.x;
    int base = t * 32;
    int loc[32];
    int run = 0;
#pragma unroll
    for (int i = 0; i < 32; ++i) { loc[i] = run; run += deg[base + i]; }
    sums[t] = run;
    __syncthreads();
    for (int d = 1; d < 1024; d <<= 1) {
        int tmp = (t >= d) ? sums[t - d] : 0;
        __syncthreads();
        sums[t] += tmp;
        __syncthreads();
    }
    int excl = sums[t] - run;
#pragma unroll
    for (int i = 0; i < 32; ++i) {
        off[base + i] = excl + loc[i];
        dis[base + i] = rsqrtf((float)(deg[base + i] + 1));
    }
    if (t == 1023) off[NN] = sums[1023];
}

__global__ __launch_bounds__(256) void scatter_kernel(const int* __restrict__ row,
                                                      const int* __restrict__ col,
                                                      const int* __restrict__ off,
                                                      int* __restrict__ cnt,
                                                      int* __restrict__ srow) {
    int e = blockIdx.x * 256 + threadIdx.x;
    if (e < EE) {
        int c = col[e];
        int p = off[c] + atomicAdd(&cnt[c], 1);
        srow[p] = row[e];
    }
}

// ---------------------------------------------------------------------------
// GCN aggregation (gather form). MODE 0: out fp32 = relu(agg+bias).
// MODE 1: t = h1 + relu(agg+bias) + inter[graph]; writes fp32 AND bf16.
template <int MODE>
__global__ __launch_bounds__(256) void agg_kernel(const float* __restrict__ Hw,
                                                  const int* __restrict__ off,
                                                  const int* __restrict__ srow,
                                                  const float* __restrict__ dis,
                                                  const float* __restrict__ bias,
                                                  const float* __restrict__ h1,
                                                  const float* __restrict__ inter,
                                                  float* __restrict__ out,
                                                  unsigned short* __restrict__ outb) {
    int c = blockIdx.x;
    int j = threadIdx.x;
    float dc = dis[c];
    float acc = dc * Hw[(size_t)c * DH_ + j];
    int s = off[c], e = off[c + 1];
    for (int i = s; i < e; ++i) {
        int r = srow[i];
        acc += dis[r] * Hw[(size_t)r * DH_ + j];
    }
    float v = fmaxf(acc * dc + bias[j], 0.f);
    if (MODE == 1) {
        int b = c >> 8;
        v = h1[(size_t)c * DH_ + j] + v + inter[b * DH_ + j];
        outb[(size_t)c * DH_ + j] = f2bf(v);
    }
    out[(size_t)c * DH_ + j] = v;
}

// ---------------------------------------------------------------------------
// bf16 MFMA GEMM: C[M,N] = A[M,K] @ B[K,N], A bf16 row-major, Bt = B^T bf16
// [N,K] row-major. 128x128 tile, 4 waves in 2x2, each wave 4x4 grid of
// 16x16x32 MFMAs. Optional bias/res(fp32)/relu; writes fp32 and/or bf16.
__global__ __launch_bounds__(256) void gemm_bf16_kernel(
    const unsigned short* __restrict__ A,
    const unsigned short* __restrict__ Bt,
    float* __restrict__ Cf,
    unsigned short* __restrict__ Cb,
    int M, int K, int N,
    const float* __restrict__ bias,
    const float* __restrict__ res,
    int do_relu) {
    constexpr int LDP = 40;
    __shared__ unsigned short As[128 * LDP];
    __shared__ unsigned short Bs[128 * LDP];
    int bm = blockIdx.y * 128;
    int bn = blockIdx.x * 128;
    int tid = threadIdx.x;
    int wave = tid >> 6, lane = tid & 63;
    int wm = (wave & 1) * 64, wn = (wave >> 1) * 64;
    int lrc = lane & 15;
    int koct = lane >> 4;

    f32x4 acc[4][4];
#pragma unroll
    for (int i = 0; i < 4; ++i)
#pragma unroll
        for (int j = 0; j < 4; ++j) acc[i][j] = (f32x4){0.f, 0.f, 0.f, 0.f};

    for (int k0 = 0; k0 < K; k0 += 32) {
#pragma unroll
        for (int it = 0; it < 2; ++it) {
            int c = tid + it * 256;
            int row = c >> 2, offk = (c & 3) * 8;
            *(uint4*)(As + row * LDP + offk) =
                *(const uint4*)(A + (size_t)(bm + row) * K + k0 + offk);
            *(uint4*)(Bs + row * LDP + offk) =
                *(const uint4*)(Bt + (size_t)(bn + row) * K + k0 + offk);
        }
        __syncthreads();
        bf16x8 af[4], bfr[4];
#pragma unroll
        for (int i = 0; i < 4; ++i)
            af[i] = *(const bf16x8*)(As + (wm + i * 16 + lrc) * LDP + koct * 8);
#pragma unroll
        for (int j = 0; j < 4; ++j)
            bfr[j] = *(const bf16x8*)(Bs + (wn + j * 16 + lrc) * LDP + koct * 8);
#pragma unroll
        for (int i = 0; i < 4; ++i)
#pragma unroll
            for (int j = 0; j < 4; ++j)
                acc[i][j] = __builtin_amdgcn_mfma_f32_16x16x32_bf16(af[i], bfr[j],
                                                                    acc[i][j], 0, 0, 0);
        __syncthreads();
    }
#pragma unroll
    for (int i = 0; i < 4; ++i) {
#pragma unroll
        for (int r = 0; r < 4; ++r) {
            int grow = bm + wm + i * 16 + koct * 4 + r;
#pragma unroll
            for (int j = 0; j < 4; ++j) {
                int gcol = bn + wn + j * 16 + lrc;
                float v = acc[i][j][r];
                if (bias) v += bias[gcol];
                if (res) v += res[(size_t)grow * N + gcol];
                if (do_relu) v = fmaxf(v, 0.f);
                if (Cf) Cf[(size_t)grow * N + gcol] = v;
                if (Cb) Cb[(size_t)grow * N + gcol] = f2bf(v);
            }
        }
    }
}

// ---------------------------------------------------------------------------
// MFMA flash attention. One block per (graph, head); 4 waves x 64 q-rows.
// QKV: [N, 768] bf16 (Q|K|V concatenated per row). Ob: [N, 256] bf16.
// Per 32-key chunk: S = Q@K^T via mfma (C-layout), online softmax in regs
// (S-acc and O-acc share the row mapping (lane>>4)*4+r), P -> per-wave LDS
// strip (A-layout round-trip, m120 pattern), O += P@V via mfma.
__global__ __launch_bounds__(256) void attn_mfma_kernel(
    const unsigned short* __restrict__ QKV,
    unsigned short* __restrict__ Ob) {
    int b = blockIdx.x >> 3, h = blockIdx.x & 7;
    __shared__ unsigned short Ks[256 * 40];   // [key][hd 32 + pad]
    __shared__ unsigned short Vt[32 * 264];   // [d][key 256 + pad]
    __shared__ unsigned short Ps[4 * 64 * 40];// per-wave [qrow 64][key 32 + pad]
    const unsigned short* kg = QKV + (size_t)b * 256 * 768 + 256 + h * 32;
    const unsigned short* vg = QKV + (size_t)b * 256 * 768 + 512 + h * 32;
    int tid = threadIdx.x;
#pragma unroll
    for (int it = 0; it < 4; ++it) {
        int c = it * 256 + tid;
        int row = c >> 2, q4 = (c & 3) * 8;
        *(uint4*)(Ks + row * 40 + q4) = *(const uint4*)(kg + (size_t)row * 768 + q4);
    }
#pragma unroll
    for (int it = 0; it < 4; ++it) {
        int c = it * 256 + tid;
        int key = c >> 2, d0 = (c & 3) * 8;
        unsigned short tmp[8];
        *(uint4*)tmp = *(const uint4*)(vg + (size_t)key * 768 + d0);
#pragma unroll
        for (int j = 0; j < 8; ++j) Vt[(d0 + j) * 264 + key] = tmp[j];
    }
    __syncthreads();

    int wave = tid >> 6, lane = tid & 63;
    int lr = lane & 15, koct = lane >> 4;
    int qrow0 = b * 256 + wave * 64;
    bf16x8 qf[4];
#pragma unroll
    for (int i = 0; i < 4; ++i)
        qf[i] = *(const bf16x8*)(QKV + (size_t)(qrow0 + i * 16 + lr) * 768 + h * 32 + koct * 8);

    f32x4 Oa[4][2];
    float mrow[4][4], lrow[4][4];
#pragma unroll
    for (int i = 0; i < 4; ++i) {
        Oa[i][0] = (f32x4){0.f, 0.f, 0.f, 0.f};
        Oa[i][1] = (f32x4){0.f, 0.f, 0.f, 0.f};
#pragma unroll
        for (int r = 0; r < 4; ++r) { mrow[i][r] = -1e30f; lrow[i][r] = 0.f; }
    }
    unsigned short* Pw = Ps + wave * (64 * 40);
    const float sc = 0.17677669529663689f;  // 1/sqrt(32)

    for (int kc = 0; kc < 256; kc += 32) {
        bf16x8 kf0 = *(const bf16x8*)(Ks + (kc + lr) * 40 + koct * 8);
        bf16x8 kf1 = *(const bf16x8*)(Ks + (kc + 16 + lr) * 40 + koct * 8);
        f32x4 Sa[4], Sb[4];
#pragma unroll
        for (int i = 0; i < 4; ++i) {
            Sa[i] = __builtin_amdgcn_mfma_f32_16x16x32_bf16(qf[i], kf0,
                        (f32x4){0.f, 0.f, 0.f, 0.f}, 0, 0, 0);
            Sb[i] = __builtin_amdgcn_mfma_f32_16x16x32_bf16(qf[i], kf1,
                        (f32x4){0.f, 0.f, 0.f, 0.f}, 0, 0, 0);
        }
#pragma unroll
        for (int i = 0; i < 4; ++i) {
#pragma unroll
            for (int r = 0; r < 4; ++r) {
                float s0 = Sa[i][r] * sc, s1 = Sb[i][r] * sc;
                float mx = fmaxf(s0, s1);
#pragma unroll
                for (int off = 1; off < 16; off <<= 1) mx = fmaxf(mx, __shfl_xor(mx, off));
                float mn = fmaxf(mrow[i][r], mx);
                float corr = __expf(mrow[i][r] - mn);
                mrow[i][r] = mn;
                float p0 = __expf(s0 - mn), p1 = __expf(s1 - mn);
                float ps = p0 + p1;
#pragma unroll
                for (int off = 1; off < 16; off <<= 1) ps += __shfl_xor(ps, off);
                lrow[i][r] = lrow[i][r] * corr + ps;
                Oa[i][0][r] *= corr;
                Oa[i][1][r] *= corr;
                int prow = i * 16 + koct * 4 + r;
                Pw[prow * 40 + lr] = f2bf(p0);
                Pw[prow * 40 + 16 + lr] = f2bf(p1);
            }
        }
        bf16x8 vf0 = *(const bf16x8*)(Vt + lr * 264 + kc + koct * 8);
        bf16x8 vf1 = *(const bf16x8*)(Vt + (16 + lr) * 264 + kc + koct * 8);
#pragma unroll
        for (int i = 0; i < 4; ++i) {
            bf16x8 pf = *(const bf16x8*)(Pw + (i * 16 + lr) * 40 + koct * 8);
            Oa[i][0] = __builtin_amdgcn_mfma_f32_16x16x32_bf16(pf, vf0, Oa[i][0], 0, 0, 0);
            Oa[i][1] = __builtin_amdgcn_mfma_f32_16x16x32_bf16(pf, vf1, Oa[i][1], 0, 0, 0);
        }
    }
#pragma unroll
    for (int i = 0; i < 4; ++i) {
#pragma unroll
        for (int r = 0; r < 4; ++r) {
            float inv = 1.f / lrow[i][r];
            int row = qrow0 + i * 16 + koct * 4 + r;
#pragma unroll
            for (int jn = 0; jn < 2; ++jn) {
                int col = h * 32 + jn * 16 + lr;
                Ob[(size_t)row * 256 + col] = f2bf(Oa[i][jn][r] * inv);
            }
        }
    }
}

// LayerNorm over last dim (256). One wave per row; in-place safe.
// Optional bf16 secondary output.
__global__ __launch_bounds__(256) void ln_kernel(const float* __restrict__ Z,
                                                 float* __restrict__ Out,
                                                 unsigned short* __restrict__ Outb,
                                                 const float* __restrict__ g,
                                                 const float* __restrict__ bt) {
    int row = blockIdx.x * 4 + (threadIdx.x >> 6);
    int lane = threadIdx.x & 63;
    const float* z = Z + (size_t)row * DH_;
    float v[4];
    float sum = 0.f;
#pragma unroll
    for (int i = 0; i < 4; ++i) { v[i] = z[lane + i * 64]; sum += v[i]; }
#pragma unroll
    for (int off = 32; off; off >>= 1) sum += __shfl_xor(sum, off);
    float mu = sum * (1.f / (float)DH_);
    float vs = 0.f;
#pragma unroll
    for (int i = 0; i < 4; ++i) { float d = v[i] - mu; vs += d * d; }
#pragma unroll
    for (int off = 32; off; off >>= 1) vs += __shfl_xor(vs, off);
    float rs = rsqrtf(vs * (1.f / (float)DH_) + EPS_);
#pragma unroll
    for (int i = 0; i < 4; ++i) {
        int col = lane + i * 64;
        float y = (v[i] - mu) * rs * g[col] + bt[col];
        Out[(size_t)row * DH_ + col] = y;
        if (Outb) Outb[(size_t)row * DH_ + col] = f2bf(y);
    }
}

// Readout: per-graph column sum of t3.
__global__ __launch_bounds__(256) void readout_kernel(const float* __restrict__ T3,
                                                      float* __restrict__ out) {
    int b = blockIdx.x, j = threadIdx.x;
    float s = 0.f;
    for (int r = 0; r < SG; ++r) s += T3[(size_t)(b * SG + r) * DH_ + j];
    out[b * DH_ + j] = s;
}

// ---------------------------------------------------------------------------
extern "C" void kernel_launch(void* const* d_in, const int* in_sizes, int n_in,
                              void* d_out, int out_size, void* d_ws, size_t ws_size,
                              hipStream_t stream) {
    const float* x       = (const float*)d_in[0];
    const int*   ei      = (const int*)d_in[1];
    const float* inter_f = (const float*)d_in[3];
    const float* bn1_g = (const float*)d_in[4],  *bn1_b = (const float*)d_in[5];
    const float* bn2_g = (const float*)d_in[6],  *bn2_b = (const float*)d_in[7];
    const float* w_conv1 = (const float*)d_in[8],  *b_conv1 = (const float*)d_in[9];
    const float* w_conv2 = (const float*)d_in[10], *b_conv2 = (const float*)d_in[11];
    const float* wq = (const float*)d_in[12], *bq = (const float*)d_in[13];
    const float* wk = (const float*)d_in[14], *bk = (const float*)d_in[15];
    const float* wv = (const float*)d_in[16], *bv = (const float*)d_in[17];
    const float* wo = (const float*)d_in[18], *bo = (const float*)d_in[19];
    const float* ln1_g = (const float*)d_in[20], *ln1_b = (const float*)d_in[21];
    const float* ln2_g = (const float*)d_in[22], *ln2_b = (const float*)d_in[23];
    const float* w_ff1 = (const float*)d_in[24], *b_ff1 = (const float*)d_in[25];
    const float* w_ff2 = (const float*)d_in[26], *b_ff2 = (const float*)d_in[27];
    float* out = (float*)d_out;

    char* base = (char*)d_ws;
    size_t o = 0;
    auto alloc = [&](size_t bytes) -> void* {
        void* p = base + o;
        o = (o + bytes + 255) & ~(size_t)255;
        return p;
    };
    int*   deg    = (int*)alloc(NN * 4);
    int*   off    = (int*)alloc((NN + 1) * 4);
    int*   cnt    = (int*)alloc(NN * 4);
    int*   srow   = (int*)alloc(EE * 4);
    float* dis    = (float*)alloc(NN * 4);
    float* csum   = (float*)alloc(256 * 4);
    float* csumsq = (float*)alloc(256 * 4);
    float* scl    = (float*)alloc(256 * 4);
    float* shf    = (float*)alloc(256 * 4);
    float* bqkv   = (float*)alloc(768 * 4);
    const size_t SLOT = (size_t)NN * DH_;            // 8M floats = 32 MB
    float* S0 = (float*)alloc(SLOT * 4);             // Hw ; later QKVb/Fb alias
    float* S1 = (float*)alloc(SLOT * 4);             // h1 ; later QKVb/Fb alias
    float* S2 = (float*)alloc(SLOT * 4);             // z2/t3
    float* S3 = (float*)alloc(SLOT * 4);             // t
    float* S4 = (float*)alloc(SLOT * 4);             // z -> t2
    unsigned short* B0 = (unsigned short*)alloc(SLOT * 2);  // Xb/X2b/tb/Ob/t2b
    unsigned short* wc1t  = (unsigned short*)alloc((size_t)DIN_ * DH_ * 2);
    unsigned short* wc2t  = (unsigned short*)alloc((size_t)DH_ * DH_ * 2);
    unsigned short* wqkvt = (unsigned short*)alloc((size_t)DH_ * DH_ * 3 * 2);
    unsigned short* wot   = (unsigned short*)alloc((size_t)DH_ * DH_ * 2);
    unsigned short* wf1t  = (unsigned short*)alloc((size_t)DH_ * DFF_ * 2);
    unsigned short* wf2t  = (unsigned short*)alloc((size_t)DFF_ * DH_ * 2);
    unsigned short* QKVb = (unsigned short*)S0;      // 48 MB over S0+S1 (dead then)
    unsigned short* Fb   = (unsigned short*)S0;      // 64 MB over S0+S1 (after attn)

    hipMemsetAsync(deg, 0, NN * 4, stream);
    hipMemsetAsync(cnt, 0, NN * 4, stream);
    hipMemsetAsync(csum, 0, 2048, stream);

    // Weight transposes (bf16) + QKV bias concat
    wtrans_kernel<<<(DIN_ * DH_ + 255) / 256, 256, 0, stream>>>(w_conv1, wc1t, DIN_, DH_);
    wtrans_kernel<<<(DH_ * DH_ + 255) / 256, 256, 0, stream>>>(w_conv2, wc2t, DH_, DH_);
    wtrans_kernel<<<(DH_ * DH_ + 255) / 256, 256, 0, stream>>>(wq, wqkvt, DH_, DH_);
    wtrans_kernel<<<(DH_ * DH_ + 255) / 256, 256, 0, stream>>>(wk, wqkvt + DH_ * DH_, DH_, DH_);
    wtrans_kernel<<<(DH_ * DH_ + 255) / 256, 256, 0, stream>>>(wv, wqkvt + 2 * DH_ * DH_, DH_, DH_);
    wtrans_kernel<<<(DH_ * DH_ + 255) / 256, 256, 0, stream>>>(wo, wot, DH_, DH_);
    wtrans_kernel<<<(DH_ * DFF_ + 255) / 256, 256, 0, stream>>>(w_ff1, wf1t, DH_, DFF_);
    wtrans_kernel<<<(DFF_ * DH_ + 255) / 256, 256, 0, stream>>>(w_ff2, wf2t, DFF_, DH_);
    bcat_kernel<<<3, 256, 0, stream>>>(bq, bk, bv, bqkv);

    // init_avg_h -> out[B*DH ...]
    initavg_kernel<<<BG, 128, 0, stream>>>(x, out + BG * DH_);

    // BN1 -> Xb bf16 (B0)
    colstats_kernel<DIN_><<<NN / 256, DIN_, 0, stream>>>(x, csum, csumsq);
    bnfin_kernel<DIN_><<<1, DIN_, 0, stream>>>(csum, csumsq, bn1_g, bn1_b, scl, shf);
    bnapply_kernel<DIN_><<<NN * DIN_ / 256, 256, 0, stream>>>(x, scl, shf, B0);

    // CSR build
    deg_kernel<<<EE / 256, 256, 0, stream>>>(ei + EE, deg);
    scan_kernel<<<1, 1024, 0, stream>>>(deg, off, dis);
    scatter_kernel<<<EE / 256, 256, 0, stream>>>(ei, ei + EE, off, cnt, srow);

    // conv1: Hw = Xb @ w_conv1 -> S0 ; h1 = relu(agg + b) -> S1
    gemm_bf16_kernel<<<dim3(DH_ / 128, NN / 128), 256, 0, stream>>>(
        B0, wc1t, S0, nullptr, NN, DIN_, DH_, nullptr, nullptr, 0);
    agg_kernel<0><<<NN, 256, 0, stream>>>(S0, off, srow, dis, b_conv1, nullptr, nullptr,
                                          S1, nullptr);

    // BN2 -> X2b bf16 (B0)
    hipMemsetAsync(csum, 0, 2048, stream);
    colstats_kernel<DH_><<<NN / 256, DH_, 0, stream>>>(S1, csum, csumsq);
    bnfin_kernel<DH_><<<1, DH_, 0, stream>>>(csum, csumsq, bn2_g, bn2_b, scl, shf);
    bnapply_kernel<DH_><<<NN * DH_ / 256, 256, 0, stream>>>(S1, scl, shf, B0);

    // conv2: Hw = X2b @ w_conv2 -> S0 ; t = h1 + relu(agg+b) + inter -> S3 + B0(bf16)
    gemm_bf16_kernel<<<dim3(DH_ / 128, NN / 128), 256, 0, stream>>>(
        B0, wc2t, S0, nullptr, NN, DH_, DH_, nullptr, nullptr, 0);
    agg_kernel<1><<<NN, 256, 0, stream>>>(S0, off, srow, dis, b_conv2, S1, inter_f,
                                          S3, B0);

    // Fused QKV projection: QKVb = tb @ [wq|wk|wv] + [bq|bk|bv]  (bf16 out)
    // (S0/S1 fp32 contents are dead here; QKVb aliases them.)
    gemm_bf16_kernel<<<dim3(768 / 128, NN / 128), 256, 0, stream>>>(
        B0, wqkvt, nullptr, QKVb, NN, DH_, 768, bqkv, nullptr, 0);

    // MFMA flash attention -> Ob bf16 (B0; tb dead after QKV gemm)
    attn_mfma_kernel<<<BG * NH, 256, 0, stream>>>(QKVb, B0);

    // z = Ob @ wo + bo + t -> S4 ; t2 = LN(z) -> S4 (+bf16 B0)
    gemm_bf16_kernel<<<dim3(DH_ / 128, NN / 128), 256, 0, stream>>>(
        B0, wot, S4, nullptr, NN, DH_, DH_, bo, S3, 0);
    ln_kernel<<<NN / 4, 256, 0, stream>>>(S4, S4, B0, ln1_g, ln1_b);

    // FFN: F = relu(t2 @ w_ff1 + b1) -> Fb (bf16, over S0+S1; QKVb dead) ;
    //      z2 = F @ w_ff2 + b2 + t2 -> S2
    gemm_bf16_kernel<<<dim3(DFF_ / 128, NN / 128), 256, 0, stream>>>(
        B0, wf1t, nullptr, Fb, NN, DH_, DFF_, b_ff1, nullptr, 1);
    gemm_bf16_kernel<<<dim3(DH_ / 128, NN / 128), 256, 0, stream>>>(
        Fb, wf2t, S2, nullptr, NN, DFF_, DH_, b_ff2, S4, 0);

    // t3 = LN(z2) in-place ; readout -> out[0 .. B*DH)
    ln_kernel<<<NN / 4, 256, 0, stream>>>(S2, S2, nullptr, ln2_g, ln2_b);
    readout_kernel<<<BG, 256, 0, stream>>>(S2, out);
}

// Round 4
// 832.120 us; speedup vs baseline: 1.9920x; 1.0739x over previous
//
#include <hip/hip_runtime.h>
#include <math.h>

// Problem constants (fixed by the reference)
#define NN   32768
#define BG   128
#define SG   256
#define EE   524288
#define DIN_ 128
#define DH_  256
#define NH   8
#define HD_  32
#define DFF_ 1024
#define EPS_ 1e-5f

typedef __attribute__((ext_vector_type(8))) short bf16x8;
typedef __attribute__((ext_vector_type(4))) float f32x4;

__device__ __forceinline__ unsigned short f2bf(float f) {
    unsigned int u = __builtin_bit_cast(unsigned int, f);
    unsigned int r = u + 0x7FFFu + ((u >> 16) & 1u);
    return (unsigned short)(r >> 16);
}
__device__ __forceinline__ float bf2f(unsigned short u) {
    return __builtin_bit_cast(float, (unsigned int)u << 16);
}

// ---------------------------------------------------------------------------
// init_avg_h: per-graph mean of raw x (graph b = rows [b*256, b*256+256)).
__global__ __launch_bounds__(128) void initavg_kernel(const float* __restrict__ X,
                                                      float* __restrict__ out2) {
    int b = blockIdx.x, j = threadIdx.x;
    float s = 0.f;
    for (int r = 0; r < SG; ++r) s += X[(size_t)(b * SG + r) * DIN_ + j];
    out2[b * DIN_ + j] = s * (1.f / (float)SG);
}

// Column sum / sumsq partials for BatchNorm stats (axis 0 over all N rows).
template <int C>
__global__ __launch_bounds__(C) void colstats_kernel(const float* __restrict__ X,
                                                     float* __restrict__ csum,
                                                     float* __restrict__ csumsq) {
    int j = threadIdx.x;
    size_t r0 = (size_t)blockIdx.x * 256;
    float s = 0.f, sq = 0.f;
    for (int r = 0; r < 256; ++r) {
        float v = X[(r0 + r) * C + j];
        s += v; sq += v * v;
    }
    atomicAdd(&csum[j], s);
    atomicAdd(&csumsq[j], sq);
}

template <int C>
__global__ __launch_bounds__(C) void bnfin_kernel(const float* __restrict__ csum,
                                                  const float* __restrict__ csumsq,
                                                  const float* __restrict__ g,
                                                  const float* __restrict__ b,
                                                  float* __restrict__ scale,
                                                  float* __restrict__ shift) {
    int j = threadIdx.x;
    float mu  = csum[j] * (1.f / (float)NN);
    float var = csumsq[j] * (1.f / (float)NN) - mu * mu;
    float s = g[j] * rsqrtf(var + EPS_);
    scale[j] = s;
    shift[j] = b[j] - mu * s;
}

// BN apply, bf16 output (feeds aggregation / MFMA GEMM A operand).
template <int C>
__global__ __launch_bounds__(256) void bnapply_kernel(const float* __restrict__ X,
                                                      const float* __restrict__ sc,
                                                      const float* __restrict__ sh,
                                                      unsigned short* __restrict__ Y) {
    int i = blockIdx.x * 256 + threadIdx.x;
    int j = i & (C - 1);
    Y[i] = f2bf(X[i] * sc[j] + sh[j]);
}

// Weight cast+transpose: W[K,N] fp32 -> Wt[N,K] bf16. Coalesced writes.
__global__ __launch_bounds__(256) void wtrans_kernel(const float* __restrict__ W,
                                                     unsigned short* __restrict__ Wt,
                                                     int K, int N) {
    int idx = blockIdx.x * 256 + threadIdx.x;
    if (idx < K * N) {
        int n = idx / K, k = idx - n * K;
        Wt[idx] = f2bf(W[(size_t)k * N + n]);
    }
}

// Concat Q/K/V biases into one fp32[768].
__global__ __launch_bounds__(256) void bcat_kernel(const float* __restrict__ bq,
                                                   const float* __restrict__ bk,
                                                   const float* __restrict__ bv,
                                                   float* __restrict__ o) {
    int j = threadIdx.x;
    if (blockIdx.x == 0) o[j] = bq[j];
    else if (blockIdx.x == 1) o[DH_ + j] = bk[j];
    else o[2 * DH_ + j] = bv[j];
}

// ---------------------------------------------------------------------------
// CSR build
__global__ __launch_bounds__(256) void deg_kernel(const int* __restrict__ col,
                                                  int* __restrict__ deg) {
    int e = blockIdx.x * 256 + threadIdx.x;
    if (e < EE) atomicAdd(&deg[col[e]], 1);
}

__global__ __launch_bounds__(1024) void scan_kernel(const int* __restrict__ deg,
                                                    int* __restrict__ off,
                                                    float* __restrict__ dis) {
    __shared__ int sums[1024];
    int t = threadIdx.x;
    int base = t * 32;
    int loc[32];
    int run = 0;
#pragma unroll
    for (int i = 0; i < 32; ++i) { loc[i] = run; run += deg[base + i]; }
    sums[t] = run;
    __syncthreads();
    for (int d = 1; d < 1024; d <<= 1) {
        int tmp = (t >= d) ? sums[t - d] : 0;
        __syncthreads();
        sums[t] += tmp;
        __syncthreads();
    }
    int excl = sums[t] - run;
#pragma unroll
    for (int i = 0; i < 32; ++i) {
        off[base + i] = excl + loc[i];
        dis[base + i] = rsqrtf((float)(deg[base + i] + 1));
    }
    if (t == 1023) off[NN] = sums[1023];
}

__global__ __launch_bounds__(256) void scatter_kernel(const int* __restrict__ row,
                                                      const int* __restrict__ col,
                                                      const int* __restrict__ off,
                                                      int* __restrict__ cnt,
                                                      int* __restrict__ srow) {
    int e = blockIdx.x * 256 + threadIdx.x;
    if (e < EE) {
        int c = col[e];
        int p = off[c] + atomicAdd(&cnt[c], 1);
        srow[p] = row[e];
    }
}

// ---------------------------------------------------------------------------
// Pure bf16 GCN aggregation: Y[c,:] = dc*(sum_e dis[r]*X[r,:] + dc*X[c,:]).
// One 64-lane group per node (4 nodes/block); EPL bf16 per lane, fp32 acc.
template <int C>
__global__ __launch_bounds__(256) void aggb_kernel(const unsigned short* __restrict__ X,
                                                   const int* __restrict__ off,
                                                   const int* __restrict__ srow,
                                                   const float* __restrict__ dis,
                                                   unsigned short* __restrict__ Y) {
    constexpr int EPL = C / 64;  // 2 (C=128) or 4 (C=256)
    int lane = threadIdx.x & 63;
    int c = blockIdx.x * 4 + (threadIdx.x >> 6);
    float dc = dis[c];
    float acc[EPL];
    {
        unsigned short t[EPL];
        const unsigned short* xc = X + (size_t)c * C + lane * EPL;
        if constexpr (EPL == 4) *(uint2*)t = *(const uint2*)xc;
        else *(unsigned int*)t = *(const unsigned int*)xc;
#pragma unroll
        for (int e2 = 0; e2 < EPL; ++e2) acc[e2] = dc * bf2f(t[e2]);
    }
    int s = off[c], en = off[c + 1];
    for (int i = s; i < en; ++i) {
        int r = srow[i];
        float dr = dis[r];
        unsigned short t[EPL];
        const unsigned short* xr = X + (size_t)r * C + lane * EPL;
        if constexpr (EPL == 4) *(uint2*)t = *(const uint2*)xr;
        else *(unsigned int*)t = *(const unsigned int*)xr;
#pragma unroll
        for (int e2 = 0; e2 < EPL; ++e2) acc[e2] += dr * bf2f(t[e2]);
    }
    unsigned short t[EPL];
#pragma unroll
    for (int e2 = 0; e2 < EPL; ++e2) t[e2] = f2bf(acc[e2] * dc);
    unsigned short* yc = Y + (size_t)c * C + lane * EPL;
    if constexpr (EPL == 4) *(uint2*)yc = *(const uint2*)t;
    else *(unsigned int*)yc = *(const unsigned int*)t;
}

// ---------------------------------------------------------------------------
// bf16 MFMA GEMM: C[M,N] = A[M,K] @ B[K,N], A bf16 row-major, Bt = B^T bf16
// [N,K] row-major. 128x128 tile, 4 waves 2x2, each wave 4x4 16x16x32 MFMAs.
// Epilogue: +bias; if relu_first: relu now; +res (fp32); +inter[row>>8] (fp32,
// per-graph); if do_relu && !relu_first: relu. Writes fp32 and/or bf16.
__global__ __launch_bounds__(256) void gemm_bf16_kernel(
    const unsigned short* __restrict__ A,
    const unsigned short* __restrict__ Bt,
    float* __restrict__ Cf,
    unsigned short* __restrict__ Cb,
    int M, int K, int N,
    const float* __restrict__ bias,
    const float* __restrict__ res,
    const float* __restrict__ inter,
    int do_relu, int relu_first) {
    constexpr int LDP = 40;
    __shared__ unsigned short As[128 * LDP];
    __shared__ unsigned short Bs[128 * LDP];
    int bm = blockIdx.y * 128;
    int bn = blockIdx.x * 128;
    int tid = threadIdx.x;
    int wave = tid >> 6, lane = tid & 63;
    int wm = (wave & 1) * 64, wn = (wave >> 1) * 64;
    int lrc = lane & 15;
    int koct = lane >> 4;

    f32x4 acc[4][4];
#pragma unroll
    for (int i = 0; i < 4; ++i)
#pragma unroll
        for (int j = 0; j < 4; ++j) acc[i][j] = (f32x4){0.f, 0.f, 0.f, 0.f};

    for (int k0 = 0; k0 < K; k0 += 32) {
#pragma unroll
        for (int it = 0; it < 2; ++it) {
            int c = tid + it * 256;
            int row = c >> 2, offk = (c & 3) * 8;
            *(uint4*)(As + row * LDP + offk) =
                *(const uint4*)(A + (size_t)(bm + row) * K + k0 + offk);
            *(uint4*)(Bs + row * LDP + offk) =
                *(const uint4*)(Bt + (size_t)(bn + row) * K + k0 + offk);
        }
        __syncthreads();
        bf16x8 af[4], bfr[4];
#pragma unroll
        for (int i = 0; i < 4; ++i)
            af[i] = *(const bf16x8*)(As + (wm + i * 16 + lrc) * LDP + koct * 8);
#pragma unroll
        for (int j = 0; j < 4; ++j)
            bfr[j] = *(const bf16x8*)(Bs + (wn + j * 16 + lrc) * LDP + koct * 8);
#pragma unroll
        for (int i = 0; i < 4; ++i)
#pragma unroll
            for (int j = 0; j < 4; ++j)
                acc[i][j] = __builtin_amdgcn_mfma_f32_16x16x32_bf16(af[i], bfr[j],
                                                                    acc[i][j], 0, 0, 0);
        __syncthreads();
    }
#pragma unroll
    for (int i = 0; i < 4; ++i) {
#pragma unroll
        for (int r = 0; r < 4; ++r) {
            int grow = bm + wm + i * 16 + koct * 4 + r;
#pragma unroll
            for (int j = 0; j < 4; ++j) {
                int gcol = bn + wn + j * 16 + lrc;
                float v = acc[i][j][r];
                if (bias) v += bias[gcol];
                if (relu_first) v = fmaxf(v, 0.f);
                if (res) v += res[(size_t)grow * N + gcol];
                if (inter) v += inter[(grow >> 8) * N + gcol];
                if (do_relu && !relu_first) v = fmaxf(v, 0.f);
                if (Cf) Cf[(size_t)grow * N + gcol] = v;
                if (Cb) Cb[(size_t)grow * N + gcol] = f2bf(v);
            }
        }
    }
}

// ---------------------------------------------------------------------------
// MFMA flash attention (m120 pattern). One block per (graph, head).
__global__ __launch_bounds__(256) void attn_mfma_kernel(
    const unsigned short* __restrict__ QKV,
    unsigned short* __restrict__ Ob) {
    int b = blockIdx.x >> 3, h = blockIdx.x & 7;
    __shared__ unsigned short Ks[256 * 40];
    __shared__ unsigned short Vt[32 * 264];
    __shared__ unsigned short Ps[4 * 64 * 40];
    const unsigned short* kg = QKV + (size_t)b * 256 * 768 + 256 + h * 32;
    const unsigned short* vg = QKV + (size_t)b * 256 * 768 + 512 + h * 32;
    int tid = threadIdx.x;
#pragma unroll
    for (int it = 0; it < 4; ++it) {
        int c = it * 256 + tid;
        int row = c >> 2, q4 = (c & 3) * 8;
        *(uint4*)(Ks + row * 40 + q4) = *(const uint4*)(kg + (size_t)row * 768 + q4);
    }
#pragma unroll
    for (int it = 0; it < 4; ++it) {
        int c = it * 256 + tid;
        int key = c >> 2, d0 = (c & 3) * 8;
        unsigned short tmp[8];
        *(uint4*)tmp = *(const uint4*)(vg + (size_t)key * 768 + d0);
#pragma unroll
        for (int j = 0; j < 8; ++j) Vt[(d0 + j) * 264 + key] = tmp[j];
    }
    __syncthreads();

    int wave = tid >> 6, lane = tid & 63;
    int lr = lane & 15, koct = lane >> 4;
    int qrow0 = b * 256 + wave * 64;
    bf16x8 qf[4];
#pragma unroll
    for (int i = 0; i < 4; ++i)
        qf[i] = *(const bf16x8*)(QKV + (size_t)(qrow0 + i * 16 + lr) * 768 + h * 32 + koct * 8);

    f32x4 Oa[4][2];
    float mrow[4][4], lrow[4][4];
#pragma unroll
    for (int i = 0; i < 4; ++i) {
        Oa[i][0] = (f32x4){0.f, 0.f, 0.f, 0.f};
        Oa[i][1] = (f32x4){0.f, 0.f, 0.f, 0.f};
#pragma unroll
        for (int r = 0; r < 4; ++r) { mrow[i][r] = -1e30f; lrow[i][r] = 0.f; }
    }
    unsigned short* Pw = Ps + wave * (64 * 40);
    const float sc = 0.17677669529663689f;

    for (int kc = 0; kc < 256; kc += 32) {
        bf16x8 kf0 = *(const bf16x8*)(Ks + (kc + lr) * 40 + koct * 8);
        bf16x8 kf1 = *(const bf16x8*)(Ks + (kc + 16 + lr) * 40 + koct * 8);
        f32x4 Sa[4], Sb[4];
#pragma unroll
        for (int i = 0; i < 4; ++i) {
            Sa[i] = __builtin_amdgcn_mfma_f32_16x16x32_bf16(qf[i], kf0,
                        (f32x4){0.f, 0.f, 0.f, 0.f}, 0, 0, 0);
            Sb[i] = __builtin_amdgcn_mfma_f32_16x16x32_bf16(qf[i], kf1,
                        (f32x4){0.f, 0.f, 0.f, 0.f}, 0, 0, 0);
        }
#pragma unroll
        for (int i = 0; i < 4; ++i) {
#pragma unroll
            for (int r = 0; r < 4; ++r) {
                float s0 = Sa[i][r] * sc, s1 = Sb[i][r] * sc;
                float mx = fmaxf(s0, s1);
#pragma unroll
                for (int off = 1; off < 16; off <<= 1) mx = fmaxf(mx, __shfl_xor(mx, off));
                float mn = fmaxf(mrow[i][r], mx);
                float corr = __expf(mrow[i][r] - mn);
                mrow[i][r] = mn;
                float p0 = __expf(s0 - mn), p1 = __expf(s1 - mn);
                float ps = p0 + p1;
#pragma unroll
                for (int off = 1; off < 16; off <<= 1) ps += __shfl_xor(ps, off);
                lrow[i][r] = lrow[i][r] * corr + ps;
                Oa[i][0][r] *= corr;
                Oa[i][1][r] *= corr;
                int prow = i * 16 + koct * 4 + r;
                Pw[prow * 40 + lr] = f2bf(p0);
                Pw[prow * 40 + 16 + lr] = f2bf(p1);
            }
        }
        bf16x8 vf0 = *(const bf16x8*)(Vt + lr * 264 + kc + koct * 8);
        bf16x8 vf1 = *(const bf16x8*)(Vt + (16 + lr) * 264 + kc + koct * 8);
#pragma unroll
        for (int i = 0; i < 4; ++i) {
            bf16x8 pf = *(const bf16x8*)(Pw + (i * 16 + lr) * 40 + koct * 8);
            Oa[i][0] = __builtin_amdgcn_mfma_f32_16x16x32_bf16(pf, vf0, Oa[i][0], 0, 0, 0);
            Oa[i][1] = __builtin_amdgcn_mfma_f32_16x16x32_bf16(pf, vf1, Oa[i][1], 0, 0, 0);
        }
    }
#pragma unroll
    for (int i = 0; i < 4; ++i) {
#pragma unroll
        for (int r = 0; r < 4; ++r) {
            float inv = 1.f / lrow[i][r];
            int row = qrow0 + i * 16 + koct * 4 + r;
#pragma unroll
            for (int jn = 0; jn < 2; ++jn) {
                int col = h * 32 + jn * 16 + lr;
                Ob[(size_t)row * 256 + col] = f2bf(Oa[i][jn][r] * inv);
            }
        }
    }
}

// LayerNorm over last dim (256). One wave per row; in-place safe.
__global__ __launch_bounds__(256) void ln_kernel(const float* __restrict__ Z,
                                                 float* __restrict__ Out,
                                                 unsigned short* __restrict__ Outb,
                                                 const float* __restrict__ g,
                                                 const float* __restrict__ bt) {
    int row = blockIdx.x * 4 + (threadIdx.x >> 6);
    int lane = threadIdx.x & 63;
    const float* z = Z + (size_t)row * DH_;
    float v[4];
    float sum = 0.f;
#pragma unroll
    for (int i = 0; i < 4; ++i) { v[i] = z[lane + i * 64]; sum += v[i]; }
#pragma unroll
    for (int off = 32; off; off >>= 1) sum += __shfl_xor(sum, off);
    float mu = sum * (1.f / (float)DH_);
    float vs = 0.f;
#pragma unroll
    for (int i = 0; i < 4; ++i) { float d = v[i] - mu; vs += d * d; }
#pragma unroll
    for (int off = 32; off; off >>= 1) vs += __shfl_xor(vs, off);
    float rs = rsqrtf(vs * (1.f / (float)DH_) + EPS_);
#pragma unroll
    for (int i = 0; i < 4; ++i) {
        int col = lane + i * 64;
        float y = (v[i] - mu) * rs * g[col] + bt[col];
        Out[(size_t)row * DH_ + col] = y;
        if (Outb) Outb[(size_t)row * DH_ + col] = f2bf(y);
    }
}

// Readout: per-graph column sum of t3.
__global__ __launch_bounds__(256) void readout_kernel(const float* __restrict__ T3,
                                                      float* __restrict__ out) {
    int b = blockIdx.x, j = threadIdx.x;
    float s = 0.f;
    for (int r = 0; r < SG; ++r) s += T3[(size_t)(b * SG + r) * DH_ + j];
    out[b * DH_ + j] = s;
}

// ---------------------------------------------------------------------------
extern "C" void kernel_launch(void* const* d_in, const int* in_sizes, int n_in,
                              void* d_out, int out_size, void* d_ws, size_t ws_size,
                              hipStream_t stream) {
    const float* x       = (const float*)d_in[0];
    const int*   ei      = (const int*)d_in[1];
    const float* inter_f = (const float*)d_in[3];
    const float* bn1_g = (const float*)d_in[4],  *bn1_b = (const float*)d_in[5];
    const float* bn2_g = (const float*)d_in[6],  *bn2_b = (const float*)d_in[7];
    const float* w_conv1 = (const float*)d_in[8],  *b_conv1 = (const float*)d_in[9];
    const float* w_conv2 = (const float*)d_in[10], *b_conv2 = (const float*)d_in[11];
    const float* wq = (const float*)d_in[12], *bq = (const float*)d_in[13];
    const float* wk = (const float*)d_in[14], *bk = (const float*)d_in[15];
    const float* wv = (const float*)d_in[16], *bv = (const float*)d_in[17];
    const float* wo = (const float*)d_in[18], *bo = (const float*)d_in[19];
    const float* ln1_g = (const float*)d_in[20], *ln1_b = (const float*)d_in[21];
    const float* ln2_g = (const float*)d_in[22], *ln2_b = (const float*)d_in[23];
    const float* w_ff1 = (const float*)d_in[24], *b_ff1 = (const float*)d_in[25];
    const float* w_ff2 = (const float*)d_in[26], *b_ff2 = (const float*)d_in[27];
    float* out = (float*)d_out;

    char* base = (char*)d_ws;
    size_t o = 0;
    auto alloc = [&](size_t bytes) -> void* {
        void* p = base + o;
        o = (o + bytes + 255) & ~(size_t)255;
        return p;
    };
    int*   deg    = (int*)alloc(NN * 4);
    int*   off    = (int*)alloc((NN + 1) * 4);
    int*   cnt    = (int*)alloc(NN * 4);
    int*   srow   = (int*)alloc(EE * 4);
    float* dis    = (float*)alloc(NN * 4);
    float* csum   = (float*)alloc(256 * 4);
    float* csumsq = (float*)alloc(256 * 4);
    float* scl    = (float*)alloc(256 * 4);
    float* shf    = (float*)alloc(256 * 4);
    float* bqkv   = (float*)alloc(768 * 4);
    const size_t SLOT = (size_t)NN * DH_;            // 8M floats = 32 MB
    float* S0 = (float*)alloc(SLOT * 4);             // Xa/X2a ; QKVb/Fb alias
    float* S1 = (float*)alloc(SLOT * 4);             // h1 ; QKVb/Fb alias
    float* S2 = (float*)alloc(SLOT * 4);             // z2/t3
    float* S3 = (float*)alloc(SLOT * 4);             // t
    float* S4 = (float*)alloc(SLOT * 4);             // z -> t2
    unsigned short* B0 = (unsigned short*)alloc(SLOT * 2);  // Xb/X2b/tb/Ob/t2b
    unsigned short* wc1t  = (unsigned short*)alloc((size_t)DIN_ * DH_ * 2);
    unsigned short* wc2t  = (unsigned short*)alloc((size_t)DH_ * DH_ * 2);
    unsigned short* wqkvt = (unsigned short*)alloc((size_t)DH_ * DH_ * 3 * 2);
    unsigned short* wot   = (unsigned short*)alloc((size_t)DH_ * DH_ * 2);
    unsigned short* wf1t  = (unsigned short*)alloc((size_t)DH_ * DFF_ * 2);
    unsigned short* wf2t  = (unsigned short*)alloc((size_t)DFF_ * DH_ * 2);
    unsigned short* Xa   = (unsigned short*)S0;      // agg outputs (dead after GEMM)
    unsigned short* QKVb = (unsigned short*)S0;      // 48 MB over S0+S1
    unsigned short* Fb   = (unsigned short*)S0;      // 64 MB over S0+S1

    hipMemsetAsync(deg, 0, NN * 4, stream);
    hipMemsetAsync(cnt, 0, NN * 4, stream);
    hipMemsetAsync(csum, 0, 2048, stream);

    // Weight transposes (bf16) + QKV bias concat
    wtrans_kernel<<<(DIN_ * DH_ + 255) / 256, 256, 0, stream>>>(w_conv1, wc1t, DIN_, DH_);
    wtrans_kernel<<<(DH_ * DH_ + 255) / 256, 256, 0, stream>>>(w_conv2, wc2t, DH_, DH_);
    wtrans_kernel<<<(DH_ * DH_ + 255) / 256, 256, 0, stream>>>(wq, wqkvt, DH_, DH_);
    wtrans_kernel<<<(DH_ * DH_ + 255) / 256, 256, 0, stream>>>(wk, wqkvt + DH_ * DH_, DH_, DH_);
    wtrans_kernel<<<(DH_ * DH_ + 255) / 256, 256, 0, stream>>>(wv, wqkvt + 2 * DH_ * DH_, DH_, DH_);
    wtrans_kernel<<<(DH_ * DH_ + 255) / 256, 256, 0, stream>>>(wo, wot, DH_, DH_);
    wtrans_kernel<<<(DH_ * DFF_ + 255) / 256, 256, 0, stream>>>(w_ff1, wf1t, DH_, DFF_);
    wtrans_kernel<<<(DFF_ * DH_ + 255) / 256, 256, 0, stream>>>(w_ff2, wf2t, DFF_, DH_);
    bcat_kernel<<<3, 256, 0, stream>>>(bq, bk, bv, bqkv);

    // init_avg_h -> out[B*DH ...]
    initavg_kernel<<<BG, 128, 0, stream>>>(x, out + BG * DH_);

    // BN1 -> Xb bf16 (B0)
    colstats_kernel<DIN_><<<NN / 256, DIN_, 0, stream>>>(x, csum, csumsq);
    bnfin_kernel<DIN_><<<1, DIN_, 0, stream>>>(csum, csumsq, bn1_g, bn1_b, scl, shf);
    bnapply_kernel<DIN_><<<NN * DIN_ / 256, 256, 0, stream>>>(x, scl, shf, B0);

    // CSR build
    deg_kernel<<<EE / 256, 256, 0, stream>>>(ei + EE, deg);
    scan_kernel<<<1, 1024, 0, stream>>>(deg, off, dis);
    scatter_kernel<<<EE / 256, 256, 0, stream>>>(ei, ei + EE, off, cnt, srow);

    // agg1 on input side (A·X)·W == A·(X·W): Xa = Anorm @ Xb  (bf16, 128 cols)
    aggb_kernel<DIN_><<<NN / 4, 256, 0, stream>>>(B0, off, srow, dis, Xa);
    // conv1: h1 = relu(Xa @ w_conv1 + b) -> S1 fp32
    gemm_bf16_kernel<<<dim3(DH_ / 128, NN / 128), 256, 0, stream>>>(
        Xa, wc1t, S1, nullptr, NN, DIN_, DH_, b_conv1, nullptr, nullptr, 1, 0);

    // BN2 -> X2b bf16 (B0)
    hipMemsetAsync(csum, 0, 2048, stream);
    colstats_kernel<DH_><<<NN / 256, DH_, 0, stream>>>(S1, csum, csumsq);
    bnfin_kernel<DH_><<<1, DH_, 0, stream>>>(csum, csumsq, bn2_g, bn2_b, scl, shf);
    bnapply_kernel<DH_><<<NN * DH_ / 256, 256, 0, stream>>>(S1, scl, shf, B0);

    // agg2: X2a = Anorm @ X2b (bf16, 256 cols)
    aggb_kernel<DH_><<<NN / 4, 256, 0, stream>>>(B0, off, srow, dis, Xa);
    // conv2: t = h1 + relu(X2a @ w_conv2 + b) + inter[graph] -> S3 fp32 + B0 bf16
    gemm_bf16_kernel<<<dim3(DH_ / 128, NN / 128), 256, 0, stream>>>(
        Xa, wc2t, S3, B0, NN, DH_, DH_, b_conv2, S1, inter_f, 1, 1);

    // Fused QKV projection: QKVb = tb @ [wq|wk|wv] + [bq|bk|bv]  (bf16 out)
    gemm_bf16_kernel<<<dim3(768 / 128, NN / 128), 256, 0, stream>>>(
        B0, wqkvt, nullptr, QKVb, NN, DH_, 768, bqkv, nullptr, nullptr, 0, 0);

    // MFMA flash attention -> Ob bf16 (B0; tb dead after QKV gemm)
    attn_mfma_kernel<<<BG * NH, 256, 0, stream>>>(QKVb, B0);

    // z = Ob @ wo + bo + t -> S4 ; t2 = LN(z) -> S4 (+bf16 B0)
    gemm_bf16_kernel<<<dim3(DH_ / 128, NN / 128), 256, 0, stream>>>(
        B0, wot, S4, nullptr, NN, DH_, DH_, bo, S3, nullptr, 0, 0);
    ln_kernel<<<NN / 4, 256, 0, stream>>>(S4, S4, B0, ln1_g, ln1_b);

    // FFN: F = relu(t2 @ w_ff1 + b1) -> Fb (bf16 over S0+S1) ;
    //      z2 = F @ w_ff2 + b2 + t2 -> S2
    gemm_bf16_kernel<<<dim3(DFF_ / 128, NN / 128), 256, 0, stream>>>(
        B0, wf1t, nullptr, Fb, NN, DH_, DFF_, b_ff1, nullptr, nullptr, 1, 0);
    gemm_bf16_kernel<<<dim3(DH_ / 128, NN / 128), 256, 0, stream>>>(
        Fb, wf2t, S2, nullptr, NN, DFF_, DH_, b_ff2, S4, nullptr, 0, 0);

    // t3 = LN(z2) in-place ; readout -> out[0 .. B*DH)
    ln_kernel<<<NN / 4, 256, 0, stream>>>(S2, S2, nullptr, ln2_g, ln2_b);
    readout_kernel<<<BG, 256, 0, stream>>>(S2, out);
}

// Round 5
// 784.903 us; speedup vs baseline: 2.1119x; 1.0602x over previous
//
#include <hip/hip_runtime.h>
#include <math.h>

// Problem constants (fixed by the reference)
#define NN   32768
#define BG   128
#define SG   256
#define EE   524288
#define DIN_ 128
#define DH_  256
#define NH   8
#define HD_  32
#define DFF_ 1024
#define EPS_ 1e-5f

typedef __attribute__((ext_vector_type(8))) short bf16x8;
typedef __attribute__((ext_vector_type(4))) float f32x4;

__device__ __forceinline__ unsigned short f2bf(float f) {
    unsigned int u = __builtin_bit_cast(unsigned int, f);
    unsigned int r = u + 0x7FFFu + ((u >> 16) & 1u);
    return (unsigned short)(r >> 16);
}
__device__ __forceinline__ float bf2f(unsigned short u) {
    return __builtin_bit_cast(float, (unsigned int)u << 16);
}
__device__ __forceinline__ unsigned int pack2bf(float a, float b) {
    return (unsigned int)f2bf(a) | ((unsigned int)f2bf(b) << 16);
}

// ---------------------------------------------------------------------------
// init_avg_h: per-graph mean of raw x (graph b = rows [b*256, b*256+256)).
__global__ __launch_bounds__(128) void initavg_kernel(const float* __restrict__ X,
                                                      float* __restrict__ out2) {
    int b = blockIdx.x, j = threadIdx.x;
    float s = 0.f;
    for (int r = 0; r < SG; ++r) s += X[(size_t)(b * SG + r) * DIN_ + j];
    out2[b * DIN_ + j] = s * (1.f / (float)SG);
}

// Column sum / sumsq partials for BatchNorm stats (axis 0 over all N rows).
template <int C>
__global__ __launch_bounds__(C) void colstats_kernel(const float* __restrict__ X,
                                                     float* __restrict__ csum,
                                                     float* __restrict__ csumsq) {
    int j = threadIdx.x;
    size_t r0 = (size_t)blockIdx.x * 256;
    float s = 0.f, sq = 0.f;
    for (int r = 0; r < 256; ++r) {
        float v = X[(r0 + r) * C + j];
        s += v; sq += v * v;
    }
    atomicAdd(&csum[j], s);
    atomicAdd(&csumsq[j], sq);
}

template <int C>
__global__ __launch_bounds__(C) void bnfin_kernel(const float* __restrict__ csum,
                                                  const float* __restrict__ csumsq,
                                                  const float* __restrict__ g,
                                                  const float* __restrict__ b,
                                                  float* __restrict__ scale,
                                                  float* __restrict__ shift) {
    int j = threadIdx.x;
    float mu  = csum[j] * (1.f / (float)NN);
    float var = csumsq[j] * (1.f / (float)NN) - mu * mu;
    float s = g[j] * rsqrtf(var + EPS_);
    scale[j] = s;
    shift[j] = b[j] - mu * s;
}

// BN apply, bf16 output (feeds aggregation / MFMA GEMM A operand).
template <int C>
__global__ __launch_bounds__(256) void bnapply_kernel(const float* __restrict__ X,
                                                      const float* __restrict__ sc,
                                                      const float* __restrict__ sh,
                                                      unsigned short* __restrict__ Y) {
    int i = blockIdx.x * 256 + threadIdx.x;
    int j = i & (C - 1);
    Y[i] = f2bf(X[i] * sc[j] + sh[j]);
}

// Weight cast+transpose: W[K,N] fp32 -> Wt[N,K] bf16. Coalesced writes.
__global__ __launch_bounds__(256) void wtrans_kernel(const float* __restrict__ W,
                                                     unsigned short* __restrict__ Wt,
                                                     int K, int N) {
    int idx = blockIdx.x * 256 + threadIdx.x;
    if (idx < K * N) {
        int n = idx / K, k = idx - n * K;
        Wt[idx] = f2bf(W[(size_t)k * N + n]);
    }
}

// Concat Q/K/V biases into one fp32[768].
__global__ __launch_bounds__(256) void bcat_kernel(const float* __restrict__ bq,
                                                   const float* __restrict__ bk,
                                                   const float* __restrict__ bv,
                                                   float* __restrict__ o) {
    int j = threadIdx.x;
    if (blockIdx.x == 0) o[j] = bq[j];
    else if (blockIdx.x == 1) o[DH_ + j] = bk[j];
    else o[2 * DH_ + j] = bv[j];
}

// ---------------------------------------------------------------------------
// CSR build
__global__ __launch_bounds__(256) void deg_kernel(const int* __restrict__ col,
                                                  int* __restrict__ deg) {
    int e = blockIdx.x * 256 + threadIdx.x;
    if (e < EE) atomicAdd(&deg[col[e]], 1);
}

__global__ __launch_bounds__(1024) void scan_kernel(const int* __restrict__ deg,
                                                    int* __restrict__ off,
                                                    float* __restrict__ dis) {
    __shared__ int sums[1024];
    int t = threadIdx.x;
    int base = t * 32;
    int loc[32];
    int run = 0;
#pragma unroll
    for (int i = 0; i < 32; ++i) { loc[i] = run; run += deg[base + i]; }
    sums[t] = run;
    __syncthreads();
    for (int d = 1; d < 1024; d <<= 1) {
        int tmp = (t >= d) ? sums[t - d] : 0;
        __syncthreads();
        sums[t] += tmp;
        __syncthreads();
    }
    int excl = sums[t] - run;
#pragma unroll
    for (int i = 0; i < 32; ++i) {
        off[base + i] = excl + loc[i];
        dis[base + i] = rsqrtf((float)(deg[base + i] + 1));
    }
    if (t == 1023) off[NN] = sums[1023];
}

__global__ __launch_bounds__(256) void scatter_kernel(const int* __restrict__ row,
                                                      const int* __restrict__ col,
                                                      const int* __restrict__ off,
                                                      int* __restrict__ cnt,
                                                      int* __restrict__ srow) {
    int e = blockIdx.x * 256 + threadIdx.x;
    if (e < EE) {
        int c = col[e];
        int p = off[c] + atomicAdd(&cnt[c], 1);
        srow[p] = row[e];
    }
}

// ---------------------------------------------------------------------------
// Pure bf16 GCN aggregation: Y[c,:] = dc*(sum_e dis[r]*X[r,:] + dc*X[c,:]).
template <int C>
__global__ __launch_bounds__(256) void aggb_kernel(const unsigned short* __restrict__ X,
                                                   const int* __restrict__ off,
                                                   const int* __restrict__ srow,
                                                   const float* __restrict__ dis,
                                                   unsigned short* __restrict__ Y) {
    constexpr int EPL = C / 64;
    int lane = threadIdx.x & 63;
    int c = blockIdx.x * 4 + (threadIdx.x >> 6);
    float dc = dis[c];
    float acc[EPL];
    {
        unsigned short t[EPL];
        const unsigned short* xc = X + (size_t)c * C + lane * EPL;
        if constexpr (EPL == 4) *(uint2*)t = *(const uint2*)xc;
        else *(unsigned int*)t = *(const unsigned int*)xc;
#pragma unroll
        for (int e2 = 0; e2 < EPL; ++e2) acc[e2] = dc * bf2f(t[e2]);
    }
    int s = off[c], en = off[c + 1];
    for (int i = s; i < en; ++i) {
        int r = srow[i];
        float dr = dis[r];
        unsigned short t[EPL];
        const unsigned short* xr = X + (size_t)r * C + lane * EPL;
        if constexpr (EPL == 4) *(uint2*)t = *(const uint2*)xr;
        else *(unsigned int*)t = *(const unsigned int*)xr;
#pragma unroll
        for (int e2 = 0; e2 < EPL; ++e2) acc[e2] += dr * bf2f(t[e2]);
    }
    unsigned short t[EPL];
#pragma unroll
    for (int e2 = 0; e2 < EPL; ++e2) t[e2] = f2bf(acc[e2] * dc);
    unsigned short* yc = Y + (size_t)c * C + lane * EPL;
    if constexpr (EPL == 4) *(uint2*)yc = *(const uint2*)t;
    else *(unsigned int*)yc = *(const unsigned int*)t;
}

// ---------------------------------------------------------------------------
// bf16 MFMA GEMM (128x128 tile, 4 waves 2x2, 16x16x32 MFMAs).
__global__ __launch_bounds__(256) void gemm_bf16_kernel(
    const unsigned short* __restrict__ A,
    const unsigned short* __restrict__ Bt,
    float* __restrict__ Cf,
    unsigned short* __restrict__ Cb,
    int M, int K, int N,
    const float* __restrict__ bias,
    const float* __restrict__ res,
    const float* __restrict__ inter,
    int do_relu, int relu_first) {
    constexpr int LDP = 40;
    __shared__ unsigned short As[128 * LDP];
    __shared__ unsigned short Bs[128 * LDP];
    int bm = blockIdx.y * 128;
    int bn = blockIdx.x * 128;
    int tid = threadIdx.x;
    int wave = tid >> 6, lane = tid & 63;
    int wm = (wave & 1) * 64, wn = (wave >> 1) * 64;
    int lrc = lane & 15;
    int koct = lane >> 4;

    f32x4 acc[4][4];
#pragma unroll
    for (int i = 0; i < 4; ++i)
#pragma unroll
        for (int j = 0; j < 4; ++j) acc[i][j] = (f32x4){0.f, 0.f, 0.f, 0.f};

    for (int k0 = 0; k0 < K; k0 += 32) {
#pragma unroll
        for (int it = 0; it < 2; ++it) {
            int c = tid + it * 256;
            int row = c >> 2, offk = (c & 3) * 8;
            *(uint4*)(As + row * LDP + offk) =
                *(const uint4*)(A + (size_t)(bm + row) * K + k0 + offk);
            *(uint4*)(Bs + row * LDP + offk) =
                *(const uint4*)(Bt + (size_t)(bn + row) * K + k0 + offk);
        }
        __syncthreads();
        bf16x8 af[4], bfr[4];
#pragma unroll
        for (int i = 0; i < 4; ++i)
            af[i] = *(const bf16x8*)(As + (wm + i * 16 + lrc) * LDP + koct * 8);
#pragma unroll
        for (int j = 0; j < 4; ++j)
            bfr[j] = *(const bf16x8*)(Bs + (wn + j * 16 + lrc) * LDP + koct * 8);
#pragma unroll
        for (int i = 0; i < 4; ++i)
#pragma unroll
            for (int j = 0; j < 4; ++j)
                acc[i][j] = __builtin_amdgcn_mfma_f32_16x16x32_bf16(af[i], bfr[j],
                                                                    acc[i][j], 0, 0, 0);
        __syncthreads();
    }
#pragma unroll
    for (int i = 0; i < 4; ++i) {
#pragma unroll
        for (int r = 0; r < 4; ++r) {
            int grow = bm + wm + i * 16 + koct * 4 + r;
#pragma unroll
            for (int j = 0; j < 4; ++j) {
                int gcol = bn + wn + j * 16 + lrc;
                float v = acc[i][j][r];
                if (bias) v += bias[gcol];
                if (relu_first) v = fmaxf(v, 0.f);
                if (res) v += res[(size_t)grow * N + gcol];
                if (inter) v += inter[(grow >> 8) * N + gcol];
                if (do_relu && !relu_first) v = fmaxf(v, 0.f);
                if (Cf) Cf[(size_t)grow * N + gcol] = v;
                if (Cb) Cb[(size_t)grow * N + gcol] = f2bf(v);
            }
        }
    }
}

// ---------------------------------------------------------------------------
// MFMA flash attention, transposed-score variant. One block per (graph, head),
// 4 waves x 64 q-rows. Per 32-key chunk: S^T = K@Q^T via mfma (C-layout puts
// q in lane&15, keys in regs/koct) -> softmax reduction is 8 in-reg ops +
// 2 shfl_xor per q-tile; P^T written as packed ds_write_b64 into a per-wave
// strip, read back as PV A-fragments (b128); corr broadcast via 64-float LDS.
__global__ __launch_bounds__(256) void attn_mfma_kernel(
    const unsigned short* __restrict__ QKV,
    unsigned short* __restrict__ Ob) {
    int b = blockIdx.x >> 3, h = blockIdx.x & 7;
    __shared__ unsigned short Ks[256 * 40];    // [key][hd 32 + pad]
    __shared__ unsigned short Vt[32 * 264];    // [d][key 256 + pad]
    __shared__ unsigned short Ps[4 * 64 * 40]; // per-wave [q 64][key 32 + pad]
    __shared__ float Lc[4 * 64];               // per-wave corr/l broadcast
    const unsigned short* kg = QKV + (size_t)b * 256 * 768 + 256 + h * 32;
    const unsigned short* vg = QKV + (size_t)b * 256 * 768 + 512 + h * 32;
    int tid = threadIdx.x;
#pragma unroll
    for (int it = 0; it < 4; ++it) {
        int c = it * 256 + tid;
        int row = c >> 2, q4 = (c & 3) * 8;
        *(uint4*)(Ks + row * 40 + q4) = *(const uint4*)(kg + (size_t)row * 768 + q4);
    }
#pragma unroll
    for (int it = 0; it < 4; ++it) {
        int c = it * 256 + tid;
        int key = c >> 2, d0 = (c & 3) * 8;
        unsigned short tmp[8];
        *(uint4*)tmp = *(const uint4*)(vg + (size_t)key * 768 + d0);
#pragma unroll
        for (int j = 0; j < 8; ++j) Vt[(d0 + j) * 264 + key] = tmp[j];
    }
    __syncthreads();

    int wave = tid >> 6, lane = tid & 63;
    int lr = lane & 15, koct = lane >> 4;
    int qrow0 = b * 256 + wave * 64;
    // Q-fragments (B-operand for S^T): q = j*16+lr, dims koct*8..+7
    bf16x8 qf[4];
#pragma unroll
    for (int j = 0; j < 4; ++j)
        qf[j] = *(const bf16x8*)(QKV + (size_t)(qrow0 + j * 16 + lr) * 768 + h * 32 + koct * 8);

    f32x4 Oa[4][2];
    float mj[4], lj[4];
#pragma unroll
    for (int i = 0; i < 4; ++i) {
        Oa[i][0] = (f32x4){0.f, 0.f, 0.f, 0.f};
        Oa[i][1] = (f32x4){0.f, 0.f, 0.f, 0.f};
        mj[i] = -1e30f; lj[i] = 0.f;
    }
    unsigned short* Pw = Ps + wave * (64 * 40);
    float* Lw = Lc + wave * 64;
    const float sc = 0.17677669529663689f;  // 1/sqrt(32)

    for (int kc = 0; kc < 256; kc += 32) {
        // A-fragments: K rows (keys kc+lr, kc+16+lr), dims koct*8..+7
        bf16x8 kf0 = *(const bf16x8*)(Ks + (kc + lr) * 40 + koct * 8);
        bf16x8 kf1 = *(const bf16x8*)(Ks + (kc + 16 + lr) * 40 + koct * 8);
        f32x4 St0[4], St1[4];
#pragma unroll
        for (int j = 0; j < 4; ++j) {
            St0[j] = __builtin_amdgcn_mfma_f32_16x16x32_bf16(kf0, qf[j],
                         (f32x4){0.f, 0.f, 0.f, 0.f}, 0, 0, 0);
            St1[j] = __builtin_amdgcn_mfma_f32_16x16x32_bf16(kf1, qf[j],
                         (f32x4){0.f, 0.f, 0.f, 0.f}, 0, 0, 0);
        }
        // Softmax per q-tile j (q = j*16+lr); lane holds 8 keys of this chunk:
        // tile0 keys koct*4+r, tile1 keys 16+koct*4+r.
#pragma unroll
        for (int j = 0; j < 4; ++j) {
            float s0[4], s1[4];
#pragma unroll
            for (int r = 0; r < 4; ++r) { s0[r] = St0[j][r] * sc; s1[r] = St1[j][r] * sc; }
            float mx = fmaxf(fmaxf(fmaxf(s0[0], s0[1]), fmaxf(s0[2], s0[3])),
                             fmaxf(fmaxf(s1[0], s1[1]), fmaxf(s1[2], s1[3])));
            mx = fmaxf(mx, __shfl_xor(mx, 16));
            mx = fmaxf(mx, __shfl_xor(mx, 32));
            float mn = fmaxf(mj[j], mx);
            float corr = __expf(mj[j] - mn);
            mj[j] = mn;
            float p0[4], p1[4], ps = 0.f;
#pragma unroll
            for (int r = 0; r < 4; ++r) {
                p0[r] = __expf(s0[r] - mn); p1[r] = __expf(s1[r] - mn);
                ps += p0[r] + p1[r];
            }
            ps += __shfl_xor(ps, 16);
            ps += __shfl_xor(ps, 32);
            lj[j] = lj[j] * corr + ps;
            if (koct == 0) Lw[j * 16 + lr] = corr;
            // P^T -> per-wave strip: row q=j*16+lr, cols t*16+koct*4..+3
            uint2 w0 = {pack2bf(p0[0], p0[1]), pack2bf(p0[2], p0[3])};
            uint2 w1 = {pack2bf(p1[0], p1[1]), pack2bf(p1[2], p1[3])};
            *(uint2*)(Pw + (j * 16 + lr) * 40 + koct * 4) = w0;
            *(uint2*)(Pw + (j * 16 + lr) * 40 + 16 + koct * 4) = w1;
        }
        // Rescale O accumulators: corr at q = i*16 + koct*4 + r (broadcast read)
#pragma unroll
        for (int i = 0; i < 4; ++i) {
            f32x4 c4 = *(const f32x4*)(Lw + i * 16 + koct * 4);
#pragma unroll
            for (int r = 0; r < 4; ++r) { Oa[i][0][r] *= c4[r]; Oa[i][1][r] *= c4[r]; }
        }
        // PV: A = P (m=q=lane&15, k=koct*8..+7), B = V^T frags
        bf16x8 vf0 = *(const bf16x8*)(Vt + lr * 264 + kc + koct * 8);
        bf16x8 vf1 = *(const bf16x8*)(Vt + (16 + lr) * 264 + kc + koct * 8);
#pragma unroll
        for (int i = 0; i < 4; ++i) {
            bf16x8 pf = *(const bf16x8*)(Pw + (i * 16 + lr) * 40 + koct * 8);
            Oa[i][0] = __builtin_amdgcn_mfma_f32_16x16x32_bf16(pf, vf0, Oa[i][0], 0, 0, 0);
            Oa[i][1] = __builtin_amdgcn_mfma_f32_16x16x32_bf16(pf, vf1, Oa[i][1], 0, 0, 0);
        }
    }
    // Broadcast l to C-layout rows, then write O.
    if (koct == 0) {
#pragma unroll
        for (int j = 0; j < 4; ++j) Lw[j * 16 + lr] = lj[j];
    }
    __builtin_amdgcn_s_waitcnt(0);  // wave-local LDS visibility
#pragma unroll
    for (int i = 0; i < 4; ++i) {
        f32x4 l4 = *(const f32x4*)(Lw + i * 16 + koct * 4);
#pragma unroll
        for (int r = 0; r < 4; ++r) {
            float inv = 1.f / l4[r];
            int row = qrow0 + i * 16 + koct * 4 + r;
#pragma unroll
            for (int jn = 0; jn < 2; ++jn) {
                int col = h * 32 + jn * 16 + lr;
                Ob[(size_t)row * 256 + col] = f2bf(Oa[i][jn][r] * inv);
            }
        }
    }
}

// LayerNorm over last dim (256). One wave per row; in-place safe.
__global__ __launch_bounds__(256) void ln_kernel(const float* __restrict__ Z,
                                                 float* __restrict__ Out,
                                                 unsigned short* __restrict__ Outb,
                                                 const float* __restrict__ g,
                                                 const float* __restrict__ bt) {
    int row = blockIdx.x * 4 + (threadIdx.x >> 6);
    int lane = threadIdx.x & 63;
    const float* z = Z + (size_t)row * DH_;
    float v[4];
    float sum = 0.f;
#pragma unroll
    for (int i = 0; i < 4; ++i) { v[i] = z[lane + i * 64]; sum += v[i]; }
#pragma unroll
    for (int off = 32; off; off >>= 1) sum += __shfl_xor(sum, off);
    float mu = sum * (1.f / (float)DH_);
    float vs = 0.f;
#pragma unroll
    for (int i = 0; i < 4; ++i) { float d = v[i] - mu; vs += d * d; }
#pragma unroll
    for (int off = 32; off; off >>= 1) vs += __shfl_xor(vs, off);
    float rs = rsqrtf(vs * (1.f / (float)DH_) + EPS_);
#pragma unroll
    for (int i = 0; i < 4; ++i) {
        int col = lane + i * 64;
        float y = (v[i] - mu) * rs * g[col] + bt[col];
        Out[(size_t)row * DH_ + col] = y;
        if (Outb) Outb[(size_t)row * DH_ + col] = f2bf(y);
    }
}

// Readout: per-graph column sum of t3.
__global__ __launch_bounds__(256) void readout_kernel(const float* __restrict__ T3,
                                                      float* __restrict__ out) {
    int b = blockIdx.x, j = threadIdx.x;
    float s = 0.f;
    for (int r = 0; r < SG; ++r) s += T3[(size_t)(b * SG + r) * DH_ + j];
    out[b * DH_ + j] = s;
}

// ---------------------------------------------------------------------------
extern "C" void kernel_launch(void* const* d_in, const int* in_sizes, int n_in,
                              void* d_out, int out_size, void* d_ws, size_t ws_size,
                              hipStream_t stream) {
    const float* x       = (const float*)d_in[0];
    const int*   ei      = (const int*)d_in[1];
    const float* inter_f = (const float*)d_in[3];
    const float* bn1_g = (const float*)d_in[4],  *bn1_b = (const float*)d_in[5];
    const float* bn2_g = (const float*)d_in[6],  *bn2_b = (const float*)d_in[7];
    const float* w_conv1 = (const float*)d_in[8],  *b_conv1 = (const float*)d_in[9];
    const float* w_conv2 = (const float*)d_in[10], *b_conv2 = (const float*)d_in[11];
    const float* wq = (const float*)d_in[12], *bq = (const float*)d_in[13];
    const float* wk = (const float*)d_in[14], *bk = (const float*)d_in[15];
    const float* wv = (const float*)d_in[16], *bv = (const float*)d_in[17];
    const float* wo = (const float*)d_in[18], *bo = (const float*)d_in[19];
    const float* ln1_g = (const float*)d_in[20], *ln1_b = (const float*)d_in[21];
    const float* ln2_g = (const float*)d_in[22], *ln2_b = (const float*)d_in[23];
    const float* w_ff1 = (const float*)d_in[24], *b_ff1 = (const float*)d_in[25];
    const float* w_ff2 = (const float*)d_in[26], *b_ff2 = (const float*)d_in[27];
    float* out = (float*)d_out;

    char* base = (char*)d_ws;
    size_t o = 0;
    auto alloc = [&](size_t bytes) -> void* {
        void* p = base + o;
        o = (o + bytes + 255) & ~(size_t)255;
        return p;
    };
    int*   deg    = (int*)alloc(NN * 4);
    int*   off    = (int*)alloc((NN + 1) * 4);
    int*   cnt    = (int*)alloc(NN * 4);
    int*   srow   = (int*)alloc(EE * 4);
    float* dis    = (float*)alloc(NN * 4);
    float* csum   = (float*)alloc(256 * 4);
    float* csumsq = (float*)alloc(256 * 4);
    float* scl    = (float*)alloc(256 * 4);
    float* shf    = (float*)alloc(256 * 4);
    float* bqkv   = (float*)alloc(768 * 4);
    const size_t SLOT = (size_t)NN * DH_;            // 8M floats = 32 MB
    float* S0 = (float*)alloc(SLOT * 4);             // Xa/X2a ; QKVb/Fb alias
    float* S1 = (float*)alloc(SLOT * 4);             // h1 ; QKVb/Fb alias
    float* S2 = (float*)alloc(SLOT * 4);             // z2/t3
    float* S3 = (float*)alloc(SLOT * 4);             // t
    float* S4 = (float*)alloc(SLOT * 4);             // z -> t2
    unsigned short* B0 = (unsigned short*)alloc(SLOT * 2);  // Xb/X2b/tb/Ob/t2b
    unsigned short* wc1t  = (unsigned short*)alloc((size_t)DIN_ * DH_ * 2);
    unsigned short* wc2t  = (unsigned short*)alloc((size_t)DH_ * DH_ * 2);
    unsigned short* wqkvt = (unsigned short*)alloc((size_t)DH_ * DH_ * 3 * 2);
    unsigned short* wot   = (unsigned short*)alloc((size_t)DH_ * DH_ * 2);
    unsigned short* wf1t  = (unsigned short*)alloc((size_t)DH_ * DFF_ * 2);
    unsigned short* wf2t  = (unsigned short*)alloc((size_t)DFF_ * DH_ * 2);
    unsigned short* Xa   = (unsigned short*)S0;      // agg outputs (dead after GEMM)
    unsigned short* QKVb = (unsigned short*)S0;      // 48 MB over S0+S1
    unsigned short* Fb   = (unsigned short*)S0;      // 64 MB over S0+S1

    hipMemsetAsync(deg, 0, NN * 4, stream);
    hipMemsetAsync(cnt, 0, NN * 4, stream);
    hipMemsetAsync(csum, 0, 2048, stream);

    // Weight transposes (bf16) + QKV bias concat
    wtrans_kernel<<<(DIN_ * DH_ + 255) / 256, 256, 0, stream>>>(w_conv1, wc1t, DIN_, DH_);
    wtrans_kernel<<<(DH_ * DH_ + 255) / 256, 256, 0, stream>>>(w_conv2, wc2t, DH_, DH_);
    wtrans_kernel<<<(DH_ * DH_ + 255) / 256, 256, 0, stream>>>(wq, wqkvt, DH_, DH_);
    wtrans_kernel<<<(DH_ * DH_ + 255) / 256, 256, 0, stream>>>(wk, wqkvt + DH_ * DH_, DH_, DH_);
    wtrans_kernel<<<(DH_ * DH_ + 255) / 256, 256, 0, stream>>>(wv, wqkvt + 2 * DH_ * DH_, DH_, DH_);
    wtrans_kernel<<<(DH_ * DH_ + 255) / 256, 256, 0, stream>>>(wo, wot, DH_, DH_);
    wtrans_kernel<<<(DH_ * DFF_ + 255) / 256, 256, 0, stream>>>(w_ff1, wf1t, DH_, DFF_);
    wtrans_kernel<<<(DFF_ * DH_ + 255) / 256, 256, 0, stream>>>(w_ff2, wf2t, DFF_, DH_);
    bcat_kernel<<<3, 256, 0, stream>>>(bq, bk, bv, bqkv);

    // init_avg_h -> out[B*DH ...]
    initavg_kernel<<<BG, 128, 0, stream>>>(x, out + BG * DH_);

    // BN1 -> Xb bf16 (B0)
    colstats_kernel<DIN_><<<NN / 256, DIN_, 0, stream>>>(x, csum, csumsq);
    bnfin_kernel<DIN_><<<1, DIN_, 0, stream>>>(csum, csumsq, bn1_g, bn1_b, scl, shf);
    bnapply_kernel<DIN_><<<NN * DIN_ / 256, 256, 0, stream>>>(x, scl, shf, B0);

    // CSR build
    deg_kernel<<<EE / 256, 256, 0, stream>>>(ei + EE, deg);
    scan_kernel<<<1, 1024, 0, stream>>>(deg, off, dis);
    scatter_kernel<<<EE / 256, 256, 0, stream>>>(ei, ei + EE, off, cnt, srow);

    // agg1 on input side (A·X)·W == A·(X·W): Xa = Anorm @ Xb  (bf16, 128 cols)
    aggb_kernel<DIN_><<<NN / 4, 256, 0, stream>>>(B0, off, srow, dis, Xa);
    // conv1: h1 = relu(Xa @ w_conv1 + b) -> S1 fp32
    gemm_bf16_kernel<<<dim3(DH_ / 128, NN / 128), 256, 0, stream>>>(
        Xa, wc1t, S1, nullptr, NN, DIN_, DH_, b_conv1, nullptr, nullptr, 1, 0);

    // BN2 -> X2b bf16 (B0)
    hipMemsetAsync(csum, 0, 2048, stream);
    colstats_kernel<DH_><<<NN / 256, DH_, 0, stream>>>(S1, csum, csumsq);
    bnfin_kernel<DH_><<<1, DH_, 0, stream>>>(csum, csumsq, bn2_g, bn2_b, scl, shf);
    bnapply_kernel<DH_><<<NN * DH_ / 256, 256, 0, stream>>>(S1, scl, shf, B0);

    // agg2: X2a = Anorm @ X2b (bf16, 256 cols)
    aggb_kernel<DH_><<<NN / 4, 256, 0, stream>>>(B0, off, srow, dis, Xa);
    // conv2: t = h1 + relu(X2a @ w_conv2 + b) + inter[graph] -> S3 fp32 + B0 bf16
    gemm_bf16_kernel<<<dim3(DH_ / 128, NN / 128), 256, 0, stream>>>(
        Xa, wc2t, S3, B0, NN, DH_, DH_, b_conv2, S1, inter_f, 1, 1);

    // Fused QKV projection: QKVb = tb @ [wq|wk|wv] + [bq|bk|bv]  (bf16 out)
    gemm_bf16_kernel<<<dim3(768 / 128, NN / 128), 256, 0, stream>>>(
        B0, wqkvt, nullptr, QKVb, NN, DH_, 768, bqkv, nullptr, nullptr, 0, 0);

    // MFMA flash attention -> Ob bf16 (B0; tb dead after QKV gemm)
    attn_mfma_kernel<<<BG * NH, 256, 0, stream>>>(QKVb, B0);

    // z = Ob @ wo + bo + t -> S4 ; t2 = LN(z) -> S4 (+bf16 B0)
    gemm_bf16_kernel<<<dim3(DH_ / 128, NN / 128), 256, 0, stream>>>(
        B0, wot, S4, nullptr, NN, DH_, DH_, bo, S3, nullptr, 0, 0);
    ln_kernel<<<NN / 4, 256, 0, stream>>>(S4, S4, B0, ln1_g, ln1_b);

    // FFN: F = relu(t2 @ w_ff1 + b1) -> Fb (bf16 over S0+S1) ;
    //      z2 = F @ w_ff2 + b2 + t2 -> S2
    gemm_bf16_kernel<<<dim3(DFF_ / 128, NN / 128), 256, 0, stream>>>(
        B0, wf1t, nullptr, Fb, NN, DH_, DFF_, b_ff1, nullptr, nullptr, 1, 0);
    gemm_bf16_kernel<<<dim3(DH_ / 128, NN / 128), 256, 0, stream>>>(
        Fb, wf2t, S2, nullptr, NN, DFF_, DH_, b_ff2, S4, nullptr, 0, 0);

    // t3 = LN(z2) in-place ; readout -> out[0 .. B*DH)
    ln_kernel<<<NN / 4, 256, 0, stream>>>(S2, S2, nullptr, ln2_g, ln2_b);
    readout_kernel<<<BG, 256, 0, stream>>>(S2, out);
}

// Round 6
// 782.016 us; speedup vs baseline: 2.1197x; 1.0037x over previous
//
#include <hip/hip_runtime.h>
#include <math.h>

// Problem constants (fixed by the reference)
#define NN   32768
#define BG   128
#define SG   256
#define EE   524288
#define DIN_ 128
#define DH_  256
#define NH   8
#define HD_  32
#define DFF_ 1024
#define EPS_ 1e-5f

typedef __attribute__((ext_vector_type(8))) short bf16x8;
typedef __attribute__((ext_vector_type(4))) float f32x4;

__device__ __forceinline__ unsigned short f2bf(float f) {
    unsigned int u = __builtin_bit_cast(unsigned int, f);
    unsigned int r = u + 0x7FFFu + ((u >> 16) & 1u);
    return (unsigned short)(r >> 16);
}
__device__ __forceinline__ float bf2f(unsigned short u) {
    return __builtin_bit_cast(float, (unsigned int)u << 16);
}
__device__ __forceinline__ unsigned int pack2bf(float a, float b) {
    return (unsigned int)f2bf(a) | ((unsigned int)f2bf(b) << 16);
}
// Async global->LDS DMA, 16 B per lane. LDS dest must be wave-uniform base +
// lane*16 (m104/m108); caller guarantees the lane-contiguous layout.
__device__ __forceinline__ void glds16(const unsigned short* g, unsigned short* l) {
    __builtin_amdgcn_global_load_lds(
        (const __attribute__((address_space(1))) void*)g,
        (__attribute__((address_space(3))) void*)l, 16, 0, 0);
}

// ---------------------------------------------------------------------------
// init_avg_h: per-graph mean of raw x (graph b = rows [b*256, b*256+256)).
__global__ __launch_bounds__(128) void initavg_kernel(const float* __restrict__ X,
                                                      float* __restrict__ out2) {
    int b = blockIdx.x, j = threadIdx.x;
    float s = 0.f;
    for (int r = 0; r < SG; ++r) s += X[(size_t)(b * SG + r) * DIN_ + j];
    out2[b * DIN_ + j] = s * (1.f / (float)SG);
}

// Column sum / sumsq partials for BatchNorm stats (axis 0 over all N rows).
template <int C>
__global__ __launch_bounds__(C) void colstats_kernel(const float* __restrict__ X,
                                                     float* __restrict__ csum,
                                                     float* __restrict__ csumsq) {
    int j = threadIdx.x;
    size_t r0 = (size_t)blockIdx.x * 256;
    float s = 0.f, sq = 0.f;
    for (int r = 0; r < 256; ++r) {
        float v = X[(r0 + r) * C + j];
        s += v; sq += v * v;
    }
    atomicAdd(&csum[j], s);
    atomicAdd(&csumsq[j], sq);
}

template <int C>
__global__ __launch_bounds__(C) void bnfin_kernel(const float* __restrict__ csum,
                                                  const float* __restrict__ csumsq,
                                                  const float* __restrict__ g,
                                                  const float* __restrict__ b,
                                                  float* __restrict__ scale,
                                                  float* __restrict__ shift) {
    int j = threadIdx.x;
    float mu  = csum[j] * (1.f / (float)NN);
    float var = csumsq[j] * (1.f / (float)NN) - mu * mu;
    float s = g[j] * rsqrtf(var + EPS_);
    scale[j] = s;
    shift[j] = b[j] - mu * s;
}

// BN apply, bf16 output (feeds aggregation / MFMA GEMM A operand).
template <int C>
__global__ __launch_bounds__(256) void bnapply_kernel(const float* __restrict__ X,
                                                      const float* __restrict__ sc,
                                                      const float* __restrict__ sh,
                                                      unsigned short* __restrict__ Y) {
    int i = blockIdx.x * 256 + threadIdx.x;
    int j = i & (C - 1);
    Y[i] = f2bf(X[i] * sc[j] + sh[j]);
}

// Weight cast+transpose: W[K,N] fp32 -> Wt[N,K] bf16. Coalesced writes.
__global__ __launch_bounds__(256) void wtrans_kernel(const float* __restrict__ W,
                                                     unsigned short* __restrict__ Wt,
                                                     int K, int N) {
    int idx = blockIdx.x * 256 + threadIdx.x;
    if (idx < K * N) {
        int n = idx / K, k = idx - n * K;
        Wt[idx] = f2bf(W[(size_t)k * N + n]);
    }
}

// Concat Q/K/V biases into one fp32[768].
__global__ __launch_bounds__(256) void bcat_kernel(const float* __restrict__ bq,
                                                   const float* __restrict__ bk,
                                                   const float* __restrict__ bv,
                                                   float* __restrict__ o) {
    int j = threadIdx.x;
    if (blockIdx.x == 0) o[j] = bq[j];
    else if (blockIdx.x == 1) o[DH_ + j] = bk[j];
    else o[2 * DH_ + j] = bv[j];
}

// ---------------------------------------------------------------------------
// CSR build
__global__ __launch_bounds__(256) void deg_kernel(const int* __restrict__ col,
                                                  int* __restrict__ deg) {
    int e = blockIdx.x * 256 + threadIdx.x;
    if (e < EE) atomicAdd(&deg[col[e]], 1);
}

__global__ __launch_bounds__(1024) void scan_kernel(const int* __restrict__ deg,
                                                    int* __restrict__ off,
                                                    float* __restrict__ dis) {
    __shared__ int sums[1024];
    int t = threadIdx.x;
    int base = t * 32;
    int loc[32];
    int run = 0;
#pragma unroll
    for (int i = 0; i < 32; ++i) { loc[i] = run; run += deg[base + i]; }
    sums[t] = run;
    __syncthreads();
    for (int d = 1; d < 1024; d <<= 1) {
        int tmp = (t >= d) ? sums[t - d] : 0;
        __syncthreads();
        sums[t] += tmp;
        __syncthreads();
    }
    int excl = sums[t] - run;
#pragma unroll
    for (int i = 0; i < 32; ++i) {
        off[base + i] = excl + loc[i];
        dis[base + i] = rsqrtf((float)(deg[base + i] + 1));
    }
    if (t == 1023) off[NN] = sums[1023];
}

__global__ __launch_bounds__(256) void scatter_kernel(const int* __restrict__ row,
                                                      const int* __restrict__ col,
                                                      const int* __restrict__ off,
                                                      int* __restrict__ cnt,
                                                      int* __restrict__ srow) {
    int e = blockIdx.x * 256 + threadIdx.x;
    if (e < EE) {
        int c = col[e];
        int p = off[c] + atomicAdd(&cnt[c], 1);
        srow[p] = row[e];
    }
}

// ---------------------------------------------------------------------------
// Pure bf16 GCN aggregation: Y[c,:] = dc*(sum_e dis[r]*X[r,:] + dc*X[c,:]).
template <int C>
__global__ __launch_bounds__(256) void aggb_kernel(const unsigned short* __restrict__ X,
                                                   const int* __restrict__ off,
                                                   const int* __restrict__ srow,
                                                   const float* __restrict__ dis,
                                                   unsigned short* __restrict__ Y) {
    constexpr int EPL = C / 64;
    int lane = threadIdx.x & 63;
    int c = blockIdx.x * 4 + (threadIdx.x >> 6);
    float dc = dis[c];
    float acc[EPL];
    {
        unsigned short t[EPL];
        const unsigned short* xc = X + (size_t)c * C + lane * EPL;
        if constexpr (EPL == 4) *(uint2*)t = *(const uint2*)xc;
        else *(unsigned int*)t = *(const unsigned int*)xc;
#pragma unroll
        for (int e2 = 0; e2 < EPL; ++e2) acc[e2] = dc * bf2f(t[e2]);
    }
    int s = off[c], en = off[c + 1];
    for (int i = s; i < en; ++i) {
        int r = srow[i];
        float dr = dis[r];
        unsigned short t[EPL];
        const unsigned short* xr = X + (size_t)r * C + lane * EPL;
        if constexpr (EPL == 4) *(uint2*)t = *(const uint2*)xr;
        else *(unsigned int*)t = *(const unsigned int*)xr;
#pragma unroll
        for (int e2 = 0; e2 < EPL; ++e2) acc[e2] += dr * bf2f(t[e2]);
    }
    unsigned short t[EPL];
#pragma unroll
    for (int e2 = 0; e2 < EPL; ++e2) t[e2] = f2bf(acc[e2] * dc);
    unsigned short* yc = Y + (size_t)c * C + lane * EPL;
    if constexpr (EPL == 4) *(uint2*)yc = *(const uint2*)t;
    else *(unsigned int*)yc = *(const unsigned int*)t;
}

// ---------------------------------------------------------------------------
// bf16 MFMA GEMM (128x128 tile, 4 waves 2x2, 16x16x32 MFMAs).
// Staging via global_load_lds width=16 (m97 pattern): unpadded 64 B LDS rows,
// lane-contiguous DMA; wave w instruction it covers rows w*32+it*16..+15.
__global__ __launch_bounds__(256) void gemm_bf16_kernel(
    const unsigned short* __restrict__ A,
    const unsigned short* __restrict__ Bt,
    float* __restrict__ Cf,
    unsigned short* __restrict__ Cb,
    int M, int K, int N,
    const float* __restrict__ bias,
    const float* __restrict__ res,
    const float* __restrict__ inter,
    int do_relu, int relu_first) {
    constexpr int LDP = 32;  // bf16 per row, no pad (required by global_load_lds)
    __shared__ unsigned short As[128 * LDP];
    __shared__ unsigned short Bs[128 * LDP];
    int bm = blockIdx.y * 128;
    int bn = blockIdx.x * 128;
    int tid = threadIdx.x;
    int wave = tid >> 6, lane = tid & 63;
    int wm = (wave & 1) * 64, wn = (wave >> 1) * 64;
    int lrc = lane & 15;
    int koct = lane >> 4;

    // staging coords: this lane DMAs row sr (+16 for 2nd chunk), k-offs skk
    int sr = wave * 32 + (lane >> 2);
    int skk = (lane & 3) * 8;
    unsigned short* lA = As + wave * 1024 + lane * 8;   // = (w*32+l/4)*32+(l%4)*8
    unsigned short* lB = Bs + wave * 1024 + lane * 8;

    f32x4 acc[4][4];
#pragma unroll
    for (int i = 0; i < 4; ++i)
#pragma unroll
        for (int j = 0; j < 4; ++j) acc[i][j] = (f32x4){0.f, 0.f, 0.f, 0.f};

    for (int k0 = 0; k0 < K; k0 += 32) {
        const unsigned short* gA = A + (size_t)(bm + sr) * K + k0 + skk;
        const unsigned short* gB = Bt + (size_t)(bn + sr) * K + k0 + skk;
        glds16(gA, lA);
        glds16(gA + (size_t)16 * K, lA + 512);
        glds16(gB, lB);
        glds16(gB + (size_t)16 * K, lB + 512);
        __syncthreads();
        bf16x8 af[4], bfr[4];
#pragma unroll
        for (int i = 0; i < 4; ++i)
            af[i] = *(const bf16x8*)(As + (wm + i * 16 + lrc) * LDP + koct * 8);
#pragma unroll
        for (int j = 0; j < 4; ++j)
            bfr[j] = *(const bf16x8*)(Bs + (wn + j * 16 + lrc) * LDP + koct * 8);
#pragma unroll
        for (int i = 0; i < 4; ++i)
#pragma unroll
            for (int j = 0; j < 4; ++j)
                acc[i][j] = __builtin_amdgcn_mfma_f32_16x16x32_bf16(af[i], bfr[j],
                                                                    acc[i][j], 0, 0, 0);
        __syncthreads();
    }
#pragma unroll
    for (int i = 0; i < 4; ++i) {
#pragma unroll
        for (int r = 0; r < 4; ++r) {
            int grow = bm + wm + i * 16 + koct * 4 + r;
#pragma unroll
            for (int j = 0; j < 4; ++j) {
                int gcol = bn + wn + j * 16 + lrc;
                float v = acc[i][j][r];
                if (bias) v += bias[gcol];
                if (relu_first) v = fmaxf(v, 0.f);
                if (res) v += res[(size_t)grow * N + gcol];
                if (inter) v += inter[(grow >> 8) * N + gcol];
                if (do_relu && !relu_first) v = fmaxf(v, 0.f);
                if (Cf) Cf[(size_t)grow * N + gcol] = v;
                if (Cb) Cb[(size_t)grow * N + gcol] = f2bf(v);
            }
        }
    }
}

// ---------------------------------------------------------------------------
// MFMA flash attention, transposed-score variant (see round 5 notes).
__global__ __launch_bounds__(256) void attn_mfma_kernel(
    const unsigned short* __restrict__ QKV,
    unsigned short* __restrict__ Ob) {
    int b = blockIdx.x >> 3, h = blockIdx.x & 7;
    __shared__ unsigned short Ks[256 * 40];    // [key][hd 32 + pad]
    __shared__ unsigned short Vt[32 * 264];    // [d][key 256 + pad]
    __shared__ unsigned short Ps[4 * 64 * 40]; // per-wave [q 64][key 32 + pad]
    __shared__ float Lc[4 * 64];               // per-wave corr/l broadcast
    const unsigned short* kg = QKV + (size_t)b * 256 * 768 + 256 + h * 32;
    const unsigned short* vg = QKV + (size_t)b * 256 * 768 + 512 + h * 32;
    int tid = threadIdx.x;
#pragma unroll
    for (int it = 0; it < 4; ++it) {
        int c = it * 256 + tid;
        int row = c >> 2, q4 = (c & 3) * 8;
        *(uint4*)(Ks + row * 40 + q4) = *(const uint4*)(kg + (size_t)row * 768 + q4);
    }
#pragma unroll
    for (int it = 0; it < 4; ++it) {
        int c = it * 256 + tid;
        int key = c >> 2, d0 = (c & 3) * 8;
        unsigned short tmp[8];
        *(uint4*)tmp = *(const uint4*)(vg + (size_t)key * 768 + d0);
#pragma unroll
        for (int j = 0; j < 8; ++j) Vt[(d0 + j) * 264 + key] = tmp[j];
    }
    __syncthreads();

    int wave = tid >> 6, lane = tid & 63;
    int lr = lane & 15, koct = lane >> 4;
    int qrow0 = b * 256 + wave * 64;
    bf16x8 qf[4];
#pragma unroll
    for (int j = 0; j < 4; ++j)
        qf[j] = *(const bf16x8*)(QKV + (size_t)(qrow0 + j * 16 + lr) * 768 + h * 32 + koct * 8);

    f32x4 Oa[4][2];
    float mj[4], lj[4];
#pragma unroll
    for (int i = 0; i < 4; ++i) {
        Oa[i][0] = (f32x4){0.f, 0.f, 0.f, 0.f};
        Oa[i][1] = (f32x4){0.f, 0.f, 0.f, 0.f};
        mj[i] = -1e30f; lj[i] = 0.f;
    }
    unsigned short* Pw = Ps + wave * (64 * 40);
    float* Lw = Lc + wave * 64;
    const float sc = 0.17677669529663689f;  // 1/sqrt(32)

    for (int kc = 0; kc < 256; kc += 32) {
        bf16x8 kf0 = *(const bf16x8*)(Ks + (kc + lr) * 40 + koct * 8);
        bf16x8 kf1 = *(const bf16x8*)(Ks + (kc + 16 + lr) * 40 + koct * 8);
        f32x4 St0[4], St1[4];
#pragma unroll
        for (int j = 0; j < 4; ++j) {
            St0[j] = __builtin_amdgcn_mfma_f32_16x16x32_bf16(kf0, qf[j],
                         (f32x4){0.f, 0.f, 0.f, 0.f}, 0, 0, 0);
            St1[j] = __builtin_amdgcn_mfma_f32_16x16x32_bf16(kf1, qf[j],
                         (f32x4){0.f, 0.f, 0.f, 0.f}, 0, 0, 0);
        }
#pragma unroll
        for (int j = 0; j < 4; ++j) {
            float s0[4], s1[4];
#pragma unroll
            for (int r = 0; r < 4; ++r) { s0[r] = St0[j][r] * sc; s1[r] = St1[j][r] * sc; }
            float mx = fmaxf(fmaxf(fmaxf(s0[0], s0[1]), fmaxf(s0[2], s0[3])),
                             fmaxf(fmaxf(s1[0], s1[1]), fmaxf(s1[2], s1[3])));
            mx = fmaxf(mx, __shfl_xor(mx, 16));
            mx = fmaxf(mx, __shfl_xor(mx, 32));
            float mn = fmaxf(mj[j], mx);
            float corr = __expf(mj[j] - mn);
            mj[j] = mn;
            float p0[4], p1[4], ps = 0.f;
#pragma unroll
            for (int r = 0; r < 4; ++r) {
                p0[r] = __expf(s0[r] - mn); p1[r] = __expf(s1[r] - mn);
                ps += p0[r] + p1[r];
            }
            ps += __shfl_xor(ps, 16);
            ps += __shfl_xor(ps, 32);
            lj[j] = lj[j] * corr + ps;
            if (koct == 0) Lw[j * 16 + lr] = corr;
            uint2 w0 = {pack2bf(p0[0], p0[1]), pack2bf(p0[2], p0[3])};
            uint2 w1 = {pack2bf(p1[0], p1[1]), pack2bf(p1[2], p1[3])};
            *(uint2*)(Pw + (j * 16 + lr) * 40 + koct * 4) = w0;
            *(uint2*)(Pw + (j * 16 + lr) * 40 + 16 + koct * 4) = w1;
        }
#pragma unroll
        for (int i = 0; i < 4; ++i) {
            f32x4 c4 = *(const f32x4*)(Lw + i * 16 + koct * 4);
#pragma unroll
            for (int r = 0; r < 4; ++r) { Oa[i][0][r] *= c4[r]; Oa[i][1][r] *= c4[r]; }
        }
        bf16x8 vf0 = *(const bf16x8*)(Vt + lr * 264 + kc + koct * 8);
        bf16x8 vf1 = *(const bf16x8*)(Vt + (16 + lr) * 264 + kc + koct * 8);
#pragma unroll
        for (int i = 0; i < 4; ++i) {
            bf16x8 pf = *(const bf16x8*)(Pw + (i * 16 + lr) * 40 + koct * 8);
            Oa[i][0] = __builtin_amdgcn_mfma_f32_16x16x32_bf16(pf, vf0, Oa[i][0], 0, 0, 0);
            Oa[i][1] = __builtin_amdgcn_mfma_f32_16x16x32_bf16(pf, vf1, Oa[i][1], 0, 0, 0);
        }
    }
    if (koct == 0) {
#pragma unroll
        for (int j = 0; j < 4; ++j) Lw[j * 16 + lr] = lj[j];
    }
    __builtin_amdgcn_s_waitcnt(0);  // wave-local LDS visibility
#pragma unroll
    for (int i = 0; i < 4; ++i) {
        f32x4 l4 = *(const f32x4*)(Lw + i * 16 + koct * 4);
#pragma unroll
        for (int r = 0; r < 4; ++r) {
            float inv = 1.f / l4[r];
            int row = qrow0 + i * 16 + koct * 4 + r;
#pragma unroll
            for (int jn = 0; jn < 2; ++jn) {
                int col = h * 32 + jn * 16 + lr;
                Ob[(size_t)row * 256 + col] = f2bf(Oa[i][jn][r] * inv);
            }
        }
    }
}

// LayerNorm over last dim (256). One wave per row; in-place safe.
__global__ __launch_bounds__(256) void ln_kernel(const float* __restrict__ Z,
                                                 float* __restrict__ Out,
                                                 unsigned short* __restrict__ Outb,
                                                 const float* __restrict__ g,
                                                 const float* __restrict__ bt) {
    int row = blockIdx.x * 4 + (threadIdx.x >> 6);
    int lane = threadIdx.x & 63;
    const float* z = Z + (size_t)row * DH_;
    float v[4];
    float sum = 0.f;
#pragma unroll
    for (int i = 0; i < 4; ++i) { v[i] = z[lane + i * 64]; sum += v[i]; }
#pragma unroll
    for (int off = 32; off; off >>= 1) sum += __shfl_xor(sum, off);
    float mu = sum * (1.f / (float)DH_);
    float vs = 0.f;
#pragma unroll
    for (int i = 0; i < 4; ++i) { float d = v[i] - mu; vs += d * d; }
#pragma unroll
    for (int off = 32; off; off >>= 1) vs += __shfl_xor(vs, off);
    float rs = rsqrtf(vs * (1.f / (float)DH_) + EPS_);
#pragma unroll
    for (int i = 0; i < 4; ++i) {
        int col = lane + i * 64;
        float y = (v[i] - mu) * rs * g[col] + bt[col];
        Out[(size_t)row * DH_ + col] = y;
        if (Outb) Outb[(size_t)row * DH_ + col] = f2bf(y);
    }
}

// Readout: per-graph column sum of t3.
__global__ __launch_bounds__(256) void readout_kernel(const float* __restrict__ T3,
                                                      float* __restrict__ out) {
    int b = blockIdx.x, j = threadIdx.x;
    float s = 0.f;
    for (int r = 0; r < SG; ++r) s += T3[(size_t)(b * SG + r) * DH_ + j];
    out[b * DH_ + j] = s;
}

// ---------------------------------------------------------------------------
extern "C" void kernel_launch(void* const* d_in, const int* in_sizes, int n_in,
                              void* d_out, int out_size, void* d_ws, size_t ws_size,
                              hipStream_t stream) {
    const float* x       = (const float*)d_in[0];
    const int*   ei      = (const int*)d_in[1];
    const float* inter_f = (const float*)d_in[3];
    const float* bn1_g = (const float*)d_in[4],  *bn1_b = (const float*)d_in[5];
    const float* bn2_g = (const float*)d_in[6],  *bn2_b = (const float*)d_in[7];
    const float* w_conv1 = (const float*)d_in[8],  *b_conv1 = (const float*)d_in[9];
    const float* w_conv2 = (const float*)d_in[10], *b_conv2 = (const float*)d_in[11];
    const float* wq = (const float*)d_in[12], *bq = (const float*)d_in[13];
    const float* wk = (const float*)d_in[14], *bk = (const float*)d_in[15];
    const float* wv = (const float*)d_in[16], *bv = (const float*)d_in[17];
    const float* wo = (const float*)d_in[18], *bo = (const float*)d_in[19];
    const float* ln1_g = (const float*)d_in[20], *ln1_b = (const float*)d_in[21];
    const float* ln2_g = (const float*)d_in[22], *ln2_b = (const float*)d_in[23];
    const float* w_ff1 = (const float*)d_in[24], *b_ff1 = (const float*)d_in[25];
    const float* w_ff2 = (const float*)d_in[26], *b_ff2 = (const float*)d_in[27];
    float* out = (float*)d_out;

    char* base = (char*)d_ws;
    size_t o = 0;
    auto alloc = [&](size_t bytes) -> void* {
        void* p = base + o;
        o = (o + bytes + 255) & ~(size_t)255;
        return p;
    };
    int*   deg    = (int*)alloc(NN * 4);
    int*   off    = (int*)alloc((NN + 1) * 4);
    int*   cnt    = (int*)alloc(NN * 4);
    int*   srow   = (int*)alloc(EE * 4);
    float* dis    = (float*)alloc(NN * 4);
    float* csum   = (float*)alloc(256 * 4);
    float* csumsq = (float*)alloc(256 * 4);
    float* scl    = (float*)alloc(256 * 4);
    float* shf    = (float*)alloc(256 * 4);
    float* bqkv   = (float*)alloc(768 * 4);
    const size_t SLOT = (size_t)NN * DH_;            // 8M floats = 32 MB
    float* S0 = (float*)alloc(SLOT * 4);             // Xa/X2a ; QKVb/Fb alias
    float* S1 = (float*)alloc(SLOT * 4);             // h1 ; QKVb/Fb alias
    float* S2 = (float*)alloc(SLOT * 4);             // z2/t3
    float* S3 = (float*)alloc(SLOT * 4);             // t
    float* S4 = (float*)alloc(SLOT * 4);             // z -> t2
    unsigned short* B0 = (unsigned short*)alloc(SLOT * 2);  // Xb/X2b/tb/Ob/t2b
    unsigned short* wc1t  = (unsigned short*)alloc((size_t)DIN_ * DH_ * 2);
    unsigned short* wc2t  = (unsigned short*)alloc((size_t)DH_ * DH_ * 2);
    unsigned short* wqkvt = (unsigned short*)alloc((size_t)DH_ * DH_ * 3 * 2);
    unsigned short* wot   = (unsigned short*)alloc((size_t)DH_ * DH_ * 2);
    unsigned short* wf1t  = (unsigned short*)alloc((size_t)DH_ * DFF_ * 2);
    unsigned short* wf2t  = (unsigned short*)alloc((size_t)DFF_ * DH_ * 2);
    unsigned short* Xa   = (unsigned short*)S0;      // agg outputs (dead after GEMM)
    unsigned short* QKVb = (unsigned short*)S0;      // 48 MB over S0+S1
    unsigned short* Fb   = (unsigned short*)S0;      // 64 MB over S0+S1

    hipMemsetAsync(deg, 0, NN * 4, stream);
    hipMemsetAsync(cnt, 0, NN * 4, stream);
    hipMemsetAsync(csum, 0, 2048, stream);

    // Weight transposes (bf16) + QKV bias concat
    wtrans_kernel<<<(DIN_ * DH_ + 255) / 256, 256, 0, stream>>>(w_conv1, wc1t, DIN_, DH_);
    wtrans_kernel<<<(DH_ * DH_ + 255) / 256, 256, 0, stream>>>(w_conv2, wc2t, DH_, DH_);
    wtrans_kernel<<<(DH_ * DH_ + 255) / 256, 256, 0, stream>>>(wq, wqkvt, DH_, DH_);
    wtrans_kernel<<<(DH_ * DH_ + 255) / 256, 256, 0, stream>>>(wk, wqkvt + DH_ * DH_, DH_, DH_);
    wtrans_kernel<<<(DH_ * DH_ + 255) / 256, 256, 0, stream>>>(wv, wqkvt + 2 * DH_ * DH_, DH_, DH_);
    wtrans_kernel<<<(DH_ * DH_ + 255) / 256, 256, 0, stream>>>(wo, wot, DH_, DH_);
    wtrans_kernel<<<(DH_ * DFF_ + 255) / 256, 256, 0, stream>>>(w_ff1, wf1t, DH_, DFF_);
    wtrans_kernel<<<(DFF_ * DH_ + 255) / 256, 256, 0, stream>>>(w_ff2, wf2t, DFF_, DH_);
    bcat_kernel<<<3, 256, 0, stream>>>(bq, bk, bv, bqkv);

    // init_avg_h -> out[B*DH ...]
    initavg_kernel<<<BG, 128, 0, stream>>>(x, out + BG * DH_);

    // BN1 -> Xb bf16 (B0)
    colstats_kernel<DIN_><<<NN / 256, DIN_, 0, stream>>>(x, csum, csumsq);
    bnfin_kernel<DIN_><<<1, DIN_, 0, stream>>>(csum, csumsq, bn1_g, bn1_b, scl, shf);
    bnapply_kernel<DIN_><<<NN * DIN_ / 256, 256, 0, stream>>>(x, scl, shf, B0);

    // CSR build
    deg_kernel<<<EE / 256, 256, 0, stream>>>(ei + EE, deg);
    scan_kernel<<<1, 1024, 0, stream>>>(deg, off, dis);
    scatter_kernel<<<EE / 256, 256, 0, stream>>>(ei, ei + EE, off, cnt, srow);

    // agg1 on input side (A·X)·W == A·(X·W): Xa = Anorm @ Xb  (bf16, 128 cols)
    aggb_kernel<DIN_><<<NN / 4, 256, 0, stream>>>(B0, off, srow, dis, Xa);
    // conv1: h1 = relu(Xa @ w_conv1 + b) -> S1 fp32
    gemm_bf16_kernel<<<dim3(DH_ / 128, NN / 128), 256, 0, stream>>>(
        Xa, wc1t, S1, nullptr, NN, DIN_, DH_, b_conv1, nullptr, nullptr, 1, 0);

    // BN2 -> X2b bf16 (B0)
    hipMemsetAsync(csum, 0, 2048, stream);
    colstats_kernel<DH_><<<NN / 256, DH_, 0, stream>>>(S1, csum, csumsq);
    bnfin_kernel<DH_><<<1, DH_, 0, stream>>>(csum, csumsq, bn2_g, bn2_b, scl, shf);
    bnapply_kernel<DH_><<<NN * DH_ / 256, 256, 0, stream>>>(S1, scl, shf, B0);

    // agg2: X2a = Anorm @ X2b (bf16, 256 cols)
    aggb_kernel<DH_><<<NN / 4, 256, 0, stream>>>(B0, off, srow, dis, Xa);
    // conv2: t = h1 + relu(X2a @ w_conv2 + b) + inter[graph] -> S3 fp32 + B0 bf16
    gemm_bf16_kernel<<<dim3(DH_ / 128, NN / 128), 256, 0, stream>>>(
        Xa, wc2t, S3, B0, NN, DH_, DH_, b_conv2, S1, inter_f, 1, 1);

    // Fused QKV projection: QKVb = tb @ [wq|wk|wv] + [bq|bk|bv]  (bf16 out)
    gemm_bf16_kernel<<<dim3(768 / 128, NN / 128), 256, 0, stream>>>(
        B0, wqkvt, nullptr, QKVb, NN, DH_, 768, bqkv, nullptr, nullptr, 0, 0);

    // MFMA flash attention -> Ob bf16 (B0; tb dead after QKV gemm)
    attn_mfma_kernel<<<BG * NH, 256, 0, stream>>>(QKVb, B0);

    // z = Ob @ wo + bo + t -> S4 ; t2 = LN(z) -> S4 (+bf16 B0)
    gemm_bf16_kernel<<<dim3(DH_ / 128, NN / 128), 256, 0, stream>>>(
        B0, wot, S4, nullptr, NN, DH_, DH_, bo, S3, nullptr, 0, 0);
    ln_kernel<<<NN / 4, 256, 0, stream>>>(S4, S4, B0, ln1_g, ln1_b);

    // FFN: F = relu(t2 @ w_ff1 + b1) -> Fb (bf16 over S0+S1) ;
    //      z2 = F @ w_ff2 + b2 + t2 -> S2
    gemm_bf16_kernel<<<dim3(DFF_ / 128, NN / 128), 256, 0, stream>>>(
        B0, wf1t, nullptr, Fb, NN, DH_, DFF_, b_ff1, nullptr, nullptr, 1, 0);
    gemm_bf16_kernel<<<dim3(DH_ / 128, NN / 128), 256, 0, stream>>>(
        Fb, wf2t, S2, nullptr, NN, DFF_, DH_, b_ff2, S4, nullptr, 0, 0);

    // t3 = LN(z2) in-place ; readout -> out[0 .. B*DH)
    ln_kernel<<<NN / 4, 256, 0, stream>>>(S2, S2, nullptr, ln2_g, ln2_b);
    readout_kernel<<<BG, 256, 0, stream>>>(S2, out);
}

// Round 7
// 773.162 us; speedup vs baseline: 2.1440x; 1.0115x over previous
//
#include <hip/hip_runtime.h>
#include <math.h>

// Problem constants (fixed by the reference)
#define NN   32768
#define BG   128
#define SG   256
#define EE   524288
#define DIN_ 128
#define DH_  256
#define NH   8
#define HD_  32
#define DFF_ 1024
#define EPS_ 1e-5f

typedef __attribute__((ext_vector_type(8))) short bf16x8;
typedef __attribute__((ext_vector_type(4))) float f32x4;

__device__ __forceinline__ unsigned short f2bf(float f) {
    unsigned int u = __builtin_bit_cast(unsigned int, f);
    unsigned int r = u + 0x7FFFu + ((u >> 16) & 1u);
    return (unsigned short)(r >> 16);
}
__device__ __forceinline__ float bf2f(unsigned short u) {
    return __builtin_bit_cast(float, (unsigned int)u << 16);
}
__device__ __forceinline__ unsigned int pack2bf(float a, float b) {
    return (unsigned int)f2bf(a) | ((unsigned int)f2bf(b) << 16);
}
// Async global->LDS DMA, 16 B per lane. LDS dest must be wave-uniform base +
// lane*16 (m104/m108); caller guarantees the lane-contiguous layout.
__device__ __forceinline__ void glds16(const unsigned short* g, unsigned short* l) {
    __builtin_amdgcn_global_load_lds(
        (const __attribute__((address_space(1))) void*)g,
        (__attribute__((address_space(3))) void*)l, 16, 0, 0);
}
// s_waitcnt with vmcnt(N) only (exp/lgkm masked off). gfx9 encoding:
// vm[3:0]=bits0-3, exp=bits4-6, lgkm=bits8-11, vm[5:4]=bits14-15.
#define WAIT_VM4() __builtin_amdgcn_s_waitcnt(0x0F74)
#define WAIT_VM0() __builtin_amdgcn_s_waitcnt(0x0F70)

// ---------------------------------------------------------------------------
// init_avg_h: per-graph mean of raw x (graph b = rows [b*256, b*256+256)).
__global__ __launch_bounds__(128) void initavg_kernel(const float* __restrict__ X,
                                                      float* __restrict__ out2) {
    int b = blockIdx.x, j = threadIdx.x;
    float s = 0.f;
    for (int r = 0; r < SG; ++r) s += X[(size_t)(b * SG + r) * DIN_ + j];
    out2[b * DIN_ + j] = s * (1.f / (float)SG);
}

// Column sum / sumsq partials for BatchNorm stats (axis 0 over all N rows).
template <int C>
__global__ __launch_bounds__(C) void colstats_kernel(const float* __restrict__ X,
                                                     float* __restrict__ csum,
                                                     float* __restrict__ csumsq) {
    int j = threadIdx.x;
    size_t r0 = (size_t)blockIdx.x * 256;
    float s = 0.f, sq = 0.f;
    for (int r = 0; r < 256; ++r) {
        float v = X[(r0 + r) * C + j];
        s += v; sq += v * v;
    }
    atomicAdd(&csum[j], s);
    atomicAdd(&csumsq[j], sq);
}

template <int C>
__global__ __launch_bounds__(C) void bnfin_kernel(const float* __restrict__ csum,
                                                  const float* __restrict__ csumsq,
                                                  const float* __restrict__ g,
                                                  const float* __restrict__ b,
                                                  float* __restrict__ scale,
                                                  float* __restrict__ shift) {
    int j = threadIdx.x;
    float mu  = csum[j] * (1.f / (float)NN);
    float var = csumsq[j] * (1.f / (float)NN) - mu * mu;
    float s = g[j] * rsqrtf(var + EPS_);
    scale[j] = s;
    shift[j] = b[j] - mu * s;
}

// BN apply, bf16 output (feeds aggregation / MFMA GEMM A operand).
template <int C>
__global__ __launch_bounds__(256) void bnapply_kernel(const float* __restrict__ X,
                                                      const float* __restrict__ sc,
                                                      const float* __restrict__ sh,
                                                      unsigned short* __restrict__ Y) {
    int i = blockIdx.x * 256 + threadIdx.x;
    int j = i & (C - 1);
    Y[i] = f2bf(X[i] * sc[j] + sh[j]);
}

// Weight cast+transpose: W[K,N] fp32 -> Wt[N,K] bf16. Coalesced writes.
__global__ __launch_bounds__(256) void wtrans_kernel(const float* __restrict__ W,
                                                     unsigned short* __restrict__ Wt,
                                                     int K, int N) {
    int idx = blockIdx.x * 256 + threadIdx.x;
    if (idx < K * N) {
        int n = idx / K, k = idx - n * K;
        Wt[idx] = f2bf(W[(size_t)k * N + n]);
    }
}

// Concat Q/K/V biases into one fp32[768].
__global__ __launch_bounds__(256) void bcat_kernel(const float* __restrict__ bq,
                                                   const float* __restrict__ bk,
                                                   const float* __restrict__ bv,
                                                   float* __restrict__ o) {
    int j = threadIdx.x;
    if (blockIdx.x == 0) o[j] = bq[j];
    else if (blockIdx.x == 1) o[DH_ + j] = bk[j];
    else o[2 * DH_ + j] = bv[j];
}

// ---------------------------------------------------------------------------
// CSR build
__global__ __launch_bounds__(256) void deg_kernel(const int* __restrict__ col,
                                                  int* __restrict__ deg) {
    int e = blockIdx.x * 256 + threadIdx.x;
    if (e < EE) atomicAdd(&deg[col[e]], 1);
}

__global__ __launch_bounds__(1024) void scan_kernel(const int* __restrict__ deg,
                                                    int* __restrict__ off,
                                                    float* __restrict__ dis) {
    __shared__ int sums[1024];
    int t = threadIdx.x;
    int base = t * 32;
    int loc[32];
    int run = 0;
#pragma unroll
    for (int i = 0; i < 32; ++i) { loc[i] = run; run += deg[base + i]; }
    sums[t] = run;
    __syncthreads();
    for (int d = 1; d < 1024; d <<= 1) {
        int tmp = (t >= d) ? sums[t - d] : 0;
        __syncthreads();
        sums[t] += tmp;
        __syncthreads();
    }
    int excl = sums[t] - run;
#pragma unroll
    for (int i = 0; i < 32; ++i) {
        off[base + i] = excl + loc[i];
        dis[base + i] = rsqrtf((float)(deg[base + i] + 1));
    }
    if (t == 1023) off[NN] = sums[1023];
}

__global__ __launch_bounds__(256) void scatter_kernel(const int* __restrict__ row,
                                                      const int* __restrict__ col,
                                                      const int* __restrict__ off,
                                                      int* __restrict__ cnt,
                                                      int* __restrict__ srow) {
    int e = blockIdx.x * 256 + threadIdx.x;
    if (e < EE) {
        int c = col[e];
        int p = off[c] + atomicAdd(&cnt[c], 1);
        srow[p] = row[e];
    }
}

// ---------------------------------------------------------------------------
// Pure bf16 GCN aggregation: Y[c,:] = dc*(sum_e dis[r]*X[r,:] + dc*X[c,:]).
template <int C>
__global__ __launch_bounds__(256) void aggb_kernel(const unsigned short* __restrict__ X,
                                                   const int* __restrict__ off,
                                                   const int* __restrict__ srow,
                                                   const float* __restrict__ dis,
                                                   unsigned short* __restrict__ Y) {
    constexpr int EPL = C / 64;
    int lane = threadIdx.x & 63;
    int c = blockIdx.x * 4 + (threadIdx.x >> 6);
    float dc = dis[c];
    float acc[EPL];
    {
        unsigned short t[EPL];
        const unsigned short* xc = X + (size_t)c * C + lane * EPL;
        if constexpr (EPL == 4) *(uint2*)t = *(const uint2*)xc;
        else *(unsigned int*)t = *(const unsigned int*)xc;
#pragma unroll
        for (int e2 = 0; e2 < EPL; ++e2) acc[e2] = dc * bf2f(t[e2]);
    }
    int s = off[c], en = off[c + 1];
    for (int i = s; i < en; ++i) {
        int r = srow[i];
        float dr = dis[r];
        unsigned short t[EPL];
        const unsigned short* xr = X + (size_t)r * C + lane * EPL;
        if constexpr (EPL == 4) *(uint2*)t = *(const uint2*)xr;
        else *(unsigned int*)t = *(const unsigned int*)xr;
#pragma unroll
        for (int e2 = 0; e2 < EPL; ++e2) acc[e2] += dr * bf2f(t[e2]);
    }
    unsigned short t[EPL];
#pragma unroll
    for (int e2 = 0; e2 < EPL; ++e2) t[e2] = f2bf(acc[e2] * dc);
    unsigned short* yc = Y + (size_t)c * C + lane * EPL;
    if constexpr (EPL == 4) *(uint2*)yc = *(const uint2*)t;
    else *(unsigned int*)yc = *(const unsigned int*)t;
}

// ---------------------------------------------------------------------------
// bf16 MFMA GEMM (128x128 tile, 4 waves 2x2, 16x16x32 MFMAs).
// Double-buffered global_load_lds pipeline with raw s_barrier + explicit
// s_waitcnt vmcnt(4): the prefetch for K-step k+1 stays in flight across the
// barrier (AITER-style; m139 structure). No __syncthreads -> no forced
// vmcnt(0) drain per iteration.
__global__ __launch_bounds__(256) void gemm_bf16_kernel(
    const unsigned short* __restrict__ A,
    const unsigned short* __restrict__ Bt,
    float* __restrict__ Cf,
    unsigned short* __restrict__ Cb,
    int M, int K, int N,
    const float* __restrict__ bias,
    const float* __restrict__ res,
    const float* __restrict__ inter,
    int do_relu, int relu_first) {
    constexpr int LDP = 32;  // bf16 per row, no pad (required by global_load_lds)
    __shared__ unsigned short As[2][128 * LDP];
    __shared__ unsigned short Bs[2][128 * LDP];
    int bm = blockIdx.y * 128;
    int bn = blockIdx.x * 128;
    int tid = threadIdx.x;
    int wave = tid >> 6, lane = tid & 63;
    int wm = (wave & 1) * 64, wn = (wave >> 1) * 64;
    int lrc = lane & 15;
    int koct = lane >> 4;

    // staging coords: this lane DMAs row sr (+16 for 2nd chunk), k-offs skk
    int sr = wave * 32 + (lane >> 2);
    int skk = (lane & 3) * 8;
    int lofs = wave * 1024 + lane * 8;  // LDS dest offset (elements)
    const unsigned short* gA0 = A + (size_t)(bm + sr) * K + skk;
    const unsigned short* gB0 = Bt + (size_t)(bn + sr) * K + skk;

    f32x4 acc[4][4];
#pragma unroll
    for (int i = 0; i < 4; ++i)
#pragma unroll
        for (int j = 0; j < 4; ++j) acc[i][j] = (f32x4){0.f, 0.f, 0.f, 0.f};

    // prologue: prefetch K-step 0 into buffer 0
    glds16(gA0, As[0] + lofs);
    glds16(gA0 + (size_t)16 * K, As[0] + lofs + 512);
    glds16(gB0, Bs[0] + lofs);
    glds16(gB0 + (size_t)16 * K, Bs[0] + lofs + 512);

    int buf = 0;
    for (int k0 = 0; k0 < K; k0 += 32) {
        int nk = k0 + 32;
        if (nk < K) {  // prefetch next K-step into the other buffer
            int nb = buf ^ 1;
            glds16(gA0 + nk, As[nb] + lofs);
            glds16(gA0 + nk + (size_t)16 * K, As[nb] + lofs + 512);
            glds16(gB0 + nk, Bs[nb] + lofs);
            glds16(gB0 + nk + (size_t)16 * K, Bs[nb] + lofs + 512);
            WAIT_VM4();  // current stage's 4 loads done; next 4 in flight
        } else {
            WAIT_VM0();
        }
        __builtin_amdgcn_s_barrier();
        bf16x8 af[4], bfr[4];
#pragma unroll
        for (int i = 0; i < 4; ++i)
            af[i] = *(const bf16x8*)(As[buf] + (wm + i * 16 + lrc) * LDP + koct * 8);
#pragma unroll
        for (int j = 0; j < 4; ++j)
            bfr[j] = *(const bf16x8*)(Bs[buf] + (wn + j * 16 + lrc) * LDP + koct * 8);
#pragma unroll
        for (int i = 0; i < 4; ++i)
#pragma unroll
            for (int j = 0; j < 4; ++j)
                acc[i][j] = __builtin_amdgcn_mfma_f32_16x16x32_bf16(af[i], bfr[j],
                                                                    acc[i][j], 0, 0, 0);
        __builtin_amdgcn_s_barrier();  // reads of buf retired before next DMA hits it
        buf ^= 1;
    }
#pragma unroll
    for (int i = 0; i < 4; ++i) {
#pragma unroll
        for (int r = 0; r < 4; ++r) {
            int grow = bm + wm + i * 16 + koct * 4 + r;
#pragma unroll
            for (int j = 0; j < 4; ++j) {
                int gcol = bn + wn + j * 16 + lrc;
                float v = acc[i][j][r];
                if (bias) v += bias[gcol];
                if (relu_first) v = fmaxf(v, 0.f);
                if (res) v += res[(size_t)grow * N + gcol];
                if (inter) v += inter[(grow >> 8) * N + gcol];
                if (do_relu && !relu_first) v = fmaxf(v, 0.f);
                if (Cf) Cf[(size_t)grow * N + gcol] = v;
                if (Cb) Cb[(size_t)grow * N + gcol] = f2bf(v);
            }
        }
    }
}

// ---------------------------------------------------------------------------
// MFMA flash attention, transposed-score variant (see round 5 notes).
__global__ __launch_bounds__(256) void attn_mfma_kernel(
    const unsigned short* __restrict__ QKV,
    unsigned short* __restrict__ Ob) {
    int b = blockIdx.x >> 3, h = blockIdx.x & 7;
    __shared__ unsigned short Ks[256 * 40];    // [key][hd 32 + pad]
    __shared__ unsigned short Vt[32 * 264];    // [d][key 256 + pad]
    __shared__ unsigned short Ps[4 * 64 * 40]; // per-wave [q 64][key 32 + pad]
    __shared__ float Lc[4 * 64];               // per-wave corr/l broadcast
    const unsigned short* kg = QKV + (size_t)b * 256 * 768 + 256 + h * 32;
    const unsigned short* vg = QKV + (size_t)b * 256 * 768 + 512 + h * 32;
    int tid = threadIdx.x;
#pragma unroll
    for (int it = 0; it < 4; ++it) {
        int c = it * 256 + tid;
        int row = c >> 2, q4 = (c & 3) * 8;
        *(uint4*)(Ks + row * 40 + q4) = *(const uint4*)(kg + (size_t)row * 768 + q4);
    }
#pragma unroll
    for (int it = 0; it < 4; ++it) {
        int c = it * 256 + tid;
        int key = c >> 2, d0 = (c & 3) * 8;
        unsigned short tmp[8];
        *(uint4*)tmp = *(const uint4*)(vg + (size_t)key * 768 + d0);
#pragma unroll
        for (int j = 0; j < 8; ++j) Vt[(d0 + j) * 264 + key] = tmp[j];
    }
    __syncthreads();

    int wave = tid >> 6, lane = tid & 63;
    int lr = lane & 15, koct = lane >> 4;
    int qrow0 = b * 256 + wave * 64;
    bf16x8 qf[4];
#pragma unroll
    for (int j = 0; j < 4; ++j)
        qf[j] = *(const bf16x8*)(QKV + (size_t)(qrow0 + j * 16 + lr) * 768 + h * 32 + koct * 8);

    f32x4 Oa[4][2];
    float mj[4], lj[4];
#pragma unroll
    for (int i = 0; i < 4; ++i) {
        Oa[i][0] = (f32x4){0.f, 0.f, 0.f, 0.f};
        Oa[i][1] = (f32x4){0.f, 0.f, 0.f, 0.f};
        mj[i] = -1e30f; lj[i] = 0.f;
    }
    unsigned short* Pw = Ps + wave * (64 * 40);
    float* Lw = Lc + wave * 64;
    const float sc = 0.17677669529663689f;  // 1/sqrt(32)

    for (int kc = 0; kc < 256; kc += 32) {
        bf16x8 kf0 = *(const bf16x8*)(Ks + (kc + lr) * 40 + koct * 8);
        bf16x8 kf1 = *(const bf16x8*)(Ks + (kc + 16 + lr) * 40 + koct * 8);
        f32x4 St0[4], St1[4];
#pragma unroll
        for (int j = 0; j < 4; ++j) {
            St0[j] = __builtin_amdgcn_mfma_f32_16x16x32_bf16(kf0, qf[j],
                         (f32x4){0.f, 0.f, 0.f, 0.f}, 0, 0, 0);
            St1[j] = __builtin_amdgcn_mfma_f32_16x16x32_bf16(kf1, qf[j],
                         (f32x4){0.f, 0.f, 0.f, 0.f}, 0, 0, 0);
        }
#pragma unroll
        for (int j = 0; j < 4; ++j) {
            float s0[4], s1[4];
#pragma unroll
            for (int r = 0; r < 4; ++r) { s0[r] = St0[j][r] * sc; s1[r] = St1[j][r] * sc; }
            float mx = fmaxf(fmaxf(fmaxf(s0[0], s0[1]), fmaxf(s0[2], s0[3])),
                             fmaxf(fmaxf(s1[0], s1[1]), fmaxf(s1[2], s1[3])));
            mx = fmaxf(mx, __shfl_xor(mx, 16));
            mx = fmaxf(mx, __shfl_xor(mx, 32));
            float mn = fmaxf(mj[j], mx);
            float corr = __expf(mj[j] - mn);
            mj[j] = mn;
            float p0[4], p1[4], ps = 0.f;
#pragma unroll
            for (int r = 0; r < 4; ++r) {
                p0[r] = __expf(s0[r] - mn); p1[r] = __expf(s1[r] - mn);
                ps += p0[r] + p1[r];
            }
            ps += __shfl_xor(ps, 16);
            ps += __shfl_xor(ps, 32);
            lj[j] = lj[j] * corr + ps;
            if (koct == 0) Lw[j * 16 + lr] = corr;
            uint2 w0 = {pack2bf(p0[0], p0[1]), pack2bf(p0[2], p0[3])};
            uint2 w1 = {pack2bf(p1[0], p1[1]), pack2bf(p1[2], p1[3])};
            *(uint2*)(Pw + (j * 16 + lr) * 40 + koct * 4) = w0;
            *(uint2*)(Pw + (j * 16 + lr) * 40 + 16 + koct * 4) = w1;
        }
#pragma unroll
        for (int i = 0; i < 4; ++i) {
            f32x4 c4 = *(const f32x4*)(Lw + i * 16 + koct * 4);
#pragma unroll
            for (int r = 0; r < 4; ++r) { Oa[i][0][r] *= c4[r]; Oa[i][1][r] *= c4[r]; }
        }
        bf16x8 vf0 = *(const bf16x8*)(Vt + lr * 264 + kc + koct * 8);
        bf16x8 vf1 = *(const bf16x8*)(Vt + (16 + lr) * 264 + kc + koct * 8);
#pragma unroll
        for (int i = 0; i < 4; ++i) {
            bf16x8 pf = *(const bf16x8*)(Pw + (i * 16 + lr) * 40 + koct * 8);
            Oa[i][0] = __builtin_amdgcn_mfma_f32_16x16x32_bf16(pf, vf0, Oa[i][0], 0, 0, 0);
            Oa[i][1] = __builtin_amdgcn_mfma_f32_16x16x32_bf16(pf, vf1, Oa[i][1], 0, 0, 0);
        }
    }
    if (koct == 0) {
#pragma unroll
        for (int j = 0; j < 4; ++j) Lw[j * 16 + lr] = lj[j];
    }
    __builtin_amdgcn_s_waitcnt(0);  // wave-local LDS visibility
#pragma unroll
    for (int i = 0; i < 4; ++i) {
        f32x4 l4 = *(const f32x4*)(Lw + i * 16 + koct * 4);
#pragma unroll
        for (int r = 0; r < 4; ++r) {
            float inv = 1.f / l4[r];
            int row = qrow0 + i * 16 + koct * 4 + r;
#pragma unroll
            for (int jn = 0; jn < 2; ++jn) {
                int col = h * 32 + jn * 16 + lr;
                Ob[(size_t)row * 256 + col] = f2bf(Oa[i][jn][r] * inv);
            }
        }
    }
}

// LayerNorm over last dim (256). One wave per row; in-place safe.
__global__ __launch_bounds__(256) void ln_kernel(const float* __restrict__ Z,
                                                 float* __restrict__ Out,
                                                 unsigned short* __restrict__ Outb,
                                                 const float* __restrict__ g,
                                                 const float* __restrict__ bt) {
    int row = blockIdx.x * 4 + (threadIdx.x >> 6);
    int lane = threadIdx.x & 63;
    const float* z = Z + (size_t)row * DH_;
    float v[4];
    float sum = 0.f;
#pragma unroll
    for (int i = 0; i < 4; ++i) { v[i] = z[lane + i * 64]; sum += v[i]; }
#pragma unroll
    for (int off = 32; off; off >>= 1) sum += __shfl_xor(sum, off);
    float mu = sum * (1.f / (float)DH_);
    float vs = 0.f;
#pragma unroll
    for (int i = 0; i < 4; ++i) { float d = v[i] - mu; vs += d * d; }
#pragma unroll
    for (int off = 32; off; off >>= 1) vs += __shfl_xor(vs, off);
    float rs = rsqrtf(vs * (1.f / (float)DH_) + EPS_);
#pragma unroll
    for (int i = 0; i < 4; ++i) {
        int col = lane + i * 64;
        float y = (v[i] - mu) * rs * g[col] + bt[col];
        Out[(size_t)row * DH_ + col] = y;
        if (Outb) Outb[(size_t)row * DH_ + col] = f2bf(y);
    }
}

// Readout: per-graph column sum of t3.
__global__ __launch_bounds__(256) void readout_kernel(const float* __restrict__ T3,
                                                      float* __restrict__ out) {
    int b = blockIdx.x, j = threadIdx.x;
    float s = 0.f;
    for (int r = 0; r < SG; ++r) s += T3[(size_t)(b * SG + r) * DH_ + j];
    out[b * DH_ + j] = s;
}

// ---------------------------------------------------------------------------
extern "C" void kernel_launch(void* const* d_in, const int* in_sizes, int n_in,
                              void* d_out, int out_size, void* d_ws, size_t ws_size,
                              hipStream_t stream) {
    const float* x       = (const float*)d_in[0];
    const int*   ei      = (const int*)d_in[1];
    const float* inter_f = (const float*)d_in[3];
    const float* bn1_g = (const float*)d_in[4],  *bn1_b = (const float*)d_in[5];
    const float* bn2_g = (const float*)d_in[6],  *bn2_b = (const float*)d_in[7];
    const float* w_conv1 = (const float*)d_in[8],  *b_conv1 = (const float*)d_in[9];
    const float* w_conv2 = (const float*)d_in[10], *b_conv2 = (const float*)d_in[11];
    const float* wq = (const float*)d_in[12], *bq = (const float*)d_in[13];
    const float* wk = (const float*)d_in[14], *bk = (const float*)d_in[15];
    const float* wv = (const float*)d_in[16], *bv = (const float*)d_in[17];
    const float* wo = (const float*)d_in[18], *bo = (const float*)d_in[19];
    const float* ln1_g = (const float*)d_in[20], *ln1_b = (const float*)d_in[21];
    const float* ln2_g = (const float*)d_in[22], *ln2_b = (const float*)d_in[23];
    const float* w_ff1 = (const float*)d_in[24], *b_ff1 = (const float*)d_in[25];
    const float* w_ff2 = (const float*)d_in[26], *b_ff2 = (const float*)d_in[27];
    float* out = (float*)d_out;

    char* base = (char*)d_ws;
    size_t o = 0;
    auto alloc = [&](size_t bytes) -> void* {
        void* p = base + o;
        o = (o + bytes + 255) & ~(size_t)255;
        return p;
    };
    int*   deg    = (int*)alloc(NN * 4);
    int*   off    = (int*)alloc((NN + 1) * 4);
    int*   cnt    = (int*)alloc(NN * 4);
    int*   srow   = (int*)alloc(EE * 4);
    float* dis    = (float*)alloc(NN * 4);
    float* csum   = (float*)alloc(256 * 4);
    float* csumsq = (float*)alloc(256 * 4);
    float* scl    = (float*)alloc(256 * 4);
    float* shf    = (float*)alloc(256 * 4);
    float* bqkv   = (float*)alloc(768 * 4);
    const size_t SLOT = (size_t)NN * DH_;            // 8M floats = 32 MB
    float* S0 = (float*)alloc(SLOT * 4);             // Xa/X2a ; QKVb/Fb alias
    float* S1 = (float*)alloc(SLOT * 4);             // h1 ; QKVb/Fb alias
    float* S2 = (float*)alloc(SLOT * 4);             // z2/t3
    float* S3 = (float*)alloc(SLOT * 4);             // t
    float* S4 = (float*)alloc(SLOT * 4);             // z -> t2
    unsigned short* B0 = (unsigned short*)alloc(SLOT * 2);  // Xb/X2b/tb/Ob/t2b
    unsigned short* wc1t  = (unsigned short*)alloc((size_t)DIN_ * DH_ * 2);
    unsigned short* wc2t  = (unsigned short*)alloc((size_t)DH_ * DH_ * 2);
    unsigned short* wqkvt = (unsigned short*)alloc((size_t)DH_ * DH_ * 3 * 2);
    unsigned short* wot   = (unsigned short*)alloc((size_t)DH_ * DH_ * 2);
    unsigned short* wf1t  = (unsigned short*)alloc((size_t)DH_ * DFF_ * 2);
    unsigned short* wf2t  = (unsigned short*)alloc((size_t)DFF_ * DH_ * 2);
    unsigned short* Xa   = (unsigned short*)S0;      // agg outputs (dead after GEMM)
    unsigned short* QKVb = (unsigned short*)S0;      // 48 MB over S0+S1
    unsigned short* Fb   = (unsigned short*)S0;      // 64 MB over S0+S1

    hipMemsetAsync(deg, 0, NN * 4, stream);
    hipMemsetAsync(cnt, 0, NN * 4, stream);
    hipMemsetAsync(csum, 0, 2048, stream);

    // Weight transposes (bf16) + QKV bias concat
    wtrans_kernel<<<(DIN_ * DH_ + 255) / 256, 256, 0, stream>>>(w_conv1, wc1t, DIN_, DH_);
    wtrans_kernel<<<(DH_ * DH_ + 255) / 256, 256, 0, stream>>>(w_conv2, wc2t, DH_, DH_);
    wtrans_kernel<<<(DH_ * DH_ + 255) / 256, 256, 0, stream>>>(wq, wqkvt, DH_, DH_);
    wtrans_kernel<<<(DH_ * DH_ + 255) / 256, 256, 0, stream>>>(wk, wqkvt + DH_ * DH_, DH_, DH_);
    wtrans_kernel<<<(DH_ * DH_ + 255) / 256, 256, 0, stream>>>(wv, wqkvt + 2 * DH_ * DH_, DH_, DH_);
    wtrans_kernel<<<(DH_ * DH_ + 255) / 256, 256, 0, stream>>>(wo, wot, DH_, DH_);
    wtrans_kernel<<<(DH_ * DFF_ + 255) / 256, 256, 0, stream>>>(w_ff1, wf1t, DH_, DFF_);
    wtrans_kernel<<<(DFF_ * DH_ + 255) / 256, 256, 0, stream>>>(w_ff2, wf2t, DFF_, DH_);
    bcat_kernel<<<3, 256, 0, stream>>>(bq, bk, bv, bqkv);

    // init_avg_h -> out[B*DH ...]
    initavg_kernel<<<BG, 128, 0, stream>>>(x, out + BG * DH_);

    // BN1 -> Xb bf16 (B0)
    colstats_kernel<DIN_><<<NN / 256, DIN_, 0, stream>>>(x, csum, csumsq);
    bnfin_kernel<DIN_><<<1, DIN_, 0, stream>>>(csum, csumsq, bn1_g, bn1_b, scl, shf);
    bnapply_kernel<DIN_><<<NN * DIN_ / 256, 256, 0, stream>>>(x, scl, shf, B0);

    // CSR build
    deg_kernel<<<EE / 256, 256, 0, stream>>>(ei + EE, deg);
    scan_kernel<<<1, 1024, 0, stream>>>(deg, off, dis);
    scatter_kernel<<<EE / 256, 256, 0, stream>>>(ei, ei + EE, off, cnt, srow);

    // agg1 on input side (A·X)·W == A·(X·W): Xa = Anorm @ Xb  (bf16, 128 cols)
    aggb_kernel<DIN_><<<NN / 4, 256, 0, stream>>>(B0, off, srow, dis, Xa);
    // conv1: h1 = relu(Xa @ w_conv1 + b) -> S1 fp32
    gemm_bf16_kernel<<<dim3(DH_ / 128, NN / 128), 256, 0, stream>>>(
        Xa, wc1t, S1, nullptr, NN, DIN_, DH_, b_conv1, nullptr, nullptr, 1, 0);

    // BN2 -> X2b bf16 (B0)
    hipMemsetAsync(csum, 0, 2048, stream);
    colstats_kernel<DH_><<<NN / 256, DH_, 0, stream>>>(S1, csum, csumsq);
    bnfin_kernel<DH_><<<1, DH_, 0, stream>>>(csum, csumsq, bn2_g, bn2_b, scl, shf);
    bnapply_kernel<DH_><<<NN * DH_ / 256, 256, 0, stream>>>(S1, scl, shf, B0);

    // agg2: X2a = Anorm @ X2b (bf16, 256 cols)
    aggb_kernel<DH_><<<NN / 4, 256, 0, stream>>>(B0, off, srow, dis, Xa);
    // conv2: t = h1 + relu(X2a @ w_conv2 + b) + inter[graph] -> S3 fp32 + B0 bf16
    gemm_bf16_kernel<<<dim3(DH_ / 128, NN / 128), 256, 0, stream>>>(
        Xa, wc2t, S3, B0, NN, DH_, DH_, b_conv2, S1, inter_f, 1, 1);

    // Fused QKV projection: QKVb = tb @ [wq|wk|wv] + [bq|bk|bv]  (bf16 out)
    gemm_bf16_kernel<<<dim3(768 / 128, NN / 128), 256, 0, stream>>>(
        B0, wqkvt, nullptr, QKVb, NN, DH_, 768, bqkv, nullptr, nullptr, 0, 0);

    // MFMA flash attention -> Ob bf16 (B0; tb dead after QKV gemm)
    attn_mfma_kernel<<<BG * NH, 256, 0, stream>>>(QKVb, B0);

    // z = Ob @ wo + bo + t -> S4 ; t2 = LN(z) -> S4 (+bf16 B0)
    gemm_bf16_kernel<<<dim3(DH_ / 128, NN / 128), 256, 0, stream>>>(
        B0, wot, S4, nullptr, NN, DH_, DH_, bo, S3, nullptr, 0, 0);
    ln_kernel<<<NN / 4, 256, 0, stream>>>(S4, S4, B0, ln1_g, ln1_b);

    // FFN: F = relu(t2 @ w_ff1 + b1) -> Fb (bf16 over S0+S1) ;
    //      z2 = F @ w_ff2 + b2 + t2 -> S2
    gemm_bf16_kernel<<<dim3(DFF_ / 128, NN / 128), 256, 0, stream>>>(
        B0, wf1t, nullptr, Fb, NN, DH_, DFF_, b_ff1, nullptr, nullptr, 1, 0);
    gemm_bf16_kernel<<<dim3(DH_ / 128, NN / 128), 256, 0, stream>>>(
        Fb, wf2t, S2, nullptr, NN, DFF_, DH_, b_ff2, S4, nullptr, 0, 0);

    // t3 = LN(z2) in-place ; readout -> out[0 .. B*DH)
    ln_kernel<<<NN / 4, 256, 0, stream>>>(S2, S2, nullptr, ln2_g, ln2_b);
    readout_kernel<<<BG, 256, 0, stream>>>(S2, out);
}

// Round 8
// 752.953 us; speedup vs baseline: 2.2015x; 1.0268x over previous
//
#include <hip/hip_runtime.h>
#include <math.h>

// Problem constants (fixed by the reference)
#define NN   32768
#define BG   128
#define SG   256
#define EE   524288
#define DIN_ 128
#define DH_  256
#define NH   8
#define HD_  32
#define DFF_ 1024
#define EPS_ 1e-5f

typedef __attribute__((ext_vector_type(8))) short bf16x8;
typedef __attribute__((ext_vector_type(4))) float f32x4;

__device__ __forceinline__ unsigned short f2bf(float f) {
    unsigned int u = __builtin_bit_cast(unsigned int, f);
    unsigned int r = u + 0x7FFFu + ((u >> 16) & 1u);
    return (unsigned short)(r >> 16);
}
__device__ __forceinline__ float bf2f(unsigned short u) {
    return __builtin_bit_cast(float, (unsigned int)u << 16);
}
__device__ __forceinline__ unsigned int pack2bf(float a, float b) {
    return (unsigned int)f2bf(a) | ((unsigned int)f2bf(b) << 16);
}
// Async global->LDS DMA, 16 B per lane. LDS dest must be wave-uniform base +
// lane*16 (m104/m108); caller guarantees the lane-contiguous layout.
__device__ __forceinline__ void glds16(const unsigned short* g, unsigned short* l) {
    __builtin_amdgcn_global_load_lds(
        (const __attribute__((address_space(1))) void*)g,
        (__attribute__((address_space(3))) void*)l, 16, 0, 0);
}
// s_waitcnt with vmcnt(N) only (exp/lgkm masked off). gfx9 encoding:
// vm[3:0]=bits0-3, exp=bits4-6, lgkm=bits8-11, vm[5:4]=bits14-15.
#define WAIT_VM4() __builtin_amdgcn_s_waitcnt(0x0F74)
#define WAIT_VM0() __builtin_amdgcn_s_waitcnt(0x0F70)

// ---------------------------------------------------------------------------
// init_avg_h: per-graph mean of raw x (graph b = rows [b*256, b*256+256)).
__global__ __launch_bounds__(128) void initavg_kernel(const float* __restrict__ X,
                                                      float* __restrict__ out2) {
    int b = blockIdx.x, j = threadIdx.x;
    float s = 0.f;
    for (int r = 0; r < SG; ++r) s += X[(size_t)(b * SG + r) * DIN_ + j];
    out2[b * DIN_ + j] = s * (1.f / (float)SG);
}

// Column sum / sumsq partials for BatchNorm stats (axis 0 over all N rows).
template <int C>
__global__ __launch_bounds__(C) void colstats_kernel(const float* __restrict__ X,
                                                     float* __restrict__ csum,
                                                     float* __restrict__ csumsq) {
    int j = threadIdx.x;
    size_t r0 = (size_t)blockIdx.x * 256;
    float s = 0.f, sq = 0.f;
    for (int r = 0; r < 256; ++r) {
        float v = X[(r0 + r) * C + j];
        s += v; sq += v * v;
    }
    atomicAdd(&csum[j], s);
    atomicAdd(&csumsq[j], sq);
}

template <int C>
__global__ __launch_bounds__(C) void bnfin_kernel(const float* __restrict__ csum,
                                                  const float* __restrict__ csumsq,
                                                  const float* __restrict__ g,
                                                  const float* __restrict__ b,
                                                  float* __restrict__ scale,
                                                  float* __restrict__ shift) {
    int j = threadIdx.x;
    float mu  = csum[j] * (1.f / (float)NN);
    float var = csumsq[j] * (1.f / (float)NN) - mu * mu;
    float s = g[j] * rsqrtf(var + EPS_);
    scale[j] = s;
    shift[j] = b[j] - mu * s;
}

// BN apply, bf16 output (feeds aggregation / MFMA GEMM A operand).
template <int C>
__global__ __launch_bounds__(256) void bnapply_kernel(const float* __restrict__ X,
                                                      const float* __restrict__ sc,
                                                      const float* __restrict__ sh,
                                                      unsigned short* __restrict__ Y) {
    int i = blockIdx.x * 256 + threadIdx.x;
    int j = i & (C - 1);
    Y[i] = f2bf(X[i] * sc[j] + sh[j]);
}

// Weight cast+transpose: W[K,N] fp32 -> Wt[N,K] bf16. Coalesced writes.
__global__ __launch_bounds__(256) void wtrans_kernel(const float* __restrict__ W,
                                                     unsigned short* __restrict__ Wt,
                                                     int K, int N) {
    int idx = blockIdx.x * 256 + threadIdx.x;
    if (idx < K * N) {
        int n = idx / K, k = idx - n * K;
        Wt[idx] = f2bf(W[(size_t)k * N + n]);
    }
}

// Concat Q/K/V biases into one fp32[768].
__global__ __launch_bounds__(256) void bcat_kernel(const float* __restrict__ bq,
                                                   const float* __restrict__ bk,
                                                   const float* __restrict__ bv,
                                                   float* __restrict__ o) {
    int j = threadIdx.x;
    if (blockIdx.x == 0) o[j] = bq[j];
    else if (blockIdx.x == 1) o[DH_ + j] = bk[j];
    else o[2 * DH_ + j] = bv[j];
}

// ---------------------------------------------------------------------------
// CSR build
__global__ __launch_bounds__(256) void deg_kernel(const int* __restrict__ col,
                                                  int* __restrict__ deg) {
    int e = blockIdx.x * 256 + threadIdx.x;
    if (e < EE) atomicAdd(&deg[col[e]], 1);
}

__global__ __launch_bounds__(1024) void scan_kernel(const int* __restrict__ deg,
                                                    int* __restrict__ off,
                                                    float* __restrict__ dis) {
    __shared__ int sums[1024];
    int t = threadIdx.x;
    int base = t * 32;
    int loc[32];
    int run = 0;
#pragma unroll
    for (int i = 0; i < 32; ++i) { loc[i] = run; run += deg[base + i]; }
    sums[t] = run;
    __syncthreads();
    for (int d = 1; d < 1024; d <<= 1) {
        int tmp = (t >= d) ? sums[t - d] : 0;
        __syncthreads();
        sums[t] += tmp;
        __syncthreads();
    }
    int excl = sums[t] - run;
#pragma unroll
    for (int i = 0; i < 32; ++i) {
        off[base + i] = excl + loc[i];
        dis[base + i] = rsqrtf((float)(deg[base + i] + 1));
    }
    if (t == 1023) off[NN] = sums[1023];
}

__global__ __launch_bounds__(256) void scatter_kernel(const int* __restrict__ row,
                                                      const int* __restrict__ col,
                                                      const int* __restrict__ off,
                                                      int* __restrict__ cnt,
                                                      int* __restrict__ srow) {
    int e = blockIdx.x * 256 + threadIdx.x;
    if (e < EE) {
        int c = col[e];
        int p = off[c] + atomicAdd(&cnt[c], 1);
        srow[p] = row[e];
    }
}

// ---------------------------------------------------------------------------
// Pure bf16 GCN aggregation: Y[c,:] = dc*(sum_e dis[r]*X[r,:] + dc*X[c,:]).
template <int C>
__global__ __launch_bounds__(256) void aggb_kernel(const unsigned short* __restrict__ X,
                                                   const int* __restrict__ off,
                                                   const int* __restrict__ srow,
                                                   const float* __restrict__ dis,
                                                   unsigned short* __restrict__ Y) {
    constexpr int EPL = C / 64;
    int lane = threadIdx.x & 63;
    int c = blockIdx.x * 4 + (threadIdx.x >> 6);
    float dc = dis[c];
    float acc[EPL];
    {
        unsigned short t[EPL];
        const unsigned short* xc = X + (size_t)c * C + lane * EPL;
        if constexpr (EPL == 4) *(uint2*)t = *(const uint2*)xc;
        else *(unsigned int*)t = *(const unsigned int*)xc;
#pragma unroll
        for (int e2 = 0; e2 < EPL; ++e2) acc[e2] = dc * bf2f(t[e2]);
    }
    int s = off[c], en = off[c + 1];
    for (int i = s; i < en; ++i) {
        int r = srow[i];
        float dr = dis[r];
        unsigned short t[EPL];
        const unsigned short* xr = X + (size_t)r * C + lane * EPL;
        if constexpr (EPL == 4) *(uint2*)t = *(const uint2*)xr;
        else *(unsigned int*)t = *(const unsigned int*)xr;
#pragma unroll
        for (int e2 = 0; e2 < EPL; ++e2) acc[e2] += dr * bf2f(t[e2]);
    }
    unsigned short t[EPL];
#pragma unroll
    for (int e2 = 0; e2 < EPL; ++e2) t[e2] = f2bf(acc[e2] * dc);
    unsigned short* yc = Y + (size_t)c * C + lane * EPL;
    if constexpr (EPL == 4) *(uint2*)yc = *(const uint2*)t;
    else *(unsigned int*)yc = *(const unsigned int*)t;
}

// ---------------------------------------------------------------------------
// bf16 MFMA GEMM (128x128 tile, 4 waves 2x2, 16x16x32 MFMAs).
// Double-buffered global_load_lds pipeline (raw s_barrier + vmcnt(4)).
// XCD-aware block swizzle: all N-blocks sharing an A-panel map to the same
// XCD (dispatch round-robins XCDs by linear block id), so the panel is
// fetched into exactly one L2 instead of up to 8 non-coherent ones.
__global__ __launch_bounds__(256) void gemm_bf16_kernel(
    const unsigned short* __restrict__ A,
    const unsigned short* __restrict__ Bt,
    float* __restrict__ Cf,
    unsigned short* __restrict__ Cb,
    int M, int K, int N,
    const float* __restrict__ bias,
    const float* __restrict__ res,
    const float* __restrict__ inter,
    int do_relu, int relu_first) {
    constexpr int LDP = 32;  // bf16 per row, no pad (required by global_load_lds)
    __shared__ unsigned short As[2][128 * LDP];
    __shared__ unsigned short Bs[2][128 * LDP];
    // XCD swizzle: d = linear id; xcd = d&7 owns contiguous panel range.
    int gx = gridDim.x, gyP = gridDim.y >> 3;  // panels per XCD
    int d = blockIdx.y * gx + blockIdx.x;
    int xcd = d & 7, j2 = d >> 3;
    int bm = (xcd * gyP + j2 / gx) * 128;
    int bn = (j2 % gx) * 128;
    int tid = threadIdx.x;
    int wave = tid >> 6, lane = tid & 63;
    int wm = (wave & 1) * 64, wn = (wave >> 1) * 64;
    int lrc = lane & 15;
    int koct = lane >> 4;

    // staging coords: this lane DMAs row sr (+16 for 2nd chunk), k-offs skk
    int sr = wave * 32 + (lane >> 2);
    int skk = (lane & 3) * 8;
    int lofs = wave * 1024 + lane * 8;  // LDS dest offset (elements)
    const unsigned short* gA0 = A + (size_t)(bm + sr) * K + skk;
    const unsigned short* gB0 = Bt + (size_t)(bn + sr) * K + skk;

    f32x4 acc[4][4];
#pragma unroll
    for (int i = 0; i < 4; ++i)
#pragma unroll
        for (int j = 0; j < 4; ++j) acc[i][j] = (f32x4){0.f, 0.f, 0.f, 0.f};

    // prologue: prefetch K-step 0 into buffer 0
    glds16(gA0, As[0] + lofs);
    glds16(gA0 + (size_t)16 * K, As[0] + lofs + 512);
    glds16(gB0, Bs[0] + lofs);
    glds16(gB0 + (size_t)16 * K, Bs[0] + lofs + 512);

    int buf = 0;
    for (int k0 = 0; k0 < K; k0 += 32) {
        int nk = k0 + 32;
        if (nk < K) {  // prefetch next K-step into the other buffer
            int nb = buf ^ 1;
            glds16(gA0 + nk, As[nb] + lofs);
            glds16(gA0 + nk + (size_t)16 * K, As[nb] + lofs + 512);
            glds16(gB0 + nk, Bs[nb] + lofs);
            glds16(gB0 + nk + (size_t)16 * K, Bs[nb] + lofs + 512);
            WAIT_VM4();  // current stage's 4 loads done; next 4 in flight
        } else {
            WAIT_VM0();
        }
        __builtin_amdgcn_s_barrier();
        bf16x8 af[4], bfr[4];
#pragma unroll
        for (int i = 0; i < 4; ++i)
            af[i] = *(const bf16x8*)(As[buf] + (wm + i * 16 + lrc) * LDP + koct * 8);
#pragma unroll
        for (int j = 0; j < 4; ++j)
            bfr[j] = *(const bf16x8*)(Bs[buf] + (wn + j * 16 + lrc) * LDP + koct * 8);
#pragma unroll
        for (int i = 0; i < 4; ++i)
#pragma unroll
            for (int j = 0; j < 4; ++j)
                acc[i][j] = __builtin_amdgcn_mfma_f32_16x16x32_bf16(af[i], bfr[j],
                                                                    acc[i][j], 0, 0, 0);
        __builtin_amdgcn_s_barrier();  // reads of buf retired before next DMA hits it
        buf ^= 1;
    }
#pragma unroll
    for (int i = 0; i < 4; ++i) {
#pragma unroll
        for (int r = 0; r < 4; ++r) {
            int grow = bm + wm + i * 16 + koct * 4 + r;
#pragma unroll
            for (int j = 0; j < 4; ++j) {
                int gcol = bn + wn + j * 16 + lrc;
                float v = acc[i][j][r];
                if (bias) v += bias[gcol];
                if (relu_first) v = fmaxf(v, 0.f);
                if (res) v += res[(size_t)grow * N + gcol];
                if (inter) v += inter[(grow >> 8) * N + gcol];
                if (do_relu && !relu_first) v = fmaxf(v, 0.f);
                if (Cf) Cf[(size_t)grow * N + gcol] = v;
                if (Cb) Cb[(size_t)grow * N + gcol] = f2bf(v);
            }
        }
    }
}

// ---------------------------------------------------------------------------
// MFMA flash attention, transposed-score variant (see round 5 notes).
__global__ __launch_bounds__(256) void attn_mfma_kernel(
    const unsigned short* __restrict__ QKV,
    unsigned short* __restrict__ Ob) {
    int b = blockIdx.x >> 3, h = blockIdx.x & 7;
    __shared__ unsigned short Ks[256 * 40];    // [key][hd 32 + pad]
    __shared__ unsigned short Vt[32 * 264];    // [d][key 256 + pad]
    __shared__ unsigned short Ps[4 * 64 * 40]; // per-wave [q 64][key 32 + pad]
    __shared__ float Lc[4 * 64];               // per-wave corr/l broadcast
    const unsigned short* kg = QKV + (size_t)b * 256 * 768 + 256 + h * 32;
    const unsigned short* vg = QKV + (size_t)b * 256 * 768 + 512 + h * 32;
    int tid = threadIdx.x;
#pragma unroll
    for (int it = 0; it < 4; ++it) {
        int c = it * 256 + tid;
        int row = c >> 2, q4 = (c & 3) * 8;
        *(uint4*)(Ks + row * 40 + q4) = *(const uint4*)(kg + (size_t)row * 768 + q4);
    }
#pragma unroll
    for (int it = 0; it < 4; ++it) {
        int c = it * 256 + tid;
        int key = c >> 2, d0 = (c & 3) * 8;
        unsigned short tmp[8];
        *(uint4*)tmp = *(const uint4*)(vg + (size_t)key * 768 + d0);
#pragma unroll
        for (int j = 0; j < 8; ++j) Vt[(d0 + j) * 264 + key] = tmp[j];
    }
    __syncthreads();

    int wave = tid >> 6, lane = tid & 63;
    int lr = lane & 15, koct = lane >> 4;
    int qrow0 = b * 256 + wave * 64;
    bf16x8 qf[4];
#pragma unroll
    for (int j = 0; j < 4; ++j)
        qf[j] = *(const bf16x8*)(QKV + (size_t)(qrow0 + j * 16 + lr) * 768 + h * 32 + koct * 8);

    f32x4 Oa[4][2];
    float mj[4], lj[4];
#pragma unroll
    for (int i = 0; i < 4; ++i) {
        Oa[i][0] = (f32x4){0.f, 0.f, 0.f, 0.f};
        Oa[i][1] = (f32x4){0.f, 0.f, 0.f, 0.f};
        mj[i] = -1e30f; lj[i] = 0.f;
    }
    unsigned short* Pw = Ps + wave * (64 * 40);
    float* Lw = Lc + wave * 64;
    const float sc = 0.17677669529663689f;  // 1/sqrt(32)

    for (int kc = 0; kc < 256; kc += 32) {
        bf16x8 kf0 = *(const bf16x8*)(Ks + (kc + lr) * 40 + koct * 8);
        bf16x8 kf1 = *(const bf16x8*)(Ks + (kc + 16 + lr) * 40 + koct * 8);
        f32x4 St0[4], St1[4];
#pragma unroll
        for (int j = 0; j < 4; ++j) {
            St0[j] = __builtin_amdgcn_mfma_f32_16x16x32_bf16(kf0, qf[j],
                         (f32x4){0.f, 0.f, 0.f, 0.f}, 0, 0, 0);
            St1[j] = __builtin_amdgcn_mfma_f32_16x16x32_bf16(kf1, qf[j],
                         (f32x4){0.f, 0.f, 0.f, 0.f}, 0, 0, 0);
        }
#pragma unroll
        for (int j = 0; j < 4; ++j) {
            float s0[4], s1[4];
#pragma unroll
            for (int r = 0; r < 4; ++r) { s0[r] = St0[j][r] * sc; s1[r] = St1[j][r] * sc; }
            float mx = fmaxf(fmaxf(fmaxf(s0[0], s0[1]), fmaxf(s0[2], s0[3])),
                             fmaxf(fmaxf(s1[0], s1[1]), fmaxf(s1[2], s1[3])));
            mx = fmaxf(mx, __shfl_xor(mx, 16));
            mx = fmaxf(mx, __shfl_xor(mx, 32));
            float mn = fmaxf(mj[j], mx);
            float corr = __expf(mj[j] - mn);
            mj[j] = mn;
            float p0[4], p1[4], ps = 0.f;
#pragma unroll
            for (int r = 0; r < 4; ++r) {
                p0[r] = __expf(s0[r] - mn); p1[r] = __expf(s1[r] - mn);
                ps += p0[r] + p1[r];
            }
            ps += __shfl_xor(ps, 16);
            ps += __shfl_xor(ps, 32);
            lj[j] = lj[j] * corr + ps;
            if (koct == 0) Lw[j * 16 + lr] = corr;
            uint2 w0 = {pack2bf(p0[0], p0[1]), pack2bf(p0[2], p0[3])};
            uint2 w1 = {pack2bf(p1[0], p1[1]), pack2bf(p1[2], p1[3])};
            *(uint2*)(Pw + (j * 16 + lr) * 40 + koct * 4) = w0;
            *(uint2*)(Pw + (j * 16 + lr) * 40 + 16 + koct * 4) = w1;
        }
#pragma unroll
        for (int i = 0; i < 4; ++i) {
            f32x4 c4 = *(const f32x4*)(Lw + i * 16 + koct * 4);
#pragma unroll
            for (int r = 0; r < 4; ++r) { Oa[i][0][r] *= c4[r]; Oa[i][1][r] *= c4[r]; }
        }
        bf16x8 vf0 = *(const bf16x8*)(Vt + lr * 264 + kc + koct * 8);
        bf16x8 vf1 = *(const bf16x8*)(Vt + (16 + lr) * 264 + kc + koct * 8);
#pragma unroll
        for (int i = 0; i < 4; ++i) {
            bf16x8 pf = *(const bf16x8*)(Pw + (i * 16 + lr) * 40 + koct * 8);
            Oa[i][0] = __builtin_amdgcn_mfma_f32_16x16x32_bf16(pf, vf0, Oa[i][0], 0, 0, 0);
            Oa[i][1] = __builtin_amdgcn_mfma_f32_16x16x32_bf16(pf, vf1, Oa[i][1], 0, 0, 0);
        }
    }
    if (koct == 0) {
#pragma unroll
        for (int j = 0; j < 4; ++j) Lw[j * 16 + lr] = lj[j];
    }
    __builtin_amdgcn_s_waitcnt(0);  // wave-local LDS visibility
#pragma unroll
    for (int i = 0; i < 4; ++i) {
        f32x4 l4 = *(const f32x4*)(Lw + i * 16 + koct * 4);
#pragma unroll
        for (int r = 0; r < 4; ++r) {
            float inv = 1.f / l4[r];
            int row = qrow0 + i * 16 + koct * 4 + r;
#pragma unroll
            for (int jn = 0; jn < 2; ++jn) {
                int col = h * 32 + jn * 16 + lr;
                Ob[(size_t)row * 256 + col] = f2bf(Oa[i][jn][r] * inv);
            }
        }
    }
}

// LayerNorm over last dim (256). One wave per row; in-place safe.
__global__ __launch_bounds__(256) void ln_kernel(const float* __restrict__ Z,
                                                 float* __restrict__ Out,
                                                 unsigned short* __restrict__ Outb,
                                                 const float* __restrict__ g,
                                                 const float* __restrict__ bt) {
    int row = blockIdx.x * 4 + (threadIdx.x >> 6);
    int lane = threadIdx.x & 63;
    const float* z = Z + (size_t)row * DH_;
    float v[4];
    float sum = 0.f;
#pragma unroll
    for (int i = 0; i < 4; ++i) { v[i] = z[lane + i * 64]; sum += v[i]; }
#pragma unroll
    for (int off = 32; off; off >>= 1) sum += __shfl_xor(sum, off);
    float mu = sum * (1.f / (float)DH_);
    float vs = 0.f;
#pragma unroll
    for (int i = 0; i < 4; ++i) { float d = v[i] - mu; vs += d * d; }
#pragma unroll
    for (int off = 32; off; off >>= 1) vs += __shfl_xor(vs, off);
    float rs = rsqrtf(vs * (1.f / (float)DH_) + EPS_);
#pragma unroll
    for (int i = 0; i < 4; ++i) {
        int col = lane + i * 64;
        float y = (v[i] - mu) * rs * g[col] + bt[col];
        Out[(size_t)row * DH_ + col] = y;
        if (Outb) Outb[(size_t)row * DH_ + col] = f2bf(y);
    }
}

// Readout: per-graph column sum of t3.
__global__ __launch_bounds__(256) void readout_kernel(const float* __restrict__ T3,
                                                      float* __restrict__ out) {
    int b = blockIdx.x, j = threadIdx.x;
    float s = 0.f;
    for (int r = 0; r < SG; ++r) s += T3[(size_t)(b * SG + r) * DH_ + j];
    out[b * DH_ + j] = s;
}

// ---------------------------------------------------------------------------
extern "C" void kernel_launch(void* const* d_in, const int* in_sizes, int n_in,
                              void* d_out, int out_size, void* d_ws, size_t ws_size,
                              hipStream_t stream) {
    const float* x       = (const float*)d_in[0];
    const int*   ei      = (const int*)d_in[1];
    const float* inter_f = (const float*)d_in[3];
    const float* bn1_g = (const float*)d_in[4],  *bn1_b = (const float*)d_in[5];
    const float* bn2_g = (const float*)d_in[6],  *bn2_b = (const float*)d_in[7];
    const float* w_conv1 = (const float*)d_in[8],  *b_conv1 = (const float*)d_in[9];
    const float* w_conv2 = (const float*)d_in[10], *b_conv2 = (const float*)d_in[11];
    const float* wq = (const float*)d_in[12], *bq = (const float*)d_in[13];
    const float* wk = (const float*)d_in[14], *bk = (const float*)d_in[15];
    const float* wv = (const float*)d_in[16], *bv = (const float*)d_in[17];
    const float* wo = (const float*)d_in[18], *bo = (const float*)d_in[19];
    const float* ln1_g = (const float*)d_in[20], *ln1_b = (const float*)d_in[21];
    const float* ln2_g = (const float*)d_in[22], *ln2_b = (const float*)d_in[23];
    const float* w_ff1 = (const float*)d_in[24], *b_ff1 = (const float*)d_in[25];
    const float* w_ff2 = (const float*)d_in[26], *b_ff2 = (const float*)d_in[27];
    float* out = (float*)d_out;

    char* base = (char*)d_ws;
    size_t o = 0;
    auto alloc = [&](size_t bytes) -> void* {
        void* p = base + o;
        o = (o + bytes + 255) & ~(size_t)255;
        return p;
    };
    int*   deg    = (int*)alloc(NN * 4);
    int*   off    = (int*)alloc((NN + 1) * 4);
    int*   cnt    = (int*)alloc(NN * 4);
    int*   srow   = (int*)alloc(EE * 4);
    float* dis    = (float*)alloc(NN * 4);
    float* csum   = (float*)alloc(256 * 4);
    float* csumsq = (float*)alloc(256 * 4);
    float* scl    = (float*)alloc(256 * 4);
    float* shf    = (float*)alloc(256 * 4);
    float* bqkv   = (float*)alloc(768 * 4);
    const size_t SLOT = (size_t)NN * DH_;            // 8M floats = 32 MB
    float* S0 = (float*)alloc(SLOT * 4);             // Xa/X2a ; QKVb/Fb alias
    float* S1 = (float*)alloc(SLOT * 4);             // h1 ; QKVb/Fb alias
    float* S2 = (float*)alloc(SLOT * 4);             // z2/t3
    float* S3 = (float*)alloc(SLOT * 4);             // t
    float* S4 = (float*)alloc(SLOT * 4);             // z -> t2
    unsigned short* B0 = (unsigned short*)alloc(SLOT * 2);  // Xb/X2b/tb/Ob/t2b
    unsigned short* wc1t  = (unsigned short*)alloc((size_t)DIN_ * DH_ * 2);
    unsigned short* wc2t  = (unsigned short*)alloc((size_t)DH_ * DH_ * 2);
    unsigned short* wqkvt = (unsigned short*)alloc((size_t)DH_ * DH_ * 3 * 2);
    unsigned short* wot   = (unsigned short*)alloc((size_t)DH_ * DH_ * 2);
    unsigned short* wf1t  = (unsigned short*)alloc((size_t)DH_ * DFF_ * 2);
    unsigned short* wf2t  = (unsigned short*)alloc((size_t)DFF_ * DH_ * 2);
    unsigned short* Xa   = (unsigned short*)S0;      // agg outputs (dead after GEMM)
    unsigned short* QKVb = (unsigned short*)S0;      // 48 MB over S0+S1
    unsigned short* Fb   = (unsigned short*)S0;      // 64 MB over S0+S1

    hipMemsetAsync(deg, 0, NN * 4, stream);
    hipMemsetAsync(cnt, 0, NN * 4, stream);
    hipMemsetAsync(csum, 0, 2048, stream);

    // Weight transposes (bf16) + QKV bias concat
    wtrans_kernel<<<(DIN_ * DH_ + 255) / 256, 256, 0, stream>>>(w_conv1, wc1t, DIN_, DH_);
    wtrans_kernel<<<(DH_ * DH_ + 255) / 256, 256, 0, stream>>>(w_conv2, wc2t, DH_, DH_);
    wtrans_kernel<<<(DH_ * DH_ + 255) / 256, 256, 0, stream>>>(wq, wqkvt, DH_, DH_);
    wtrans_kernel<<<(DH_ * DH_ + 255) / 256, 256, 0, stream>>>(wk, wqkvt + DH_ * DH_, DH_, DH_);
    wtrans_kernel<<<(DH_ * DH_ + 255) / 256, 256, 0, stream>>>(wv, wqkvt + 2 * DH_ * DH_, DH_, DH_);
    wtrans_kernel<<<(DH_ * DH_ + 255) / 256, 256, 0, stream>>>(wo, wot, DH_, DH_);
    wtrans_kernel<<<(DH_ * DFF_ + 255) / 256, 256, 0, stream>>>(w_ff1, wf1t, DH_, DFF_);
    wtrans_kernel<<<(DFF_ * DH_ + 255) / 256, 256, 0, stream>>>(w_ff2, wf2t, DFF_, DH_);
    bcat_kernel<<<3, 256, 0, stream>>>(bq, bk, bv, bqkv);

    // init_avg_h -> out[B*DH ...]
    initavg_kernel<<<BG, 128, 0, stream>>>(x, out + BG * DH_);

    // BN1 -> Xb bf16 (B0)
    colstats_kernel<DIN_><<<NN / 256, DIN_, 0, stream>>>(x, csum, csumsq);
    bnfin_kernel<DIN_><<<1, DIN_, 0, stream>>>(csum, csumsq, bn1_g, bn1_b, scl, shf);
    bnapply_kernel<DIN_><<<NN * DIN_ / 256, 256, 0, stream>>>(x, scl, shf, B0);

    // CSR build
    deg_kernel<<<EE / 256, 256, 0, stream>>>(ei + EE, deg);
    scan_kernel<<<1, 1024, 0, stream>>>(deg, off, dis);
    scatter_kernel<<<EE / 256, 256, 0, stream>>>(ei, ei + EE, off, cnt, srow);

    // agg1 on input side (A·X)·W == A·(X·W): Xa = Anorm @ Xb  (bf16, 128 cols)
    aggb_kernel<DIN_><<<NN / 4, 256, 0, stream>>>(B0, off, srow, dis, Xa);
    // conv1: h1 = relu(Xa @ w_conv1 + b) -> S1 fp32
    gemm_bf16_kernel<<<dim3(DH_ / 128, NN / 128), 256, 0, stream>>>(
        Xa, wc1t, S1, nullptr, NN, DIN_, DH_, b_conv1, nullptr, nullptr, 1, 0);

    // BN2 -> X2b bf16 (B0)
    hipMemsetAsync(csum, 0, 2048, stream);
    colstats_kernel<DH_><<<NN / 256, DH_, 0, stream>>>(S1, csum, csumsq);
    bnfin_kernel<DH_><<<1, DH_, 0, stream>>>(csum, csumsq, bn2_g, bn2_b, scl, shf);
    bnapply_kernel<DH_><<<NN * DH_ / 256, 256, 0, stream>>>(S1, scl, shf, B0);

    // agg2: X2a = Anorm @ X2b (bf16, 256 cols)
    aggb_kernel<DH_><<<NN / 4, 256, 0, stream>>>(B0, off, srow, dis, Xa);
    // conv2: t = h1 + relu(X2a @ w_conv2 + b) + inter[graph] -> S3 fp32 + B0 bf16
    gemm_bf16_kernel<<<dim3(DH_ / 128, NN / 128), 256, 0, stream>>>(
        Xa, wc2t, S3, B0, NN, DH_, DH_, b_conv2, S1, inter_f, 1, 1);

    // Fused QKV projection: QKVb = tb @ [wq|wk|wv] + [bq|bk|bv]  (bf16 out)
    gemm_bf16_kernel<<<dim3(768 / 128, NN / 128), 256, 0, stream>>>(
        B0, wqkvt, nullptr, QKVb, NN, DH_, 768, bqkv, nullptr, nullptr, 0, 0);

    // MFMA flash attention -> Ob bf16 (B0; tb dead after QKV gemm)
    attn_mfma_kernel<<<BG * NH, 256, 0, stream>>>(QKVb, B0);

    // z = Ob @ wo + bo + t -> S4 ; t2 = LN(z) -> S4 (+bf16 B0)
    gemm_bf16_kernel<<<dim3(DH_ / 128, NN / 128), 256, 0, stream>>>(
        B0, wot, S4, nullptr, NN, DH_, DH_, bo, S3, nullptr, 0, 0);
    ln_kernel<<<NN / 4, 256, 0, stream>>>(S4, S4, B0, ln1_g, ln1_b);

    // FFN: F = relu(t2 @ w_ff1 + b1) -> Fb (bf16 over S0+S1) ;
    //      z2 = F @ w_ff2 + b2 + t2 -> S2
    gemm_bf16_kernel<<<dim3(DFF_ / 128, NN / 128), 256, 0, stream>>>(
        B0, wf1t, nullptr, Fb, NN, DH_, DFF_, b_ff1, nullptr, nullptr, 1, 0);
    gemm_bf16_kernel<<<dim3(DH_ / 128, NN / 128), 256, 0, stream>>>(
        Fb, wf2t, S2, nullptr, NN, DFF_, DH_, b_ff2, S4, nullptr, 0, 0);

    // t3 = LN(z2) in-place ; readout -> out[0 .. B*DH)
    ln_kernel<<<NN / 4, 256, 0, stream>>>(S2, S2, nullptr, ln2_g, ln2_b);
    readout_kernel<<<BG, 256, 0, stream>>>(S2, out);
}

// Round 10
// 702.941 us; speedup vs baseline: 2.3581x; 1.0711x over previous
//
#include <hip/hip_runtime.h>
#include <math.h>

// Problem constants (fixed by the reference)
#define NN   32768
#define BG   128
#define SG   256
#define EE   524288
#define DIN_ 128
#define DH_  256
#define NH   8
#define HD_  32
#define DFF_ 1024
#define EPS_ 1e-5f

typedef __attribute__((ext_vector_type(8))) short bf16x8;
typedef __attribute__((ext_vector_type(4))) float f32x4;

__device__ __forceinline__ unsigned short f2bf(float f) {
    unsigned int u = __builtin_bit_cast(unsigned int, f);
    unsigned int r = u + 0x7FFFu + ((u >> 16) & 1u);
    return (unsigned short)(r >> 16);
}
__device__ __forceinline__ float bf2f(unsigned short u) {
    return __builtin_bit_cast(float, (unsigned int)u << 16);
}
__device__ __forceinline__ unsigned int pack2bf(float a, float b) {
    return (unsigned int)f2bf(a) | ((unsigned int)f2bf(b) << 16);
}
// Async global->LDS DMA, 16 B per lane (dest = wave-uniform base + lane*16).
__device__ __forceinline__ void glds16(const unsigned short* g, unsigned short* l) {
    __builtin_amdgcn_global_load_lds(
        (const __attribute__((address_space(1))) void*)g,
        (__attribute__((address_space(3))) void*)l, 16, 0, 0);
}
// s_waitcnt with vmcnt(N) only (exp/lgkm masked off).
#define WAIT_VM4() __builtin_amdgcn_s_waitcnt(0x0F74)
#define WAIT_VM0() __builtin_amdgcn_s_waitcnt(0x0F70)

// ---------------------------------------------------------------------------
// init_avg_h: per-graph mean of raw x (graph b = rows [b*256, b*256+256)).
__global__ __launch_bounds__(128) void initavg_kernel(const float* __restrict__ X,
                                                      float* __restrict__ out2) {
    int b = blockIdx.x, j = threadIdx.x;
    float s = 0.f;
    for (int r = 0; r < SG; ++r) s += X[(size_t)(b * SG + r) * DIN_ + j];
    out2[b * DIN_ + j] = s * (1.f / (float)SG);
}

// Column sum / sumsq partials for BatchNorm stats; fp32 input (BN1).
template <int C>
__global__ __launch_bounds__(C) void colstats_kernel(const float* __restrict__ X,
                                                     float* __restrict__ csum,
                                                     float* __restrict__ csumsq) {
    int j = threadIdx.x;
    size_t r0 = (size_t)blockIdx.x * 256;
    float s = 0.f, sq = 0.f;
    for (int r = 0; r < 256; ++r) {
        float v = X[(r0 + r) * C + j];
        s += v; sq += v * v;
    }
    atomicAdd(&csum[j], s);
    atomicAdd(&csumsq[j], sq);
}

// bf16-input variant (BN2 stats over h1b).
template <int C>
__global__ __launch_bounds__(C) void colstats_b_kernel(const unsigned short* __restrict__ X,
                                                       float* __restrict__ csum,
                                                       float* __restrict__ csumsq) {
    int j = threadIdx.x;
    size_t r0 = (size_t)blockIdx.x * 256;
    float s = 0.f, sq = 0.f;
    for (int r = 0; r < 256; ++r) {
        float v = bf2f(X[(r0 + r) * C + j]);
        s += v; sq += v * v;
    }
    atomicAdd(&csum[j], s);
    atomicAdd(&csumsq[j], sq);
}

template <int C>
__global__ __launch_bounds__(C) void bnfin_kernel(const float* __restrict__ csum,
                                                  const float* __restrict__ csumsq,
                                                  const float* __restrict__ g,
                                                  const float* __restrict__ b,
                                                  float* __restrict__ scale,
                                                  float* __restrict__ shift) {
    int j = threadIdx.x;
    float mu  = csum[j] * (1.f / (float)NN);
    float var = csumsq[j] * (1.f / (float)NN) - mu * mu;
    float s = g[j] * rsqrtf(var + EPS_);
    scale[j] = s;
    shift[j] = b[j] - mu * s;
}

// BN apply, fp32 in -> bf16 out (BN1).
template <int C>
__global__ __launch_bounds__(256) void bnapply_kernel(const float* __restrict__ X,
                                                      const float* __restrict__ sc,
                                                      const float* __restrict__ sh,
                                                      unsigned short* __restrict__ Y) {
    int i = blockIdx.x * 256 + threadIdx.x;
    int j = i & (C - 1);
    Y[i] = f2bf(X[i] * sc[j] + sh[j]);
}

// BN apply, bf16 in -> bf16 out (BN2).
template <int C>
__global__ __launch_bounds__(256) void bnapply_b_kernel(const unsigned short* __restrict__ X,
                                                        const float* __restrict__ sc,
                                                        const float* __restrict__ sh,
                                                        unsigned short* __restrict__ Y) {
    int i = blockIdx.x * 256 + threadIdx.x;
    int j = i & (C - 1);
    Y[i] = f2bf(bf2f(X[i]) * sc[j] + sh[j]);
}

// Weight cast+transpose: W[K,N] fp32 -> Wt[N,K] bf16.
__global__ __launch_bounds__(256) void wtrans_kernel(const float* __restrict__ W,
                                                     unsigned short* __restrict__ Wt,
                                                     int K, int N) {
    int idx = blockIdx.x * 256 + threadIdx.x;
    if (idx < K * N) {
        int n = idx / K, k = idx - n * K;
        Wt[idx] = f2bf(W[(size_t)k * N + n]);
    }
}

// Concat Q/K/V biases into one fp32[768].
__global__ __launch_bounds__(256) void bcat_kernel(const float* __restrict__ bq,
                                                   const float* __restrict__ bk,
                                                   const float* __restrict__ bv,
                                                   float* __restrict__ o) {
    int j = threadIdx.x;
    if (blockIdx.x == 0) o[j] = bq[j];
    else if (blockIdx.x == 1) o[DH_ + j] = bk[j];
    else o[2 * DH_ + j] = bv[j];
}

// ---------------------------------------------------------------------------
// CSR build
__global__ __launch_bounds__(256) void deg_kernel(const int* __restrict__ col,
                                                  int* __restrict__ deg) {
    int e = blockIdx.x * 256 + threadIdx.x;
    if (e < EE) atomicAdd(&deg[col[e]], 1);
}

__global__ __launch_bounds__(1024) void scan_kernel(const int* __restrict__ deg,
                                                    int* __restrict__ off,
                                                    float* __restrict__ dis) {
    __shared__ int sums[1024];
    int t = threadIdx.x;
    int base = t * 32;
    int loc[32];
    int run = 0;
#pragma unroll
    for (int i = 0; i < 32; ++i) { loc[i] = run; run += deg[base + i]; }
    sums[t] = run;
    __syncthreads();
    for (int d = 1; d < 1024; d <<= 1) {
        int tmp = (t >= d) ? sums[t - d] : 0;
        __syncthreads();
        sums[t] += tmp;
        __syncthreads();
    }
    int excl = sums[t] - run;
#pragma unroll
    for (int i = 0; i < 32; ++i) {
        off[base + i] = excl + loc[i];
        dis[base + i] = rsqrtf((float)(deg[base + i] + 1));
    }
    if (t == 1023) off[NN] = sums[1023];
}

__global__ __launch_bounds__(256) void scatter_kernel(const int* __restrict__ row,
                                                      const int* __restrict__ col,
                                                      const int* __restrict__ off,
                                                      int* __restrict__ cnt,
                                                      int* __restrict__ srow) {
    int e = blockIdx.x * 256 + threadIdx.x;
    if (e < EE) {
        int c = col[e];
        int p = off[c] + atomicAdd(&cnt[c], 1);
        srow[p] = row[e];
    }
}

// ---------------------------------------------------------------------------
// Pure bf16 GCN aggregation: Y[c,:] = dc*(sum_e dis[r]*X[r,:] + dc*X[c,:]).
template <int C>
__global__ __launch_bounds__(256) void aggb_kernel(const unsigned short* __restrict__ X,
                                                   const int* __restrict__ off,
                                                   const int* __restrict__ srow,
                                                   const float* __restrict__ dis,
                                                   unsigned short* __restrict__ Y) {
    constexpr int EPL = C / 64;
    int lane = threadIdx.x & 63;
    int c = blockIdx.x * 4 + (threadIdx.x >> 6);
    float dc = dis[c];
    float acc[EPL];
    {
        unsigned short t[EPL];
        const unsigned short* xc = X + (size_t)c * C + lane * EPL;
        if constexpr (EPL == 4) *(uint2*)t = *(const uint2*)xc;
        else *(unsigned int*)t = *(const unsigned int*)xc;
#pragma unroll
        for (int e2 = 0; e2 < EPL; ++e2) acc[e2] = dc * bf2f(t[e2]);
    }
    int s = off[c], en = off[c + 1];
    for (int i = s; i < en; ++i) {
        int r = srow[i];
        float dr = dis[r];
        unsigned short t[EPL];
        const unsigned short* xr = X + (size_t)r * C + lane * EPL;
        if constexpr (EPL == 4) *(uint2*)t = *(const uint2*)xr;
        else *(unsigned int*)t = *(const unsigned int*)xr;
#pragma unroll
        for (int e2 = 0; e2 < EPL; ++e2) acc[e2] += dr * bf2f(t[e2]);
    }
    unsigned short t[EPL];
#pragma unroll
    for (int e2 = 0; e2 < EPL; ++e2) t[e2] = f2bf(acc[e2] * dc);
    unsigned short* yc = Y + (size_t)c * C + lane * EPL;
    if constexpr (EPL == 4) *(uint2*)yc = *(const uint2*)t;
    else *(unsigned int*)yc = *(const unsigned int*)t;
}

// ---------------------------------------------------------------------------
// bf16 MFMA GEMM (128x128 tile, 4 waves 2x2, 16x16x32 MFMAs).
// Double-buffered global_load_lds (raw s_barrier + vmcnt(4)), XCD swizzle,
// XOR-swizzled LDS chunk layout (slot s of row r holds global chunk
// s ^ ((r>>1)&3); readers fetch slot koct ^ ((lrc>>1)&3)). All outputs bf16.
__global__ __launch_bounds__(256) void gemm_bf16_kernel(
    const unsigned short* __restrict__ A,
    const unsigned short* __restrict__ Bt,
    unsigned short* __restrict__ Cb,
    int M, int K, int N,
    const float* __restrict__ bias,
    const unsigned short* __restrict__ resb,
    const float* __restrict__ inter,
    int do_relu, int relu_first) {
    constexpr int LDP = 32;  // bf16 per row, no pad (required by global_load_lds)
    __shared__ unsigned short As[2][128 * LDP];
    __shared__ unsigned short Bs[2][128 * LDP];
    // XCD swizzle: d = linear id; xcd = d&7 owns a contiguous panel range.
    int gx = gridDim.x, gyP = gridDim.y >> 3;
    int d = blockIdx.y * gx + blockIdx.x;
    int xcd = d & 7, j2 = d >> 3;
    int bm = (xcd * gyP + j2 / gx) * 128;
    int bn = (j2 % gx) * 128;
    int tid = threadIdx.x;
    int wave = tid >> 6, lane = tid & 63;
    int wm = (wave & 1) * 64, wn = (wave >> 1) * 64;
    int lrc = lane & 15;
    int koct = lane >> 4;
    int rsw = (lrc >> 1) & 3;                  // read-side swizzle key
    int rofsA = (koct ^ rsw) * 8;              // slot element-offset for frag reads

    // staging: lane l DMAs row wave*32 + l/4 (+16), global chunk (l&3)^((l>>3)&3)
    int sr = wave * 32 + (lane >> 2);
    int cg = (lane & 3) ^ ((lane >> 3) & 3);
    int skk = cg * 8;
    int lofs = wave * 1024 + lane * 8;
    const unsigned short* gA0 = A + (size_t)(bm + sr) * K + skk;
    const unsigned short* gB0 = Bt + (size_t)(bn + sr) * K + skk;

    f32x4 acc[4][4];
#pragma unroll
    for (int i = 0; i < 4; ++i)
#pragma unroll
        for (int j = 0; j < 4; ++j) acc[i][j] = (f32x4){0.f, 0.f, 0.f, 0.f};

    // prologue: prefetch K-step 0 into buffer 0
    glds16(gA0, As[0] + lofs);
    glds16(gA0 + (size_t)16 * K, As[0] + lofs + 512);
    glds16(gB0, Bs[0] + lofs);
    glds16(gB0 + (size_t)16 * K, Bs[0] + lofs + 512);

    int buf = 0;
    for (int k0 = 0; k0 < K; k0 += 32) {
        int nk = k0 + 32;
        if (nk < K) {
            int nb = buf ^ 1;
            glds16(gA0 + nk, As[nb] + lofs);
            glds16(gA0 + nk + (size_t)16 * K, As[nb] + lofs + 512);
            glds16(gB0 + nk, Bs[nb] + lofs);
            glds16(gB0 + nk + (size_t)16 * K, Bs[nb] + lofs + 512);
            WAIT_VM4();
        } else {
            WAIT_VM0();
        }
        __builtin_amdgcn_s_barrier();
        bf16x8 af[4], bfr[4];
#pragma unroll
        for (int i = 0; i < 4; ++i)
            af[i] = *(const bf16x8*)(As[buf] + (wm + i * 16 + lrc) * LDP + rofsA);
#pragma unroll
        for (int j = 0; j < 4; ++j)
            bfr[j] = *(const bf16x8*)(Bs[buf] + (wn + j * 16 + lrc) * LDP + rofsA);
#pragma unroll
        for (int i = 0; i < 4; ++i)
#pragma unroll
            for (int j = 0; j < 4; ++j)
                acc[i][j] = __builtin_amdgcn_mfma_f32_16x16x32_bf16(af[i], bfr[j],
                                                                    acc[i][j], 0, 0, 0);
        __builtin_amdgcn_s_barrier();
        buf ^= 1;
    }
#pragma unroll
    for (int i = 0; i < 4; ++i) {
#pragma unroll
        for (int r = 0; r < 4; ++r) {
            int grow = bm + wm + i * 16 + koct * 4 + r;
#pragma unroll
            for (int j = 0; j < 4; ++j) {
                int gcol = bn + wn + j * 16 + lrc;
                float v = acc[i][j][r];
                if (bias) v += bias[gcol];
                if (relu_first) v = fmaxf(v, 0.f);
                if (resb) v += bf2f(resb[(size_t)grow * N + gcol]);
                if (inter) v += inter[(grow >> 8) * N + gcol];
                if (do_relu && !relu_first) v = fmaxf(v, 0.f);
                Cb[(size_t)grow * N + gcol] = f2bf(v);
            }
        }
    }
}

// ---------------------------------------------------------------------------
// MFMA flash attention, transposed-score variant (round-5 notes).
__global__ __launch_bounds__(256) void attn_mfma_kernel(
    const unsigned short* __restrict__ QKV,
    unsigned short* __restrict__ Ob) {
    int b = blockIdx.x >> 3, h = blockIdx.x & 7;
    __shared__ unsigned short Ks[256 * 40];
    __shared__ unsigned short Vt[32 * 264];
    __shared__ unsigned short Ps[4 * 64 * 40];
    __shared__ float Lc[4 * 64];
    const unsigned short* kg = QKV + (size_t)b * 256 * 768 + 256 + h * 32;
    const unsigned short* vg = QKV + (size_t)b * 256 * 768 + 512 + h * 32;
    int tid = threadIdx.x;
#pragma unroll
    for (int it = 0; it < 4; ++it) {
        int c = it * 256 + tid;
        int row = c >> 2, q4 = (c & 3) * 8;
        *(uint4*)(Ks + row * 40 + q4) = *(const uint4*)(kg + (size_t)row * 768 + q4);
    }
#pragma unroll
    for (int it = 0; it < 4; ++it) {
        int c = it * 256 + tid;
        int key = c >> 2, d0 = (c & 3) * 8;
        unsigned short tmp[8];
        *(uint4*)tmp = *(const uint4*)(vg + (size_t)key * 768 + d0);
#pragma unroll
        for (int j = 0; j < 8; ++j) Vt[(d0 + j) * 264 + key] = tmp[j];
    }
    __syncthreads();

    int wave = tid >> 6, lane = tid & 63;
    int lr = lane & 15, koct = lane >> 4;
    int qrow0 = b * 256 + wave * 64;
    bf16x8 qf[4];
#pragma unroll
    for (int j = 0; j < 4; ++j)
        qf[j] = *(const bf16x8*)(QKV + (size_t)(qrow0 + j * 16 + lr) * 768 + h * 32 + koct * 8);

    f32x4 Oa[4][2];
    float mj[4], lj[4];
#pragma unroll
    for (int i = 0; i < 4; ++i) {
        Oa[i][0] = (f32x4){0.f, 0.f, 0.f, 0.f};
        Oa[i][1] = (f32x4){0.f, 0.f, 0.f, 0.f};
        mj[i] = -1e30f; lj[i] = 0.f;
    }
    unsigned short* Pw = Ps + wave * (64 * 40);
    float* Lw = Lc + wave * 64;
    const float sc = 0.17677669529663689f;  // 1/sqrt(32)

    for (int kc = 0; kc < 256; kc += 32) {
        bf16x8 kf0 = *(const bf16x8*)(Ks + (kc + lr) * 40 + koct * 8);
        bf16x8 kf1 = *(const bf16x8*)(Ks + (kc + 16 + lr) * 40 + koct * 8);
        f32x4 St0[4], St1[4];
#pragma unroll
        for (int j = 0; j < 4; ++j) {
            St0[j] = __builtin_amdgcn_mfma_f32_16x16x32_bf16(kf0, qf[j],
                         (f32x4){0.f, 0.f, 0.f, 0.f}, 0, 0, 0);
            St1[j] = __builtin_amdgcn_mfma_f32_16x16x32_bf16(kf1, qf[j],
                         (f32x4){0.f, 0.f, 0.f, 0.f}, 0, 0, 0);
        }
#pragma unroll
        for (int j = 0; j < 4; ++j) {
            float s0[4], s1[4];
#pragma unroll
            for (int r = 0; r < 4; ++r) { s0[r] = St0[j][r] * sc; s1[r] = St1[j][r] * sc; }
            float mx = fmaxf(fmaxf(fmaxf(s0[0], s0[1]), fmaxf(s0[2], s0[3])),
                             fmaxf(fmaxf(s1[0], s1[1]), fmaxf(s1[2], s1[3])));
            mx = fmaxf(mx, __shfl_xor(mx, 16));
            mx = fmaxf(mx, __shfl_xor(mx, 32));
            float mn = fmaxf(mj[j], mx);
            float corr = __expf(mj[j] - mn);
            mj[j] = mn;
            float p0[4], p1[4], ps = 0.f;
#pragma unroll
            for (int r = 0; r < 4; ++r) {
                p0[r] = __expf(s0[r] - mn); p1[r] = __expf(s1[r] - mn);
                ps += p0[r] + p1[r];
            }
            ps += __shfl_xor(ps, 16);
            ps += __shfl_xor(ps, 32);
            lj[j] = lj[j] * corr + ps;
            if (koct == 0) Lw[j * 16 + lr] = corr;
            uint2 w0 = {pack2bf(p0[0], p0[1]), pack2bf(p0[2], p0[3])};
            uint2 w1 = {pack2bf(p1[0], p1[1]), pack2bf(p1[2], p1[3])};
            *(uint2*)(Pw + (j * 16 + lr) * 40 + koct * 4) = w0;
            *(uint2*)(Pw + (j * 16 + lr) * 40 + 16 + koct * 4) = w1;
        }
#pragma unroll
        for (int i = 0; i < 4; ++i) {
            f32x4 c4 = *(const f32x4*)(Lw + i * 16 + koct * 4);
#pragma unroll
            for (int r = 0; r < 4; ++r) { Oa[i][0][r] *= c4[r]; Oa[i][1][r] *= c4[r]; }
        }
        bf16x8 vf0 = *(const bf16x8*)(Vt + lr * 264 + kc + koct * 8);
        bf16x8 vf1 = *(const bf16x8*)(Vt + (16 + lr) * 264 + kc + koct * 8);
#pragma unroll
        for (int i = 0; i < 4; ++i) {
            bf16x8 pf = *(const bf16x8*)(Pw + (i * 16 + lr) * 40 + koct * 8);
            Oa[i][0] = __builtin_amdgcn_mfma_f32_16x16x32_bf16(pf, vf0, Oa[i][0], 0, 0, 0);
            Oa[i][1] = __builtin_amdgcn_mfma_f32_16x16x32_bf16(pf, vf1, Oa[i][1], 0, 0, 0);
        }
    }
    if (koct == 0) {
#pragma unroll
        for (int j = 0; j < 4; ++j) Lw[j * 16 + lr] = lj[j];
    }
    __builtin_amdgcn_s_waitcnt(0);
#pragma unroll
    for (int i = 0; i < 4; ++i) {
        f32x4 l4 = *(const f32x4*)(Lw + i * 16 + koct * 4);
#pragma unroll
        for (int r = 0; r < 4; ++r) {
            float inv = 1.f / l4[r];
            int row = qrow0 + i * 16 + koct * 4 + r;
#pragma unroll
            for (int jn = 0; jn < 2; ++jn) {
                int col = h * 32 + jn * 16 + lr;
                Ob[(size_t)row * 256 + col] = f2bf(Oa[i][jn][r] * inv);
            }
        }
    }
}

// LayerNorm over last dim (256), bf16 in -> bf16 out. One wave per row.
__global__ __launch_bounds__(256) void lnb_kernel(const unsigned short* __restrict__ Z,
                                                  unsigned short* __restrict__ Out,
                                                  const float* __restrict__ g,
                                                  const float* __restrict__ bt) {
    int row = blockIdx.x * 4 + (threadIdx.x >> 6);
    int lane = threadIdx.x & 63;
    const unsigned short* z = Z + (size_t)row * DH_;
    float v[4];
    float sum = 0.f;
#pragma unroll
    for (int i = 0; i < 4; ++i) { v[i] = bf2f(z[lane + i * 64]); sum += v[i]; }
#pragma unroll
    for (int off = 32; off; off >>= 1) sum += __shfl_xor(sum, off);
    float mu = sum * (1.f / (float)DH_);
    float vs = 0.f;
#pragma unroll
    for (int i = 0; i < 4; ++i) { float d = v[i] - mu; vs += d * d; }
#pragma unroll
    for (int off = 32; off; off >>= 1) vs += __shfl_xor(vs, off);
    float rs = rsqrtf(vs * (1.f / (float)DH_) + EPS_);
#pragma unroll
    for (int i = 0; i < 4; ++i) {
        int col = lane + i * 64;
        Out[(size_t)row * DH_ + col] = f2bf((v[i] - mu) * rs * g[col] + bt[col]);
    }
}

// Readout: per-graph column sum of t3 (bf16 in, fp32 out).
__global__ __launch_bounds__(256) void readout_kernel(const unsigned short* __restrict__ T3,
                                                      float* __restrict__ out) {
    int b = blockIdx.x, j = threadIdx.x;
    float s = 0.f;
    for (int r = 0; r < SG; ++r) s += bf2f(T3[(size_t)(b * SG + r) * DH_ + j]);
    out[b * DH_ + j] = s;
}

// ---------------------------------------------------------------------------
extern "C" void kernel_launch(void* const* d_in, const int* in_sizes, int n_in,
                              void* d_out, int out_size, void* d_ws, size_t ws_size,
                              hipStream_t stream) {
    const float* x       = (const float*)d_in[0];
    const int*   ei      = (const int*)d_in[1];
    const float* inter_f = (const float*)d_in[3];
    const float* bn1_g = (const float*)d_in[4],  *bn1_b = (const float*)d_in[5];
    const float* bn2_g = (const float*)d_in[6],  *bn2_b = (const float*)d_in[7];
    const float* w_conv1 = (const float*)d_in[8],  *b_conv1 = (const float*)d_in[9];
    const float* w_conv2 = (const float*)d_in[10], *b_conv2 = (const float*)d_in[11];
    const float* wq = (const float*)d_in[12], *bq = (const float*)d_in[13];
    const float* wk = (const float*)d_in[14], *bk = (const float*)d_in[15];
    const float* wv = (const float*)d_in[16], *bv = (const float*)d_in[17];
    const float* wo = (const float*)d_in[18], *bo = (const float*)d_in[19];
    const float* ln1_g = (const float*)d_in[20], *ln1_b = (const float*)d_in[21];
    const float* ln2_g = (const float*)d_in[22], *ln2_b = (const float*)d_in[23];
    const float* w_ff1 = (const float*)d_in[24], *b_ff1 = (const float*)d_in[25];
    const float* w_ff2 = (const float*)d_in[26], *b_ff2 = (const float*)d_in[27];
    float* out = (float*)d_out;

    char* base = (char*)d_ws;
    size_t o = 0;
    auto alloc = [&](size_t bytes) -> void* {
        void* p = base + o;
        o = (o + bytes + 255) & ~(size_t)255;
        return p;
    };
    int*   deg    = (int*)alloc(NN * 4);
    int*   off    = (int*)alloc((NN + 1) * 4);
    int*   cnt    = (int*)alloc(NN * 4);
    int*   srow   = (int*)alloc(EE * 4);
    float* dis    = (float*)alloc(NN * 4);
    float* csum   = (float*)alloc(256 * 4);
    float* csumsq = (float*)alloc(256 * 4);
    float* scl    = (float*)alloc(256 * 4);
    float* shf    = (float*)alloc(256 * 4);
    float* bqkv   = (float*)alloc(768 * 4);
    const size_t SLOT = (size_t)NN * DH_;  // 8M elements (16 MB bf16)
    // Arena (64 MB = NN*DFF bf16) with phase-disjoint tenants:
    //   phase1: Xa[0..4M) | X2b[4M..12M) | X2a[12M..20M)   (elements)
    //   phase2: QKVb[0..24M) | zb[24M..32M)
    //   phase3: Fb[0..32M)
    unsigned short* Arena = (unsigned short*)alloc((size_t)NN * DFF_ * 2);
    unsigned short* TB = (unsigned short*)alloc(SLOT * 2);  // tb -> z2b
    unsigned short* B0 = (unsigned short*)alloc(SLOT * 2);  // Xb->h1b->Ob->t2b->t3b
    unsigned short* wc1t  = (unsigned short*)alloc((size_t)DIN_ * DH_ * 2);
    unsigned short* wc2t  = (unsigned short*)alloc((size_t)DH_ * DH_ * 2);
    unsigned short* wqkvt = (unsigned short*)alloc((size_t)DH_ * DH_ * 3 * 2);
    unsigned short* wot   = (unsigned short*)alloc((size_t)DH_ * DH_ * 2);
    unsigned short* wf1t  = (unsigned short*)alloc((size_t)DH_ * DFF_ * 2);
    unsigned short* wf2t  = (unsigned short*)alloc((size_t)DFF_ * DH_ * 2);
    unsigned short* Xa   = Arena;                               // NN*DIN (4M)
    unsigned short* X2b  = Arena + (size_t)NN * DIN_;           // [4M..12M)
    unsigned short* X2a  = Arena + (size_t)NN * DIN_ + SLOT;    // [12M..20M)
    unsigned short* QKVb = Arena;                               // [0..24M)
    unsigned short* zb   = Arena + SLOT * 3;                    // [24M..32M)
    unsigned short* Fb   = Arena;                               // [0..32M)
    unsigned short* tb   = TB;
    unsigned short* z2b  = TB;

    hipMemsetAsync(deg, 0, NN * 4, stream);
    hipMemsetAsync(cnt, 0, NN * 4, stream);
    hipMemsetAsync(csum, 0, 2048, stream);

    // Weight transposes (bf16) + QKV bias concat
    wtrans_kernel<<<(DIN_ * DH_ + 255) / 256, 256, 0, stream>>>(w_conv1, wc1t, DIN_, DH_);
    wtrans_kernel<<<(DH_ * DH_ + 255) / 256, 256, 0, stream>>>(w_conv2, wc2t, DH_, DH_);
    wtrans_kernel<<<(DH_ * DH_ + 255) / 256, 256, 0, stream>>>(wq, wqkvt, DH_, DH_);
    wtrans_kernel<<<(DH_ * DH_ + 255) / 256, 256, 0, stream>>>(wk, wqkvt + DH_ * DH_, DH_, DH_);
    wtrans_kernel<<<(DH_ * DH_ + 255) / 256, 256, 0, stream>>>(wv, wqkvt + 2 * DH_ * DH_, DH_, DH_);
    wtrans_kernel<<<(DH_ * DH_ + 255) / 256, 256, 0, stream>>>(wo, wot, DH_, DH_);
    wtrans_kernel<<<(DH_ * DFF_ + 255) / 256, 256, 0, stream>>>(w_ff1, wf1t, DH_, DFF_);
    wtrans_kernel<<<(DFF_ * DH_ + 255) / 256, 256, 0, stream>>>(w_ff2, wf2t, DFF_, DH_);
    bcat_kernel<<<3, 256, 0, stream>>>(bq, bk, bv, bqkv);

    // init_avg_h -> out[B*DH ...]
    initavg_kernel<<<BG, 128, 0, stream>>>(x, out + BG * DH_);

    // BN1 -> Xb bf16 (B0)
    colstats_kernel<DIN_><<<NN / 256, DIN_, 0, stream>>>(x, csum, csumsq);
    bnfin_kernel<DIN_><<<1, DIN_, 0, stream>>>(csum, csumsq, bn1_g, bn1_b, scl, shf);
    bnapply_kernel<DIN_><<<NN * DIN_ / 256, 256, 0, stream>>>(x, scl, shf, B0);

    // CSR build
    deg_kernel<<<EE / 256, 256, 0, stream>>>(ei + EE, deg);
    scan_kernel<<<1, 1024, 0, stream>>>(deg, off, dis);
    scatter_kernel<<<EE / 256, 256, 0, stream>>>(ei, ei + EE, off, cnt, srow);

    // agg1 (A·X)·W == A·(X·W): Xa = Anorm @ Xb (bf16, 128 cols)
    aggb_kernel<DIN_><<<NN / 4, 256, 0, stream>>>(B0, off, srow, dis, Xa);
    // conv1: h1b = relu(Xa @ w_conv1 + b) -> B0 (Xb dead)
    gemm_bf16_kernel<<<dim3(DH_ / 128, NN / 128), 256, 0, stream>>>(
        Xa, wc1t, B0, NN, DIN_, DH_, b_conv1, nullptr, nullptr, 1, 0);

    // BN2 (stats on bf16 h1b) -> X2b
    hipMemsetAsync(csum, 0, 2048, stream);
    colstats_b_kernel<DH_><<<NN / 256, DH_, 0, stream>>>(B0, csum, csumsq);
    bnfin_kernel<DH_><<<1, DH_, 0, stream>>>(csum, csumsq, bn2_g, bn2_b, scl, shf);
    bnapply_b_kernel<DH_><<<NN * DH_ / 256, 256, 0, stream>>>(B0, scl, shf, X2b);

    // agg2: X2a = Anorm @ X2b (disjoint arena regions)
    aggb_kernel<DH_><<<NN / 4, 256, 0, stream>>>(X2b, off, srow, dis, X2a);
    // conv2: tb = h1b + relu(X2a @ w_conv2 + b) + inter[graph] -> TB
    gemm_bf16_kernel<<<dim3(DH_ / 128, NN / 128), 256, 0, stream>>>(
        X2a, wc2t, tb, NN, DH_, DH_, b_conv2, B0, inter_f, 1, 1);

    // Fused QKV: QKVb = tb @ [wq|wk|wv] + bqkv -> Arena[0..48MB) (X2* dead; tb in TB)
    gemm_bf16_kernel<<<dim3(768 / 128, NN / 128), 256, 0, stream>>>(
        tb, wqkvt, QKVb, NN, DH_, 768, bqkv, nullptr, nullptr, 0, 0);

    // MFMA flash attention -> Ob (B0; h1b dead)
    attn_mfma_kernel<<<BG * NH, 256, 0, stream>>>(QKVb, B0);

    // O-proj: zb = Ob @ wo + bo + tb -> Arena[48..64MB) ; t2b = LN(zb) -> B0
    gemm_bf16_kernel<<<dim3(DH_ / 128, NN / 128), 256, 0, stream>>>(
        B0, wot, zb, NN, DH_, DH_, bo, tb, nullptr, 0, 0);
    lnb_kernel<<<NN / 4, 256, 0, stream>>>(zb, B0, ln1_g, ln1_b);

    // FFN: Fb = relu(t2b @ w_ff1 + b1) -> Arena[0..64MB) (QKVb, zb dead) ;
    //      z2b = Fb @ w_ff2 + b2 + t2b -> TB (tb dead)
    gemm_bf16_kernel<<<dim3(DFF_ / 128, NN / 128), 256, 0, stream>>>(
        B0, wf1t, Fb, NN, DH_, DFF_, b_ff1, nullptr, nullptr, 1, 0);
    gemm_bf16_kernel<<<dim3(DH_ / 128, NN / 128), 256, 0, stream>>>(
        Fb, wf2t, z2b, NN, DFF_, DH_, b_ff2, B0, nullptr, 0, 0);

    // t3b = LN(z2b) -> B0 (t2b dead) ; readout -> out[0 .. B*DH)
    lnb_kernel<<<NN / 4, 256, 0, stream>>>(z2b, B0, ln2_g, ln2_b);
    readout_kernel<<<BG, 256, 0, stream>>>(B0, out);
}

// Round 11
// 637.840 us; speedup vs baseline: 2.5988x; 1.1021x over previous
//
#include <hip/hip_runtime.h>
#include <math.h>

// Problem constants (fixed by the reference)
#define NN   32768
#define BG   128
#define SG   256
#define EE   524288
#define DIN_ 128
#define DH_  256
#define NH   8
#define HD_  32
#define DFF_ 1024
#define EPS_ 1e-5f

typedef __attribute__((ext_vector_type(8))) short bf16x8;
typedef __attribute__((ext_vector_type(4))) float f32x4;

__device__ __forceinline__ unsigned short f2bf(float f) {
    unsigned int u = __builtin_bit_cast(unsigned int, f);
    unsigned int r = u + 0x7FFFu + ((u >> 16) & 1u);
    return (unsigned short)(r >> 16);
}
__device__ __forceinline__ float bf2f(unsigned short u) {
    return __builtin_bit_cast(float, (unsigned int)u << 16);
}
__device__ __forceinline__ unsigned int pack2bf(float a, float b) {
    return (unsigned int)f2bf(a) | ((unsigned int)f2bf(b) << 16);
}
// Async global->LDS DMA, 16 B per lane (dest = wave-uniform base + lane*16).
__device__ __forceinline__ void glds16(const unsigned short* g, unsigned short* l) {
    __builtin_amdgcn_global_load_lds(
        (const __attribute__((address_space(1))) void*)g,
        (__attribute__((address_space(3))) void*)l, 16, 0, 0);
}
// s_waitcnt with vmcnt(N) only (exp/lgkm masked off).
#define WAIT_VM4() __builtin_amdgcn_s_waitcnt(0x0F74)
#define WAIT_VM0() __builtin_amdgcn_s_waitcnt(0x0F70)

// ---------------------------------------------------------------------------
// init_avg_h: per-graph mean of raw x (graph b = rows [b*256, b*256+256)).
__global__ __launch_bounds__(128) void initavg_kernel(const float* __restrict__ X,
                                                      float* __restrict__ out2) {
    int b = blockIdx.x, j = threadIdx.x;
    float s = 0.f;
    for (int r = 0; r < SG; ++r) s += X[(size_t)(b * SG + r) * DIN_ + j];
    out2[b * DIN_ + j] = s * (1.f / (float)SG);
}

// Column sum / sumsq partials for BatchNorm stats; fp32 input (BN1).
template <int C>
__global__ __launch_bounds__(C) void colstats_kernel(const float* __restrict__ X,
                                                     float* __restrict__ csum,
                                                     float* __restrict__ csumsq) {
    int j = threadIdx.x;
    size_t r0 = (size_t)blockIdx.x * 256;
    float s = 0.f, sq = 0.f;
    for (int r = 0; r < 256; ++r) {
        float v = X[(r0 + r) * C + j];
        s += v; sq += v * v;
    }
    atomicAdd(&csum[j], s);
    atomicAdd(&csumsq[j], sq);
}

// bf16-input variant (BN2 stats over h1b).
template <int C>
__global__ __launch_bounds__(C) void colstats_b_kernel(const unsigned short* __restrict__ X,
                                                       float* __restrict__ csum,
                                                       float* __restrict__ csumsq) {
    int j = threadIdx.x;
    size_t r0 = (size_t)blockIdx.x * 256;
    float s = 0.f, sq = 0.f;
    for (int r = 0; r < 256; ++r) {
        float v = bf2f(X[(r0 + r) * C + j]);
        s += v; sq += v * v;
    }
    atomicAdd(&csum[j], s);
    atomicAdd(&csumsq[j], sq);
}

template <int C>
__global__ __launch_bounds__(C) void bnfin_kernel(const float* __restrict__ csum,
                                                  const float* __restrict__ csumsq,
                                                  const float* __restrict__ g,
                                                  const float* __restrict__ b,
                                                  float* __restrict__ scale,
                                                  float* __restrict__ shift) {
    int j = threadIdx.x;
    float mu  = csum[j] * (1.f / (float)NN);
    float var = csumsq[j] * (1.f / (float)NN) - mu * mu;
    float s = g[j] * rsqrtf(var + EPS_);
    scale[j] = s;
    shift[j] = b[j] - mu * s;
}

// BN apply, fp32 in -> bf16 out (BN1).
template <int C>
__global__ __launch_bounds__(256) void bnapply_kernel(const float* __restrict__ X,
                                                      const float* __restrict__ sc,
                                                      const float* __restrict__ sh,
                                                      unsigned short* __restrict__ Y) {
    int i = blockIdx.x * 256 + threadIdx.x;
    int j = i & (C - 1);
    Y[i] = f2bf(X[i] * sc[j] + sh[j]);
}

// Weight cast+transpose: W[K,N] fp32 -> Wt[N,K] bf16.
__global__ __launch_bounds__(256) void wtrans_kernel(const float* __restrict__ W,
                                                     unsigned short* __restrict__ Wt,
                                                     int K, int N) {
    int idx = blockIdx.x * 256 + threadIdx.x;
    if (idx < K * N) {
        int n = idx / K, k = idx - n * K;
        Wt[idx] = f2bf(W[(size_t)k * N + n]);
    }
}

// Concat Q/K/V biases into one fp32[768].
__global__ __launch_bounds__(256) void bcat_kernel(const float* __restrict__ bq,
                                                   const float* __restrict__ bk,
                                                   const float* __restrict__ bv,
                                                   float* __restrict__ o) {
    int j = threadIdx.x;
    if (blockIdx.x == 0) o[j] = bq[j];
    else if (blockIdx.x == 1) o[DH_ + j] = bk[j];
    else o[2 * DH_ + j] = bv[j];
}

// ---------------------------------------------------------------------------
// CSR build
__global__ __launch_bounds__(256) void deg_kernel(const int* __restrict__ col,
                                                  int* __restrict__ deg) {
    int e = blockIdx.x * 256 + threadIdx.x;
    if (e < EE) atomicAdd(&deg[col[e]], 1);
}

__global__ __launch_bounds__(1024) void scan_kernel(const int* __restrict__ deg,
                                                    int* __restrict__ off,
                                                    float* __restrict__ dis) {
    __shared__ int sums[1024];
    int t = threadIdx.x;
    int base = t * 32;
    int loc[32];
    int run = 0;
#pragma unroll
    for (int i = 0; i < 32; ++i) { loc[i] = run; run += deg[base + i]; }
    sums[t] = run;
    __syncthreads();
    for (int d = 1; d < 1024; d <<= 1) {
        int tmp = (t >= d) ? sums[t - d] : 0;
        __syncthreads();
        sums[t] += tmp;
        __syncthreads();
    }
    int excl = sums[t] - run;
#pragma unroll
    for (int i = 0; i < 32; ++i) {
        off[base + i] = excl + loc[i];
        dis[base + i] = rsqrtf((float)(deg[base + i] + 1));
    }
    if (t == 1023) off[NN] = sums[1023];
}

__global__ __launch_bounds__(256) void scatter_kernel(const int* __restrict__ row,
                                                      const int* __restrict__ col,
                                                      const int* __restrict__ off,
                                                      int* __restrict__ cnt,
                                                      int* __restrict__ srow) {
    int e = blockIdx.x * 256 + threadIdx.x;
    if (e < EE) {
        int c = col[e];
        int p = off[c] + atomicAdd(&cnt[c], 1);
        srow[p] = row[e];
    }
}

// ---------------------------------------------------------------------------
// bf16 GCN aggregation, 4x-unrolled edge loop for MLP.
// FUSE_BN=0: Y[c,:] = dc*(sum_e dis[r]*X[r,:] + dc*X[c,:]).
// FUSE_BN=1: aggregates raw X and applies BN inside (linearity):
//   Y[c,j] = dc*( scl[j]*acc_j + shf[j]*wsum ), wsum = sum dis[r] + dc.
template <int C, int FUSE_BN>
__global__ __launch_bounds__(256) void aggb_kernel(const unsigned short* __restrict__ X,
                                                   const int* __restrict__ off,
                                                   const int* __restrict__ srow,
                                                   const float* __restrict__ dis,
                                                   const float* __restrict__ scl,
                                                   const float* __restrict__ shf,
                                                   unsigned short* __restrict__ Y) {
    constexpr int EPL = C / 64;
    int lane = threadIdx.x & 63;
    int c = blockIdx.x * 4 + (threadIdx.x >> 6);
    float dc = dis[c];
    float acc[EPL];
    float wsum = dc;
    {
        unsigned short t[EPL];
        const unsigned short* xc = X + (size_t)c * C + lane * EPL;
        if constexpr (EPL == 4) *(uint2*)t = *(const uint2*)xc;
        else *(unsigned int*)t = *(const unsigned int*)xc;
#pragma unroll
        for (int e2 = 0; e2 < EPL; ++e2) acc[e2] = dc * bf2f(t[e2]);
    }
    int s = off[c], en = off[c + 1];
    int i = s;
    for (; i + 4 <= en; i += 4) {
        int r0 = srow[i], r1 = srow[i + 1], r2 = srow[i + 2], r3 = srow[i + 3];
        float d0 = dis[r0], d1 = dis[r1], d2 = dis[r2], d3 = dis[r3];
        unsigned short t0[EPL], t1[EPL], t2[EPL], t3[EPL];
        const unsigned short* p0 = X + (size_t)r0 * C + lane * EPL;
        const unsigned short* p1 = X + (size_t)r1 * C + lane * EPL;
        const unsigned short* p2 = X + (size_t)r2 * C + lane * EPL;
        const unsigned short* p3 = X + (size_t)r3 * C + lane * EPL;
        if constexpr (EPL == 4) {
            *(uint2*)t0 = *(const uint2*)p0;
            *(uint2*)t1 = *(const uint2*)p1;
            *(uint2*)t2 = *(const uint2*)p2;
            *(uint2*)t3 = *(const uint2*)p3;
        } else {
            *(unsigned int*)t0 = *(const unsigned int*)p0;
            *(unsigned int*)t1 = *(const unsigned int*)p1;
            *(unsigned int*)t2 = *(const unsigned int*)p2;
            *(unsigned int*)t3 = *(const unsigned int*)p3;
        }
        wsum += d0 + d1 + d2 + d3;
#pragma unroll
        for (int e2 = 0; e2 < EPL; ++e2) {
            acc[e2] += d0 * bf2f(t0[e2]) + d1 * bf2f(t1[e2]) +
                       d2 * bf2f(t2[e2]) + d3 * bf2f(t3[e2]);
        }
    }
    for (; i < en; ++i) {
        int r = srow[i];
        float dr = dis[r];
        unsigned short t[EPL];
        const unsigned short* xr = X + (size_t)r * C + lane * EPL;
        if constexpr (EPL == 4) *(uint2*)t = *(const uint2*)xr;
        else *(unsigned int*)t = *(const unsigned int*)xr;
        wsum += dr;
#pragma unroll
        for (int e2 = 0; e2 < EPL; ++e2) acc[e2] += dr * bf2f(t[e2]);
    }
    unsigned short t[EPL];
#pragma unroll
    for (int e2 = 0; e2 < EPL; ++e2) {
        float v;
        if constexpr (FUSE_BN) {
            int j = lane * EPL + e2;
            v = dc * (scl[j] * acc[e2] + shf[j] * wsum);
        } else {
            v = dc * acc[e2];
        }
        t[e2] = f2bf(v);
    }
    unsigned short* yc = Y + (size_t)c * C + lane * EPL;
    if constexpr (EPL == 4) *(uint2*)yc = *(const uint2*)t;
    else *(unsigned int*)yc = *(const unsigned int*)t;
}

// ---------------------------------------------------------------------------
// bf16 MFMA GEMM (128x128 tile, 4 waves 2x2, 16x16x32 MFMAs).
// Double-buffered global_load_lds (raw s_barrier + vmcnt(4)), XCD swizzle,
// XOR-swizzled LDS chunk layout. All outputs bf16.
__global__ __launch_bounds__(256) void gemm_bf16_kernel(
    const unsigned short* __restrict__ A,
    const unsigned short* __restrict__ Bt,
    unsigned short* __restrict__ Cb,
    int M, int K, int N,
    const float* __restrict__ bias,
    const unsigned short* __restrict__ resb,
    const float* __restrict__ inter,
    int do_relu, int relu_first) {
    constexpr int LDP = 32;
    __shared__ unsigned short As[2][128 * LDP];
    __shared__ unsigned short Bs[2][128 * LDP];
    int gx = gridDim.x, gyP = gridDim.y >> 3;
    int d = blockIdx.y * gx + blockIdx.x;
    int xcd = d & 7, j2 = d >> 3;
    int bm = (xcd * gyP + j2 / gx) * 128;
    int bn = (j2 % gx) * 128;
    int tid = threadIdx.x;
    int wave = tid >> 6, lane = tid & 63;
    int wm = (wave & 1) * 64, wn = (wave >> 1) * 64;
    int lrc = lane & 15;
    int koct = lane >> 4;
    int rsw = (lrc >> 1) & 3;
    int rofsA = (koct ^ rsw) * 8;

    int sr = wave * 32 + (lane >> 2);
    int cg = (lane & 3) ^ ((lane >> 3) & 3);
    int skk = cg * 8;
    int lofs = wave * 1024 + lane * 8;
    const unsigned short* gA0 = A + (size_t)(bm + sr) * K + skk;
    const unsigned short* gB0 = Bt + (size_t)(bn + sr) * K + skk;

    f32x4 acc[4][4];
#pragma unroll
    for (int i = 0; i < 4; ++i)
#pragma unroll
        for (int j = 0; j < 4; ++j) acc[i][j] = (f32x4){0.f, 0.f, 0.f, 0.f};

    glds16(gA0, As[0] + lofs);
    glds16(gA0 + (size_t)16 * K, As[0] + lofs + 512);
    glds16(gB0, Bs[0] + lofs);
    glds16(gB0 + (size_t)16 * K, Bs[0] + lofs + 512);

    int buf = 0;
    for (int k0 = 0; k0 < K; k0 += 32) {
        int nk = k0 + 32;
        if (nk < K) {
            int nb = buf ^ 1;
            glds16(gA0 + nk, As[nb] + lofs);
            glds16(gA0 + nk + (size_t)16 * K, As[nb] + lofs + 512);
            glds16(gB0 + nk, Bs[nb] + lofs);
            glds16(gB0 + nk + (size_t)16 * K, Bs[nb] + lofs + 512);
            WAIT_VM4();
        } else {
            WAIT_VM0();
        }
        __builtin_amdgcn_s_barrier();
        bf16x8 af[4], bfr[4];
#pragma unroll
        for (int i = 0; i < 4; ++i)
            af[i] = *(const bf16x8*)(As[buf] + (wm + i * 16 + lrc) * LDP + rofsA);
#pragma unroll
        for (int j = 0; j < 4; ++j)
            bfr[j] = *(const bf16x8*)(Bs[buf] + (wn + j * 16 + lrc) * LDP + rofsA);
#pragma unroll
        for (int i = 0; i < 4; ++i)
#pragma unroll
            for (int j = 0; j < 4; ++j)
                acc[i][j] = __builtin_amdgcn_mfma_f32_16x16x32_bf16(af[i], bfr[j],
                                                                    acc[i][j], 0, 0, 0);
        __builtin_amdgcn_s_barrier();
        buf ^= 1;
    }
#pragma unroll
    for (int i = 0; i < 4; ++i) {
#pragma unroll
        for (int r = 0; r < 4; ++r) {
            int grow = bm + wm + i * 16 + koct * 4 + r;
#pragma unroll
            for (int j = 0; j < 4; ++j) {
                int gcol = bn + wn + j * 16 + lrc;
                float v = acc[i][j][r];
                if (bias) v += bias[gcol];
                if (relu_first) v = fmaxf(v, 0.f);
                if (resb) v += bf2f(resb[(size_t)grow * N + gcol]);
                if (inter) v += inter[(grow >> 8) * N + gcol];
                if (do_relu && !relu_first) v = fmaxf(v, 0.f);
                Cb[(size_t)grow * N + gcol] = f2bf(v);
            }
        }
    }
}

// ---------------------------------------------------------------------------
// MFMA flash attention, transposed-score variant (round-5 notes).
__global__ __launch_bounds__(256) void attn_mfma_kernel(
    const unsigned short* __restrict__ QKV,
    unsigned short* __restrict__ Ob) {
    int b = blockIdx.x >> 3, h = blockIdx.x & 7;
    __shared__ unsigned short Ks[256 * 40];
    __shared__ unsigned short Vt[32 * 264];
    __shared__ unsigned short Ps[4 * 64 * 40];
    __shared__ float Lc[4 * 64];
    const unsigned short* kg = QKV + (size_t)b * 256 * 768 + 256 + h * 32;
    const unsigned short* vg = QKV + (size_t)b * 256 * 768 + 512 + h * 32;
    int tid = threadIdx.x;
#pragma unroll
    for (int it = 0; it < 4; ++it) {
        int c = it * 256 + tid;
        int row = c >> 2, q4 = (c & 3) * 8;
        *(uint4*)(Ks + row * 40 + q4) = *(const uint4*)(kg + (size_t)row * 768 + q4);
    }
#pragma unroll
    for (int it = 0; it < 4; ++it) {
        int c = it * 256 + tid;
        int key = c >> 2, d0 = (c & 3) * 8;
        unsigned short tmp[8];
        *(uint4*)tmp = *(const uint4*)(vg + (size_t)key * 768 + d0);
#pragma unroll
        for (int j = 0; j < 8; ++j) Vt[(d0 + j) * 264 + key] = tmp[j];
    }
    __syncthreads();

    int wave = tid >> 6, lane = tid & 63;
    int lr = lane & 15, koct = lane >> 4;
    int qrow0 = b * 256 + wave * 64;
    bf16x8 qf[4];
#pragma unroll
    for (int j = 0; j < 4; ++j)
        qf[j] = *(const bf16x8*)(QKV + (size_t)(qrow0 + j * 16 + lr) * 768 + h * 32 + koct * 8);

    f32x4 Oa[4][2];
    float mj[4], lj[4];
#pragma unroll
    for (int i = 0; i < 4; ++i) {
        Oa[i][0] = (f32x4){0.f, 0.f, 0.f, 0.f};
        Oa[i][1] = (f32x4){0.f, 0.f, 0.f, 0.f};
        mj[i] = -1e30f; lj[i] = 0.f;
    }
    unsigned short* Pw = Ps + wave * (64 * 40);
    float* Lw = Lc + wave * 64;
    const float sc = 0.17677669529663689f;  // 1/sqrt(32)

    for (int kc = 0; kc < 256; kc += 32) {
        bf16x8 kf0 = *(const bf16x8*)(Ks + (kc + lr) * 40 + koct * 8);
        bf16x8 kf1 = *(const bf16x8*)(Ks + (kc + 16 + lr) * 40 + koct * 8);
        f32x4 St0[4], St1[4];
#pragma unroll
        for (int j = 0; j < 4; ++j) {
            St0[j] = __builtin_amdgcn_mfma_f32_16x16x32_bf16(kf0, qf[j],
                         (f32x4){0.f, 0.f, 0.f, 0.f}, 0, 0, 0);
            St1[j] = __builtin_amdgcn_mfma_f32_16x16x32_bf16(kf1, qf[j],
                         (f32x4){0.f, 0.f, 0.f, 0.f}, 0, 0, 0);
        }
#pragma unroll
        for (int j = 0; j < 4; ++j) {
            float s0[4], s1[4];
#pragma unroll
            for (int r = 0; r < 4; ++r) { s0[r] = St0[j][r] * sc; s1[r] = St1[j][r] * sc; }
            float mx = fmaxf(fmaxf(fmaxf(s0[0], s0[1]), fmaxf(s0[2], s0[3])),
                             fmaxf(fmaxf(s1[0], s1[1]), fmaxf(s1[2], s1[3])));
            mx = fmaxf(mx, __shfl_xor(mx, 16));
            mx = fmaxf(mx, __shfl_xor(mx, 32));
            float mn = fmaxf(mj[j], mx);
            float corr = __expf(mj[j] - mn);
            mj[j] = mn;
            float p0[4], p1[4], ps = 0.f;
#pragma unroll
            for (int r = 0; r < 4; ++r) {
                p0[r] = __expf(s0[r] - mn); p1[r] = __expf(s1[r] - mn);
                ps += p0[r] + p1[r];
            }
            ps += __shfl_xor(ps, 16);
            ps += __shfl_xor(ps, 32);
            lj[j] = lj[j] * corr + ps;
            if (koct == 0) Lw[j * 16 + lr] = corr;
            uint2 w0 = {pack2bf(p0[0], p0[1]), pack2bf(p0[2], p0[3])};
            uint2 w1 = {pack2bf(p1[0], p1[1]), pack2bf(p1[2], p1[3])};
            *(uint2*)(Pw + (j * 16 + lr) * 40 + koct * 4) = w0;
            *(uint2*)(Pw + (j * 16 + lr) * 40 + 16 + koct * 4) = w1;
        }
#pragma unroll
        for (int i = 0; i < 4; ++i) {
            f32x4 c4 = *(const f32x4*)(Lw + i * 16 + koct * 4);
#pragma unroll
            for (int r = 0; r < 4; ++r) { Oa[i][0][r] *= c4[r]; Oa[i][1][r] *= c4[r]; }
        }
        bf16x8 vf0 = *(const bf16x8*)(Vt + lr * 264 + kc + koct * 8);
        bf16x8 vf1 = *(const bf16x8*)(Vt + (16 + lr) * 264 + kc + koct * 8);
#pragma unroll
        for (int i = 0; i < 4; ++i) {
            bf16x8 pf = *(const bf16x8*)(Pw + (i * 16 + lr) * 40 + koct * 8);
            Oa[i][0] = __builtin_amdgcn_mfma_f32_16x16x32_bf16(pf, vf0, Oa[i][0], 0, 0, 0);
            Oa[i][1] = __builtin_amdgcn_mfma_f32_16x16x32_bf16(pf, vf1, Oa[i][1], 0, 0, 0);
        }
    }
    if (koct == 0) {
#pragma unroll
        for (int j = 0; j < 4; ++j) Lw[j * 16 + lr] = lj[j];
    }
    __builtin_amdgcn_s_waitcnt(0);
#pragma unroll
    for (int i = 0; i < 4; ++i) {
        f32x4 l4 = *(const f32x4*)(Lw + i * 16 + koct * 4);
#pragma unroll
        for (int r = 0; r < 4; ++r) {
            float inv = 1.f / l4[r];
            int row = qrow0 + i * 16 + koct * 4 + r;
#pragma unroll
            for (int jn = 0; jn < 2; ++jn) {
                int col = h * 32 + jn * 16 + lr;
                Ob[(size_t)row * 256 + col] = f2bf(Oa[i][jn][r] * inv);
            }
        }
    }
}

// LayerNorm over last dim (256), bf16 in -> bf16 out. One wave per row.
__global__ __launch_bounds__(256) void lnb_kernel(const unsigned short* __restrict__ Z,
                                                  unsigned short* __restrict__ Out,
                                                  const float* __restrict__ g,
                                                  const float* __restrict__ bt) {
    int row = blockIdx.x * 4 + (threadIdx.x >> 6);
    int lane = threadIdx.x & 63;
    const unsigned short* z = Z + (size_t)row * DH_;
    float v[4];
    float sum = 0.f;
#pragma unroll
    for (int i = 0; i < 4; ++i) { v[i] = bf2f(z[lane + i * 64]); sum += v[i]; }
#pragma unroll
    for (int off = 32; off; off >>= 1) sum += __shfl_xor(sum, off);
    float mu = sum * (1.f / (float)DH_);
    float vs = 0.f;
#pragma unroll
    for (int i = 0; i < 4; ++i) { float d = v[i] - mu; vs += d * d; }
#pragma unroll
    for (int off = 32; off; off >>= 1) vs += __shfl_xor(vs, off);
    float rs = rsqrtf(vs * (1.f / (float)DH_) + EPS_);
#pragma unroll
    for (int i = 0; i < 4; ++i) {
        int col = lane + i * 64;
        Out[(size_t)row * DH_ + col] = f2bf((v[i] - mu) * rs * g[col] + bt[col]);
    }
}

// Readout: per-graph column sum of t3 (bf16 in, fp32 out).
__global__ __launch_bounds__(256) void readout_kernel(const unsigned short* __restrict__ T3,
                                                      float* __restrict__ out) {
    int b = blockIdx.x, j = threadIdx.x;
    float s = 0.f;
    for (int r = 0; r < SG; ++r) s += bf2f(T3[(size_t)(b * SG + r) * DH_ + j]);
    out[b * DH_ + j] = s;
}

// ---------------------------------------------------------------------------
extern "C" void kernel_launch(void* const* d_in, const int* in_sizes, int n_in,
                              void* d_out, int out_size, void* d_ws, size_t ws_size,
                              hipStream_t stream) {
    const float* x       = (const float*)d_in[0];
    const int*   ei      = (const int*)d_in[1];
    const float* inter_f = (const float*)d_in[3];
    const float* bn1_g = (const float*)d_in[4],  *bn1_b = (const float*)d_in[5];
    const float* bn2_g = (const float*)d_in[6],  *bn2_b = (const float*)d_in[7];
    const float* w_conv1 = (const float*)d_in[8],  *b_conv1 = (const float*)d_in[9];
    const float* w_conv2 = (const float*)d_in[10], *b_conv2 = (const float*)d_in[11];
    const float* wq = (const float*)d_in[12], *bq = (const float*)d_in[13];
    const float* wk = (const float*)d_in[14], *bk = (const float*)d_in[15];
    const float* wv = (const float*)d_in[16], *bv = (const float*)d_in[17];
    const float* wo = (const float*)d_in[18], *bo = (const float*)d_in[19];
    const float* ln1_g = (const float*)d_in[20], *ln1_b = (const float*)d_in[21];
    const float* ln2_g = (const float*)d_in[22], *ln2_b = (const float*)d_in[23];
    const float* w_ff1 = (const float*)d_in[24], *b_ff1 = (const float*)d_in[25];
    const float* w_ff2 = (const float*)d_in[26], *b_ff2 = (const float*)d_in[27];
    float* out = (float*)d_out;

    char* base = (char*)d_ws;
    size_t o = 0;
    auto alloc = [&](size_t bytes) -> void* {
        void* p = base + o;
        o = (o + bytes + 255) & ~(size_t)255;
        return p;
    };
    int*   deg    = (int*)alloc(NN * 4);
    int*   off    = (int*)alloc((NN + 1) * 4);
    int*   cnt    = (int*)alloc(NN * 4);
    int*   srow   = (int*)alloc(EE * 4);
    float* dis    = (float*)alloc(NN * 4);
    float* csum   = (float*)alloc(256 * 4);
    float* csumsq = (float*)alloc(256 * 4);
    float* scl    = (float*)alloc(256 * 4);
    float* shf    = (float*)alloc(256 * 4);
    float* bqkv   = (float*)alloc(768 * 4);
    const size_t SLOT = (size_t)NN * DH_;  // 8M elements (16 MB bf16)
    // Arena (64 MB) phase-disjoint tenants:
    //   phase1: Xa[0..4M) | X2a[4M..12M)
    //   phase2: QKVb[0..24M) | zb[24M..32M)
    //   phase3: Fb[0..32M)
    unsigned short* Arena = (unsigned short*)alloc((size_t)NN * DFF_ * 2);
    unsigned short* TB = (unsigned short*)alloc(SLOT * 2);  // tb -> z2b
    unsigned short* B0 = (unsigned short*)alloc(SLOT * 2);  // Xb->h1b->Ob->t2b->t3b
    unsigned short* wc1t  = (unsigned short*)alloc((size_t)DIN_ * DH_ * 2);
    unsigned short* wc2t  = (unsigned short*)alloc((size_t)DH_ * DH_ * 2);
    unsigned short* wqkvt = (unsigned short*)alloc((size_t)DH_ * DH_ * 3 * 2);
    unsigned short* wot   = (unsigned short*)alloc((size_t)DH_ * DH_ * 2);
    unsigned short* wf1t  = (unsigned short*)alloc((size_t)DH_ * DFF_ * 2);
    unsigned short* wf2t  = (unsigned short*)alloc((size_t)DFF_ * DH_ * 2);
    unsigned short* Xa   = Arena;                            // NN*DIN (4M)
    unsigned short* X2a  = Arena + (size_t)NN * DIN_;        // [4M..12M)
    unsigned short* QKVb = Arena;                            // [0..24M)
    unsigned short* zb   = Arena + SLOT * 3;                 // [24M..32M)
    unsigned short* Fb   = Arena;                            // [0..32M)
    unsigned short* tb   = TB;
    unsigned short* z2b  = TB;

    hipMemsetAsync(deg, 0, NN * 4, stream);
    hipMemsetAsync(cnt, 0, NN * 4, stream);
    hipMemsetAsync(csum, 0, 2048, stream);

    // Weight transposes (bf16) + QKV bias concat
    wtrans_kernel<<<(DIN_ * DH_ + 255) / 256, 256, 0, stream>>>(w_conv1, wc1t, DIN_, DH_);
    wtrans_kernel<<<(DH_ * DH_ + 255) / 256, 256, 0, stream>>>(w_conv2, wc2t, DH_, DH_);
    wtrans_kernel<<<(DH_ * DH_ + 255) / 256, 256, 0, stream>>>(wq, wqkvt, DH_, DH_);
    wtrans_kernel<<<(DH_ * DH_ + 255) / 256, 256, 0, stream>>>(wk, wqkvt + DH_ * DH_, DH_, DH_);
    wtrans_kernel<<<(DH_ * DH_ + 255) / 256, 256, 0, stream>>>(wv, wqkvt + 2 * DH_ * DH_, DH_, DH_);
    wtrans_kernel<<<(DH_ * DH_ + 255) / 256, 256, 0, stream>>>(wo, wot, DH_, DH_);
    wtrans_kernel<<<(DH_ * DFF_ + 255) / 256, 256, 0, stream>>>(w_ff1, wf1t, DH_, DFF_);
    wtrans_kernel<<<(DFF_ * DH_ + 255) / 256, 256, 0, stream>>>(w_ff2, wf2t, DFF_, DH_);
    bcat_kernel<<<3, 256, 0, stream>>>(bq, bk, bv, bqkv);

    // init_avg_h -> out[B*DH ...]
    initavg_kernel<<<BG, 128, 0, stream>>>(x, out + BG * DH_);

    // BN1 -> Xb bf16 (B0)
    colstats_kernel<DIN_><<<NN / 256, DIN_, 0, stream>>>(x, csum, csumsq);
    bnfin_kernel<DIN_><<<1, DIN_, 0, stream>>>(csum, csumsq, bn1_g, bn1_b, scl, shf);
    bnapply_kernel<DIN_><<<NN * DIN_ / 256, 256, 0, stream>>>(x, scl, shf, B0);

    // CSR build
    deg_kernel<<<EE / 256, 256, 0, stream>>>(ei + EE, deg);
    scan_kernel<<<1, 1024, 0, stream>>>(deg, off, dis);
    scatter_kernel<<<EE / 256, 256, 0, stream>>>(ei, ei + EE, off, cnt, srow);

    // agg1 (A·X)·W == A·(X·W): Xa = Anorm @ Xb (bf16, 128 cols)
    aggb_kernel<DIN_, 0><<<NN / 4, 256, 0, stream>>>(B0, off, srow, dis,
                                                     nullptr, nullptr, Xa);
    // conv1: h1b = relu(Xa @ w_conv1 + b) -> B0 (Xb dead)
    gemm_bf16_kernel<<<dim3(DH_ / 128, NN / 128), 256, 0, stream>>>(
        Xa, wc1t, B0, NN, DIN_, DH_, b_conv1, nullptr, nullptr, 1, 0);

    // BN2 stats on h1b -> scale/shift (apply fused into agg2)
    hipMemsetAsync(csum, 0, 2048, stream);
    colstats_b_kernel<DH_><<<NN / 256, DH_, 0, stream>>>(B0, csum, csumsq);
    bnfin_kernel<DH_><<<1, DH_, 0, stream>>>(csum, csumsq, bn2_g, bn2_b, scl, shf);

    // agg2 with fused BN apply: X2a = Anorm @ (h1b*s + b) -> Arena[4M..12M)
    aggb_kernel<DH_, 1><<<NN / 4, 256, 0, stream>>>(B0, off, srow, dis,
                                                    scl, shf, X2a);
    // conv2: tb = h1b + relu(X2a @ w_conv2 + b) + inter[graph] -> TB
    gemm_bf16_kernel<<<dim3(DH_ / 128, NN / 128), 256, 0, stream>>>(
        X2a, wc2t, tb, NN, DH_, DH_, b_conv2, B0, inter_f, 1, 1);

    // Fused QKV: QKVb = tb @ [wq|wk|wv] + bqkv -> Arena[0..48MB)
    gemm_bf16_kernel<<<dim3(768 / 128, NN / 128), 256, 0, stream>>>(
        tb, wqkvt, QKVb, NN, DH_, 768, bqkv, nullptr, nullptr, 0, 0);

    // MFMA flash attention -> Ob (B0; h1b dead)
    attn_mfma_kernel<<<BG * NH, 256, 0, stream>>>(QKVb, B0);

    // O-proj: zb = Ob @ wo + bo + tb -> Arena[48..64MB) ; t2b = LN(zb) -> B0
    gemm_bf16_kernel<<<dim3(DH_ / 128, NN / 128), 256, 0, stream>>>(
        B0, wot, zb, NN, DH_, DH_, bo, tb, nullptr, 0, 0);
    lnb_kernel<<<NN / 4, 256, 0, stream>>>(zb, B0, ln1_g, ln1_b);

    // FFN: Fb = relu(t2b @ w_ff1 + b1) -> Arena[0..64MB) ;
    //      z2b = Fb @ w_ff2 + b2 + t2b -> TB (tb dead)
    gemm_bf16_kernel<<<dim3(DFF_ / 128, NN / 128), 256, 0, stream>>>(
        B0, wf1t, Fb, NN, DH_, DFF_, b_ff1, nullptr, nullptr, 1, 0);
    gemm_bf16_kernel<<<dim3(DH_ / 128, NN / 128), 256, 0, stream>>>(
        Fb, wf2t, z2b, NN, DFF_, DH_, b_ff2, B0, nullptr, 0, 0);

    // t3b = LN(z2b) -> B0 (t2b dead) ; readout -> out[0 .. B*DH)
    lnb_kernel<<<NN / 4, 256, 0, stream>>>(z2b, B0, ln2_g, ln2_b);
    readout_kernel<<<BG, 256, 0, stream>>>(B0, out);
}